// Round 1
// baseline (1633.467 us; speedup 1.0000x reference)
//
#include <hip/hip_runtime.h>
#include <cstdint>
#include <cstddef>

// ---------------------------------------------------------------------------
// RegionSelectionAttention, fp32 baseline (correctness-first round).
// B=8, C=256, NH=4, HD=64, H=W=64, coarse grid 32x32 (P=1024), kf=256,
// fine tokens = 1024 per (b,h) pair. All heavy ops as 64x64-tile fp32 GEMMs.
// ---------------------------------------------------------------------------

#define SCALE_ 0.125f  // HD^-0.5
#define EPS_ 1e-5f

__device__ __forceinline__ void fma16(float (&acc)[4][4], const float4 a, const float4 b) {
  acc[0][0] = fmaf(a.x, b.x, acc[0][0]); acc[0][1] = fmaf(a.x, b.y, acc[0][1]);
  acc[0][2] = fmaf(a.x, b.z, acc[0][2]); acc[0][3] = fmaf(a.x, b.w, acc[0][3]);
  acc[1][0] = fmaf(a.y, b.x, acc[1][0]); acc[1][1] = fmaf(a.y, b.y, acc[1][1]);
  acc[1][2] = fmaf(a.y, b.z, acc[1][2]); acc[1][3] = fmaf(a.y, b.w, acc[1][3]);
  acc[2][0] = fmaf(a.z, b.x, acc[2][0]); acc[2][1] = fmaf(a.z, b.y, acc[2][1]);
  acc[2][2] = fmaf(a.z, b.z, acc[2][2]); acc[2][3] = fmaf(a.z, b.w, acc[2][3]);
  acc[3][0] = fmaf(a.w, b.x, acc[3][0]); acc[3][1] = fmaf(a.w, b.y, acc[3][1]);
  acc[3][2] = fmaf(a.w, b.z, acc[3][2]); acc[3][3] = fmaf(a.w, b.w, acc[3][3]);
}

// ---------------- K1: downsample conv k4 s2 p1, implicit GEMM --------------
// out xd[b][oc][32][32]; M=oc(256) x N=pix(8192), K = 256 ic * 16 taps
__global__ __launch_bounds__(256) void k_conv_down(
    const float* __restrict__ x, const float* __restrict__ w,
    const float* __restrict__ bias, float* __restrict__ xd) {
  __shared__ float As[16][68];
  __shared__ float Bs[16][68];
  const int t = threadIdx.x;
  const int pix0 = blockIdx.x * 64;
  const int oc0 = blockIdx.y * 64;
  const int ty = t >> 4, tx = t & 15;
  const int bimg = pix0 >> 10, pos = pix0 & 1023;
  float acc[4][4] = {};
  for (int ic = 0; ic < 256; ++ic) {
    // A: w_down[(oc0+ocl)*4096 + ic*16 + kk], store As[kk][ocl]
    {
      int ocl = t >> 2;
      int kk0 = (t & 3) * 4;
      const float4 wv = *(const float4*)&w[(size_t)(oc0 + ocl) * 4096 + ic * 16 + kk0];
      As[kk0 + 0][ocl] = wv.x; As[kk0 + 1][ocl] = wv.y;
      As[kk0 + 2][ocl] = wv.z; As[kk0 + 3][ocl] = wv.w;
    }
    // B: gathered input patch, Bs[kk][pixl]
    {
      int pl = t & 63;
      int pix = pix0 + pl;
      int rem = pix & 1023;
      int oy = rem >> 5, ox = rem & 31;
#pragma unroll
      for (int j = 0; j < 4; ++j) {
        int kk = (t >> 6) + j * 4;
        int ky = kk >> 2, kx = kk & 3;
        int iy = 2 * oy + ky - 1, ix = 2 * ox + kx - 1;
        float v = 0.f;
        if (iy >= 0 && iy < 64 && ix >= 0 && ix < 64)
          v = x[((size_t)(bimg * 256 + ic) * 64 + iy) * 64 + ix];
        Bs[kk][pl] = v;
      }
    }
    __syncthreads();
#pragma unroll
    for (int kk = 0; kk < 16; ++kk) {
      float4 a = *(const float4*)&As[kk][ty * 4];
      float4 b = *(const float4*)&Bs[kk][tx * 4];
      fma16(acc, a, b);
    }
    __syncthreads();
  }
#pragma unroll
  for (int i = 0; i < 4; ++i) {
    int oc = oc0 + ty * 4 + i;
    float bv = bias[oc];
    float4 o = make_float4(acc[i][0] + bv, acc[i][1] + bv, acc[i][2] + bv, acc[i][3] + bv);
    *(float4*)&xd[((size_t)(bimg * 256 + oc)) * 1024 + pos + tx * 4] = o;
  }
}

// ---------------- K2/K9: qkv projection (coarse MODE=0 / fine gather MODE=1)
// q/k/v out: [pair][tok][64]
template <int MODE>
__global__ __launch_bounds__(256) void k_qkv(
    const float* __restrict__ src, const float* __restrict__ wq,
    const float* __restrict__ bq, const int* __restrict__ topk,
    float* __restrict__ qout, float* __restrict__ kout, float* __restrict__ vout) {
  __shared__ float tokT[64][68];
  const int t = threadIdx.x;
  const int tok0 = blockIdx.x * 64;
  const int pair = blockIdx.y;
  const int b = pair >> 2, h = pair & 3;
  // load token tile: tokT[d][tl]
#pragma unroll
  for (int j = 0; j < 16; ++j) {
    int e = t + j * 256;
    int d = e >> 6, tl = e & 63;
    float v;
    if (MODE == 0) {
      v = src[((size_t)(b * 256 + h * 64 + d)) * 1024 + tok0 + tl];
    } else {
      int tok = tok0 + tl;
      int pp = topk[pair * 256 + (tok >> 2)];
      int py = (tok >> 1) & 1, px = tok & 1;
      int ry = (pp >> 5) * 2 + py, rx = (pp & 31) * 2 + px;
      v = src[((size_t)(b * 256 + h * 64 + d) * 64 + ry) * 64 + rx];
    }
    tokT[d][tl] = v;
  }
  __syncthreads();
  const int col_g = t & 15;   // 12 cols each
  const int tok_g = t >> 4;   // 4 toks each
  float acc[4][12] = {};
  for (int d = 0; d < 64; ++d) {
    float4 tv4 = *(const float4*)&tokT[d][tok_g * 4];
    const float* wr = wq + d * 192 + col_g * 12;
    float wv[12];
#pragma unroll
    for (int c = 0; c < 12; c += 4) {
      float4 w4 = *(const float4*)&wr[c];
      wv[c] = w4.x; wv[c + 1] = w4.y; wv[c + 2] = w4.z; wv[c + 3] = w4.w;
    }
    float tvv[4] = {tv4.x, tv4.y, tv4.z, tv4.w};
#pragma unroll
    for (int i = 0; i < 4; ++i)
#pragma unroll
      for (int c = 0; c < 12; ++c) acc[i][c] = fmaf(tvv[i], wv[c], acc[i][c]);
  }
#pragma unroll
  for (int i = 0; i < 4; ++i) {
    int tok = tok0 + tok_g * 4 + i;
#pragma unroll
    for (int c = 0; c < 12; ++c) {
      int col = col_g * 12 + c;
      float val = acc[i][c] + bq[col];
      float* dst = (col < 64) ? qout : ((col < 128) ? kout : vout);
      dst[((size_t)pair * 1024 + tok) * 64 + (col & 63)] = val;
    }
  }
}

// ---------------- K3: S = scale * q @ k^T, per slice of 16 pairs -----------
__global__ __launch_bounds__(256) void k_qk(
    const float* __restrict__ q, const float* __restrict__ kmat,
    float* __restrict__ S, int pair0) {
  __shared__ float Qt[64][68];
  __shared__ float Kt[64][68];
  const int t = threadIdx.x;
  const int k0 = blockIdx.x * 64, q0 = blockIdx.y * 64;
  const int lp = blockIdx.z;
  const int pair = pair0 + lp;
#pragma unroll
  for (int j = 0; j < 4; ++j) {
    int e = t * 4 + j * 1024;
    int d = e & 63, row = e >> 6;
    float4 qv = *(const float4*)&q[((size_t)pair * 1024 + q0 + row) * 64 + d];
    Qt[d + 0][row] = qv.x; Qt[d + 1][row] = qv.y; Qt[d + 2][row] = qv.z; Qt[d + 3][row] = qv.w;
    float4 kv = *(const float4*)&kmat[((size_t)pair * 1024 + k0 + row) * 64 + d];
    Kt[d + 0][row] = kv.x; Kt[d + 1][row] = kv.y; Kt[d + 2][row] = kv.z; Kt[d + 3][row] = kv.w;
  }
  __syncthreads();
  const int ty = t >> 4, tx = t & 15;
  float acc[4][4] = {};
#pragma unroll 8
  for (int d = 0; d < 64; ++d) {
    float4 a = *(const float4*)&Qt[d][ty * 4];
    float4 b = *(const float4*)&Kt[d][tx * 4];
    fma16(acc, a, b);
  }
#pragma unroll
  for (int i = 0; i < 4; ++i) {
    float4 o = make_float4(acc[i][0] * SCALE_, acc[i][1] * SCALE_,
                           acc[i][2] * SCALE_, acc[i][3] * SCALE_);
    *(float4*)&S[((size_t)lp * 1024 + q0 + ty * 4 + i) * 1024 + k0 + tx * 4] = o;
  }
}

// ---------------- K4: row softmax in place (rows of 1024) ------------------
__global__ __launch_bounds__(256) void k_softmax(float* __restrict__ S) {
  const int row = blockIdx.x;
  float* r = S + (size_t)row * 1024;
  const int t = threadIdx.x;
  __shared__ float red[4];
  __shared__ float bcast;
  float4 v = *(const float4*)&r[t * 4];
  float m = fmaxf(fmaxf(v.x, v.y), fmaxf(v.z, v.w));
#pragma unroll
  for (int off = 32; off > 0; off >>= 1) m = fmaxf(m, __shfl_down(m, off));
  if ((t & 63) == 0) red[t >> 6] = m;
  __syncthreads();
  if (t == 0) bcast = fmaxf(fmaxf(red[0], red[1]), fmaxf(red[2], red[3]));
  __syncthreads();
  m = bcast;
  v.x = __expf(v.x - m); v.y = __expf(v.y - m);
  v.z = __expf(v.z - m); v.w = __expf(v.w - m);
  float s = v.x + v.y + v.z + v.w;
#pragma unroll
  for (int off = 32; off > 0; off >>= 1) s += __shfl_down(s, off);
  __syncthreads();
  if ((t & 63) == 0) red[t >> 6] = s;
  __syncthreads();
  if (t == 0) bcast = red[0] + red[1] + red[2] + red[3];
  __syncthreads();
  float inv = 1.0f / bcast;
  v.x *= inv; v.y *= inv; v.z *= inv; v.w *= inv;
  *(float4*)&r[t * 4] = v;
}

// ---------------- K5: coarse_score[k] += sum_q attn[q][k] ------------------
__global__ __launch_bounds__(256) void k_score(
    const float* __restrict__ S, float* __restrict__ score, int pair0) {
  const int t = threadIdx.x;
  const int kbase = blockIdx.x * 256;
  const int qc = blockIdx.y;
  const int lp = blockIdx.z;
  float s = 0.f;
  const float* base = S + ((size_t)lp * 1024 + qc * 128) * 1024 + kbase + t;
  for (int qq = 0; qq < 128; ++qq) s += base[(size_t)qq * 1024];
  atomicAdd(&score[(pair0 + lp) * 1024 + kbase + t], s);
}

// ---------------- K6: per-pair top-256 via bitonic sort --------------------
__global__ __launch_bounds__(256) void k_topk(
    const float* __restrict__ score, int* __restrict__ idx) {
  __shared__ unsigned long long key[1024];
  const int pair = blockIdx.x;
  const int t = threadIdx.x;
#pragma unroll
  for (int j = 0; j < 4; ++j) {
    int i = t + j * 256;
    unsigned u = __float_as_uint(score[pair * 1024 + i]);
    u = u ^ ((u & 0x80000000u) ? 0xFFFFFFFFu : 0x80000000u);  // ascending map
    u = ~u;                                                    // descending
    key[i] = ((unsigned long long)u << 32) | (unsigned)i;
  }
  __syncthreads();
  for (int k = 2; k <= 1024; k <<= 1) {
    for (int j = k >> 1; j > 0; j >>= 1) {
      for (int w = 0; w < 4; ++w) {
        int i = t + w * 256;
        int l = i ^ j;
        if (l > i) {
          bool up = ((i & k) == 0);
          unsigned long long a = key[i], b = key[l];
          if ((a > b) == up) { key[i] = b; key[l] = a; }
        }
      }
      __syncthreads();
    }
  }
  idx[pair * 256 + t] = (int)(key[t] & 0xFFFFFFFFu);
}

// ---------------- K7: out = attn @ v. STORE_CHW: [b][c][32][32]; else [pair][tok][d]
template <int STORE_CHW>
__global__ __launch_bounds__(256) void k_av(
    const float* __restrict__ S, const float* __restrict__ v,
    float* __restrict__ out, int pair0) {
  __shared__ float St[64][68];
  __shared__ float Vs[64][68];
  const int t = threadIdx.x;
  const int q0 = blockIdx.x * 64;
  const int lp = blockIdx.y;
  const int pair = pair0 + lp;
  const int ty = t >> 4, tx = t & 15;
  float acc[4][4] = {};
  for (int kc = 0; kc < 16; ++kc) {
    int kb = kc * 64;
#pragma unroll
    for (int j = 0; j < 4; ++j) {
      int e = t * 4 + j * 1024;
      int cc = e & 63, row = e >> 6;
      float4 sv = *(const float4*)&S[((size_t)lp * 1024 + q0 + row) * 1024 + kb + cc];
      St[cc + 0][row] = sv.x; St[cc + 1][row] = sv.y; St[cc + 2][row] = sv.z; St[cc + 3][row] = sv.w;
      float4 vv = *(const float4*)&v[((size_t)pair * 1024 + kb + row) * 64 + cc];
      *(float4*)&Vs[row][cc] = vv;
    }
    __syncthreads();
#pragma unroll 8
    for (int kk = 0; kk < 64; ++kk) {
      float4 a = *(const float4*)&St[kk][ty * 4];
      float4 b = *(const float4*)&Vs[kk][tx * 4];
      fma16(acc, a, b);
    }
    __syncthreads();
  }
  if (STORE_CHW) {
    // bounce through LDS to store [b][h*64+d][p] coalesced
#pragma unroll
    for (int i = 0; i < 4; ++i)
#pragma unroll
      for (int j = 0; j < 4; ++j) St[tx * 4 + j][ty * 4 + i] = acc[i][j];
    __syncthreads();
    const int b = pair >> 2, h = pair & 3;
#pragma unroll
    for (int j2 = 0; j2 < 16; ++j2) {
      int e = t + j2 * 256;
      int d = e >> 6, ql = e & 63;
      out[((size_t)(b * 256 + h * 64 + d)) * 1024 + q0 + ql] = St[d][ql];
    }
  } else {
#pragma unroll
    for (int i = 0; i < 4; ++i) {
      int tok = q0 + ty * 4 + i;
      float4 o = make_float4(acc[i][0], acc[i][1], acc[i][2], acc[i][3]);
      *(float4*)&out[((size_t)pair * 1024 + tok) * 64 + tx * 4] = o;
    }
  }
}

// ---------------- K8a: repack w_up -> wt[class][k=ic*4+tap][oc] ------------
__global__ __launch_bounds__(256) void k_repack_wup(
    const float* __restrict__ w_up, float* __restrict__ wt) {
  int e = blockIdx.x * 256 + threadIdx.x;  // 4*1024*256 = 2^20
  int oc = e & 255;
  int kidx = (e >> 8) & 1023;
  int c = e >> 18;
  int ic = kidx >> 2, tap = kidx & 3, tk = tap >> 1, txi = tap & 1;
  int ry = c >> 1, rx = c & 1;
  int ky = (1 - ry) + 2 * tk, kx = (1 - rx) + 2 * txi;
  wt[e] = w_up[((size_t)(ic * 256 + oc) * 4 + ky) * 4 + kx];
}

// ---------------- K8: ConvTranspose k4 s2 p1 as 4 parity-class GEMMs -------
__global__ __launch_bounds__(256) void k_convT(
    const float* __restrict__ in,   // [b][c][32][32]
    const float* __restrict__ wt,   // [class][k][oc]
    const float* __restrict__ bias, float* __restrict__ out) {  // [b][c][64][64]
  __shared__ float As[16][68];
  __shared__ float Bs[16][68];
  const int t = threadIdx.x;
  const int pix0 = blockIdx.x * 64;
  const int oc0 = blockIdx.y * 64;
  const int c = blockIdx.z;
  const int ry = c >> 1, rx = c & 1;
  const int bimg = pix0 >> 10;
  const int ty = t >> 4, tx = t & 15;
  float acc[4][4] = {};
  for (int kc = 0; kc < 64; ++kc) {
    int k0 = kc * 16;
#pragma unroll
    for (int j = 0; j < 4; ++j) {
      int e = t + j * 256;
      int ocl = e & 63, kk = e >> 6;
      As[kk][ocl] = wt[((size_t)(c << 10) + k0 + kk) * 256 + oc0 + ocl];
      int pl = ocl;
      int pix = pix0 + pl;
      int rem = pix & 1023;
      int tyy = rem >> 5, txx = rem & 31;
      int k = k0 + kk;
      int ic = k >> 2, tap = k & 3, tk = tap >> 1, txi = tap & 1;
      int iy = tyy + ry - tk, ix = txx + rx - txi;
      float vv = 0.f;
      if (iy >= 0 && iy < 32 && ix >= 0 && ix < 32)
        vv = in[((size_t)(bimg * 256 + ic) * 32 + iy) * 32 + ix];
      Bs[kk][pl] = vv;
    }
    __syncthreads();
#pragma unroll
    for (int kk = 0; kk < 16; ++kk) {
      float4 a = *(const float4*)&As[kk][ty * 4];
      float4 b = *(const float4*)&Bs[kk][tx * 4];
      fma16(acc, a, b);
    }
    __syncthreads();
  }
#pragma unroll
  for (int i = 0; i < 4; ++i) {
    int oc = oc0 + ty * 4 + i;
    float bv = bias[oc];
#pragma unroll
    for (int j = 0; j < 4; ++j) {
      int pix = pix0 + tx * 4 + j;
      int rem = pix & 1023;
      int tyy = rem >> 5, txx = rem & 31;
      int y = tyy * 2 + ry, xx = txx * 2 + rx;
      out[((size_t)(bimg * 256 + oc) * 64 + y) * 64 + xx] = acc[i][j] + bv;
    }
  }
}

// ---------------- K11: scatter-add fine outputs into y (coarse buf) --------
__global__ __launch_bounds__(256) void k_scatter(
    const float* __restrict__ outf, const int* __restrict__ idx,
    float* __restrict__ y) {
  int g = blockIdx.x * 256 + threadIdx.x;  // 32*1024*64
  int pair = g >> 16;
  int rem = g & 65535;
  int tok = rem >> 6, d = rem & 63;
  int b = pair >> 2, h = pair & 3;
  int pp = idx[pair * 256 + (tok >> 2)];
  int py = (tok >> 1) & 1, px = tok & 1;
  int ry = (pp >> 5) * 2 + py, rx = (pp & 31) * 2 + px;
  y[((size_t)(b * 256 + h * 64 + d) * 64 + ry) * 64 + rx] += outf[g];
}

// ---------------- K12: depthwise 3x3 + BN + relu6 --------------------------
__global__ __launch_bounds__(256) void k_dwconv(
    const float* __restrict__ y, const float* __restrict__ wdw,
    const float* __restrict__ g, const float* __restrict__ bb,
    const float* __restrict__ m, const float* __restrict__ vv,
    float* __restrict__ yd) {
  int gi = blockIdx.x * 256 + threadIdx.x;  // 8*256*64*64
  int x = gi & 63, yy = (gi >> 6) & 63, ch = (gi >> 12) & 255, b = gi >> 20;
  const float* plane = y + (size_t)(b * 256 + ch) * 4096;
  const float* wc = wdw + ch * 9;
  float s = 0.f;
#pragma unroll
  for (int ky = 0; ky < 3; ++ky) {
    int iy = yy + ky - 1;
    if (iy < 0 || iy >= 64) continue;
#pragma unroll
    for (int kx = 0; kx < 3; ++kx) {
      int ix = x + kx - 1;
      if (ix < 0 || ix >= 64) continue;
      s = fmaf(plane[iy * 64 + ix], wc[ky * 3 + kx], s);
    }
  }
  float sc = g[ch] * rsqrtf(vv[ch] + EPS_);
  float val = s * sc + (bb[ch] - m[ch] * sc);
  yd[gi] = fminf(fmaxf(val, 0.f), 6.f);
}

// ---------------- K13: pointwise 1x1 GEMM + BN + relu6 ---------------------
__global__ __launch_bounds__(256) void k_pw(
    const float* __restrict__ yd, const float* __restrict__ w,
    const float* __restrict__ g, const float* __restrict__ bb,
    const float* __restrict__ m, const float* __restrict__ vv,
    float* __restrict__ out) {
  __shared__ float As[32][68];
  __shared__ float Bs[32][68];
  const int t = threadIdx.x;
  const int pix0 = blockIdx.x * 64;  // 32768 pixels total
  const int oc0 = blockIdx.y * 64;
  const int ty = t >> 4, tx = t & 15;
  const int bimg = pix0 >> 12, pos = pix0 & 4095;
  float acc[4][4] = {};
  for (int kc = 0; kc < 8; ++kc) {
    int ic0 = kc * 32;
#pragma unroll
    for (int j = 0; j < 2; ++j) {
      int e = t * 4 + j * 1024;
      int icl = e & 31, ocl = e >> 5;
      float4 wv = *(const float4*)&w[(size_t)(oc0 + ocl) * 256 + ic0 + icl];
      As[icl + 0][ocl] = wv.x; As[icl + 1][ocl] = wv.y;
      As[icl + 2][ocl] = wv.z; As[icl + 3][ocl] = wv.w;
      int pixl = e & 63, icl2 = e >> 6;
      float4 bv = *(const float4*)&yd[(size_t)(bimg * 256 + ic0 + icl2) * 4096 + pos + pixl];
      *(float4*)&Bs[icl2][pixl] = bv;
    }
    __syncthreads();
#pragma unroll 8
    for (int kk = 0; kk < 32; ++kk) {
      float4 a = *(const float4*)&As[kk][ty * 4];
      float4 b = *(const float4*)&Bs[kk][tx * 4];
      fma16(acc, a, b);
    }
    __syncthreads();
  }
#pragma unroll
  for (int i = 0; i < 4; ++i) {
    int oc = oc0 + ty * 4 + i;
    float sc = g[oc] * rsqrtf(vv[oc] + EPS_);
    float off = bb[oc] - m[oc] * sc;
    float4 o;
    o.x = fminf(fmaxf(acc[i][0] * sc + off, 0.f), 6.f);
    o.y = fminf(fmaxf(acc[i][1] * sc + off, 0.f), 6.f);
    o.z = fminf(fmaxf(acc[i][2] * sc + off, 0.f), 6.f);
    o.w = fminf(fmaxf(acc[i][3] * sc + off, 0.f), 6.f);
    *(float4*)&out[(size_t)(bimg * 256 + oc) * 4096 + pos + tx * 4] = o;
  }
}

// ---------------------------------------------------------------------------
extern "C" void kernel_launch(void* const* d_in, const int* in_sizes, int n_in,
                              void* d_out, int out_size, void* d_ws, size_t ws_size,
                              hipStream_t stream) {
  (void)in_sizes; (void)n_in; (void)out_size; (void)ws_size;
  const float* x       = (const float*)d_in[0];
  const float* w_down  = (const float*)d_in[1];
  const float* b_down  = (const float*)d_in[2];
  const float* w_qkv_c = (const float*)d_in[3];
  const float* b_qkv_c = (const float*)d_in[4];
  const float* w_up    = (const float*)d_in[5];
  const float* b_up    = (const float*)d_in[6];
  const float* w_qkv_f = (const float*)d_in[7];
  const float* b_qkv_f = (const float*)d_in[8];
  const float* w_dw    = (const float*)d_in[9];
  const float* bn_dw_g = (const float*)d_in[10];
  const float* bn_dw_b = (const float*)d_in[11];
  const float* bn_dw_m = (const float*)d_in[12];
  const float* bn_dw_v = (const float*)d_in[13];
  const float* w_pw    = (const float*)d_in[14];
  const float* bn_pw_g = (const float*)d_in[15];
  const float* bn_pw_b = (const float*)d_in[16];
  const float* bn_pw_m = (const float*)d_in[17];
  const float* bn_pw_v = (const float*)d_in[18];

  // workspace layout (floats); total ~38.9M floats (~156 MB)
  float* ws = (float*)d_ws;
  float* S      = ws;                      // 16*1024*1024 = 16,777,216 (attn slice; later yd)
  float* qb     = ws + 16777216;           // 2,097,152
  float* kb     = qb + 2097152;
  float* vb     = kb + 2097152;
  float* xd     = vb + 2097152;
  float* outc   = xd + 2097152;            // coarse attn out [b][c][32][32]
  float* coarse = outc + 2097152;          // 8,388,608 [b][c][64][64] -> becomes y
  float* outf   = coarse + 8388608;        // 2,097,152
  float* score  = outf + 2097152;          // 32,768
  float* wupt   = score + 32768;           // 1,048,576
  int*   idx    = (int*)(wupt + 1048576);  // 8,192 ints
  float* yd     = S;                       // reuse after fine attention

  hipMemsetAsync(score, 0, 32768 * sizeof(float), stream);
  k_repack_wup<<<4096, 256, 0, stream>>>(w_up, wupt);
  k_conv_down<<<dim3(128, 4), 256, 0, stream>>>(x, w_down, b_down, xd);
  k_qkv<0><<<dim3(16, 32), 256, 0, stream>>>(xd, w_qkv_c, b_qkv_c, nullptr, qb, kb, vb);

  // coarse attention, 2 slices of 16 pairs
  for (int s = 0; s < 2; ++s) {
    int pair0 = s * 16;
    k_qk<<<dim3(16, 16, 16), 256, 0, stream>>>(qb, kb, S, pair0);
    k_softmax<<<16384, 256, 0, stream>>>(S);
    k_score<<<dim3(4, 8, 16), 256, 0, stream>>>(S, score, pair0);
    k_av<1><<<dim3(16, 16), 256, 0, stream>>>(S, vb, outc, pair0);
  }
  k_topk<<<32, 256, 0, stream>>>(score, idx);
  k_convT<<<dim3(128, 4, 4), 256, 0, stream>>>(outc, wupt, b_up, coarse);

  // fine attention (reuses q/k/v buffers and S)
  k_qkv<1><<<dim3(16, 32), 256, 0, stream>>>(coarse, w_qkv_f, b_qkv_f, idx, qb, kb, vb);
  for (int s = 0; s < 2; ++s) {
    int pair0 = s * 16;
    k_qk<<<dim3(16, 16, 16), 256, 0, stream>>>(qb, kb, S, pair0);
    k_softmax<<<16384, 256, 0, stream>>>(S);
    k_av<0><<<dim3(16, 16), 256, 0, stream>>>(S, vb, outf, pair0);
  }
  k_scatter<<<8192, 256, 0, stream>>>(outf, idx, coarse);
  k_dwconv<<<32768, 256, 0, stream>>>(coarse, w_dw, bn_dw_g, bn_dw_b, bn_dw_m, bn_dw_v, yd);
  k_pw<<<dim3(512, 4), 256, 0, stream>>>(yd, w_pw, bn_pw_g, bn_pw_b, bn_pw_m, bn_pw_v, (float*)d_out);
}

// Round 2
// 1306.013 us; speedup vs baseline: 1.2507x; 1.2507x over previous
//
#include <hip/hip_runtime.h>
#include <cstdint>
#include <cstddef>

// ---------------------------------------------------------------------------
// RegionSelectionAttention fp32. Round 2: restructured conv GEMMs.
// B=8, C=256, NH=4, HD=64, H=W=64, coarse 32x32 (P=1024), kf=256.
// Score path (down-conv -> q,k -> QK^T -> softmax -> colsum -> top-k) stays
// fp32: order-statistic gaps at the 256/257 boundary are ~1e-3.
// ---------------------------------------------------------------------------

#define SCALE_ 0.125f  // HD^-0.5
#define EPS_ 1e-5f

__device__ __forceinline__ void fma16(float (&acc)[4][4], const float4 a, const float4 b) {
  acc[0][0] = fmaf(a.x, b.x, acc[0][0]); acc[0][1] = fmaf(a.x, b.y, acc[0][1]);
  acc[0][2] = fmaf(a.x, b.z, acc[0][2]); acc[0][3] = fmaf(a.x, b.w, acc[0][3]);
  acc[1][0] = fmaf(a.y, b.x, acc[1][0]); acc[1][1] = fmaf(a.y, b.y, acc[1][1]);
  acc[1][2] = fmaf(a.y, b.z, acc[1][2]); acc[1][3] = fmaf(a.y, b.w, acc[1][3]);
  acc[2][0] = fmaf(a.z, b.x, acc[2][0]); acc[2][1] = fmaf(a.z, b.y, acc[2][1]);
  acc[2][2] = fmaf(a.z, b.z, acc[2][2]); acc[2][3] = fmaf(a.z, b.w, acc[2][3]);
  acc[3][0] = fmaf(a.w, b.x, acc[3][0]); acc[3][1] = fmaf(a.w, b.y, acc[3][1]);
  acc[3][2] = fmaf(a.w, b.z, acc[3][2]); acc[3][3] = fmaf(a.w, b.w, acc[3][3]);
}

// ---------------- pad x -> xp[plane][66][66] (zero border) -----------------
__global__ __launch_bounds__(256) void k_pad_x(
    const float* __restrict__ x, float* __restrict__ xp) {
  const int plane = blockIdx.x;  // 2048
  const float* src = x + (size_t)plane * 4096;
  float* dst = xp + (size_t)plane * 4356;
  for (int e = threadIdx.x; e < 4356; e += 256) {
    int r = e / 66, cc = e - r * 66;
    float v = 0.f;
    if (r >= 1 && r <= 64 && cc >= 1 && cc <= 64) v = src[(r - 1) * 64 + (cc - 1)];
    dst[e] = v;
  }
}

// ---------------- repack w_down[oc][4096] -> wdt[k][oc] --------------------
__global__ __launch_bounds__(256) void k_repack_wdt(
    const float* __restrict__ w, float* __restrict__ wdt) {
  int e = blockIdx.x * 256 + threadIdx.x;  // 1048576
  int k = e & 4095, oc = e >> 12;
  wdt[(size_t)k * 256 + oc] = w[e];
}

// ---------------- K1: downsample conv k4 s2 p1, split-K z=2 ----------------
// out xdp[z][b][oc][1024] (no bias; bias+sum fused in k_qkv<0>)
__global__ __launch_bounds__(256) void k_conv_down(
    const float* __restrict__ xp, const float* __restrict__ wdt,
    float* __restrict__ xdp) {
  __shared__ float As[64][68];
  __shared__ float Bs[64][68];
  const int t = threadIdx.x;
  const int pix0 = blockIdx.x * 64;
  const int oc0 = blockIdx.y * 64;
  const int z = blockIdx.z;  // ic half
  const int bimg = pix0 >> 10, pos = pix0 & 1023;
  const int ty = t >> 4, tx = t & 15;
  // B staging geometry (hoisted): thread covers pixel pl for 1 of 4 ics
  const int pl = t & 63, icl = t >> 6;
  const int rem = (pix0 + pl) & 1023;
  const int oy = rem >> 5, ox = rem & 31;
  const float* xb = xp + ((size_t)(bimg * 256 + z * 128 + icl)) * 4356 + (oy * 2) * 66 + ox * 2;
  // A staging geometry: row akk, 16-col chunk
  const int akk = t >> 2, ac0 = (t & 3) * 16;
  const float* wr = wdt + ((size_t)(z * 2048 + akk)) * 256 + oc0 + ac0;

  float acc[4][4] = {};
  for (int ch = 0; ch < 32; ++ch) {
    float4 w0 = *(const float4*)(wr + 0);
    float4 w1 = *(const float4*)(wr + 4);
    float4 w2 = *(const float4*)(wr + 8);
    float4 w3 = *(const float4*)(wr + 12);
    float bv[16];
#pragma unroll
    for (int tap = 0; tap < 16; ++tap)
      bv[tap] = xb[(tap >> 2) * 66 + (tap & 3)];
    __syncthreads();
    *(float4*)&As[akk][ac0 + 0] = w0;
    *(float4*)&As[akk][ac0 + 4] = w1;
    *(float4*)&As[akk][ac0 + 8] = w2;
    *(float4*)&As[akk][ac0 + 12] = w3;
#pragma unroll
    for (int tap = 0; tap < 16; ++tap) Bs[icl * 16 + tap][pl] = bv[tap];
    __syncthreads();
#pragma unroll
    for (int kk = 0; kk < 64; ++kk) {
      float4 a = *(const float4*)&As[kk][ty * 4];
      float4 b = *(const float4*)&Bs[kk][tx * 4];
      fma16(acc, a, b);
    }
    __syncthreads();
    wr += 64 * 256;
    xb += 4 * 4356;
  }
  float* outp = xdp + ((size_t)z * 8 + bimg) * 256 * 1024;
#pragma unroll
  for (int i = 0; i < 4; ++i) {
    int oc = oc0 + ty * 4 + i;
    *(float4*)&outp[(size_t)oc * 1024 + pos + tx * 4] =
        make_float4(acc[i][0], acc[i][1], acc[i][2], acc[i][3]);
  }
}

// ---------------- K2/K9: qkv projection ------------------------------------
// MODE 0: coarse, src = xdp half0, src2 = half1, cbias = b_down (fused sum)
// MODE 1: fine gather from coarse via topk
template <int MODE>
__global__ __launch_bounds__(256) void k_qkv(
    const float* __restrict__ src, const float* __restrict__ src2,
    const float* __restrict__ cbias, const float* __restrict__ wq,
    const float* __restrict__ bq, const int* __restrict__ topk,
    float* __restrict__ qout, float* __restrict__ kout, float* __restrict__ vout) {
  __shared__ float tokT[64][68];
  const int t = threadIdx.x;
  const int tok0 = blockIdx.x * 64;
  const int pair = blockIdx.y;
  const int b = pair >> 2, h = pair & 3;
#pragma unroll
  for (int j = 0; j < 16; ++j) {
    int e = t + j * 256;
    int d = e >> 6, tl = e & 63;
    float v;
    if (MODE == 0) {
      size_t i = ((size_t)(b * 256 + h * 64 + d)) * 1024 + tok0 + tl;
      v = src[i] + src2[i] + cbias[h * 64 + d];
    } else {
      int tok = tok0 + tl;
      int pp = topk[pair * 256 + (tok >> 2)];
      int py = (tok >> 1) & 1, px = tok & 1;
      int ry = (pp >> 5) * 2 + py, rx = (pp & 31) * 2 + px;
      v = src[((size_t)(b * 256 + h * 64 + d) * 64 + ry) * 64 + rx];
    }
    tokT[d][tl] = v;
  }
  __syncthreads();
  const int col_g = t & 15;
  const int tok_g = t >> 4;
  float acc[4][12] = {};
  for (int d = 0; d < 64; ++d) {
    float4 tv4 = *(const float4*)&tokT[d][tok_g * 4];
    const float* wr = wq + d * 192 + col_g * 12;
    float wv[12];
#pragma unroll
    for (int c = 0; c < 12; c += 4) {
      float4 w4 = *(const float4*)&wr[c];
      wv[c] = w4.x; wv[c + 1] = w4.y; wv[c + 2] = w4.z; wv[c + 3] = w4.w;
    }
    float tvv[4] = {tv4.x, tv4.y, tv4.z, tv4.w};
#pragma unroll
    for (int i = 0; i < 4; ++i)
#pragma unroll
      for (int c = 0; c < 12; ++c) acc[i][c] = fmaf(tvv[i], wv[c], acc[i][c]);
  }
#pragma unroll
  for (int i = 0; i < 4; ++i) {
    int tok = tok0 + tok_g * 4 + i;
#pragma unroll
    for (int c = 0; c < 12; ++c) {
      int col = col_g * 12 + c;
      float val = acc[i][c] + bq[col];
      float* dst = (col < 64) ? qout : ((col < 128) ? kout : vout);
      dst[((size_t)pair * 1024 + tok) * 64 + (col & 63)] = val;
    }
  }
}

// ---------------- K3: S = scale * q @ k^T ----------------------------------
__global__ __launch_bounds__(256) void k_qk(
    const float* __restrict__ q, const float* __restrict__ kmat,
    float* __restrict__ S, int pair0) {
  __shared__ float Qt[64][68];
  __shared__ float Kt[64][68];
  const int t = threadIdx.x;
  const int k0 = blockIdx.x * 64, q0 = blockIdx.y * 64;
  const int lp = blockIdx.z;
  const int pair = pair0 + lp;
#pragma unroll
  for (int j = 0; j < 4; ++j) {
    int e = t * 4 + j * 1024;
    int d = e & 63, row = e >> 6;
    float4 qv = *(const float4*)&q[((size_t)pair * 1024 + q0 + row) * 64 + d];
    Qt[d + 0][row] = qv.x; Qt[d + 1][row] = qv.y; Qt[d + 2][row] = qv.z; Qt[d + 3][row] = qv.w;
    float4 kv = *(const float4*)&kmat[((size_t)pair * 1024 + k0 + row) * 64 + d];
    Kt[d + 0][row] = kv.x; Kt[d + 1][row] = kv.y; Kt[d + 2][row] = kv.z; Kt[d + 3][row] = kv.w;
  }
  __syncthreads();
  const int ty = t >> 4, tx = t & 15;
  float acc[4][4] = {};
#pragma unroll 8
  for (int d = 0; d < 64; ++d) {
    float4 a = *(const float4*)&Qt[d][ty * 4];
    float4 b = *(const float4*)&Kt[d][tx * 4];
    fma16(acc, a, b);
  }
#pragma unroll
  for (int i = 0; i < 4; ++i) {
    float4 o = make_float4(acc[i][0] * SCALE_, acc[i][1] * SCALE_,
                           acc[i][2] * SCALE_, acc[i][3] * SCALE_);
    *(float4*)&S[((size_t)lp * 1024 + q0 + ty * 4 + i) * 1024 + k0 + tx * 4] = o;
  }
}

// ---------------- K4: row softmax in place ---------------------------------
__global__ __launch_bounds__(256) void k_softmax(float* __restrict__ S) {
  const int row = blockIdx.x;
  float* r = S + (size_t)row * 1024;
  const int t = threadIdx.x;
  __shared__ float red[4];
  __shared__ float bcast;
  float4 v = *(const float4*)&r[t * 4];
  float m = fmaxf(fmaxf(v.x, v.y), fmaxf(v.z, v.w));
#pragma unroll
  for (int off = 32; off > 0; off >>= 1) m = fmaxf(m, __shfl_down(m, off));
  if ((t & 63) == 0) red[t >> 6] = m;
  __syncthreads();
  if (t == 0) bcast = fmaxf(fmaxf(red[0], red[1]), fmaxf(red[2], red[3]));
  __syncthreads();
  m = bcast;
  v.x = __expf(v.x - m); v.y = __expf(v.y - m);
  v.z = __expf(v.z - m); v.w = __expf(v.w - m);
  float s = v.x + v.y + v.z + v.w;
#pragma unroll
  for (int off = 32; off > 0; off >>= 1) s += __shfl_down(s, off);
  __syncthreads();
  if ((t & 63) == 0) red[t >> 6] = s;
  __syncthreads();
  if (t == 0) bcast = red[0] + red[1] + red[2] + red[3];
  __syncthreads();
  float inv = 1.0f / bcast;
  v.x *= inv; v.y *= inv; v.z *= inv; v.w *= inv;
  *(float4*)&r[t * 4] = v;
}

// ---------------- K5: coarse_score[k] += sum_q attn[q][k] ------------------
__global__ __launch_bounds__(256) void k_score(
    const float* __restrict__ S, float* __restrict__ score, int pair0) {
  const int t = threadIdx.x;
  const int kbase = blockIdx.x * 256;
  const int qc = blockIdx.y;
  const int lp = blockIdx.z;
  float s = 0.f;
  const float* base = S + ((size_t)lp * 1024 + qc * 128) * 1024 + kbase + t;
  for (int qq = 0; qq < 128; ++qq) s += base[(size_t)qq * 1024];
  atomicAdd(&score[(pair0 + lp) * 1024 + kbase + t], s);
}

// ---------------- K6: per-pair top-256 via bitonic sort --------------------
__global__ __launch_bounds__(256) void k_topk(
    const float* __restrict__ score, int* __restrict__ idx) {
  __shared__ unsigned long long key[1024];
  const int pair = blockIdx.x;
  const int t = threadIdx.x;
#pragma unroll
  for (int j = 0; j < 4; ++j) {
    int i = t + j * 256;
    unsigned u = __float_as_uint(score[pair * 1024 + i]);
    u = u ^ ((u & 0x80000000u) ? 0xFFFFFFFFu : 0x80000000u);
    u = ~u;
    key[i] = ((unsigned long long)u << 32) | (unsigned)i;
  }
  __syncthreads();
  for (int k = 2; k <= 1024; k <<= 1) {
    for (int j = k >> 1; j > 0; j >>= 1) {
      for (int w = 0; w < 4; ++w) {
        int i = t + w * 256;
        int l = i ^ j;
        if (l > i) {
          bool up = ((i & k) == 0);
          unsigned long long a = key[i], b = key[l];
          if ((a > b) == up) { key[i] = b; key[l] = a; }
        }
      }
      __syncthreads();
    }
  }
  idx[pair * 256 + t] = (int)(key[t] & 0xFFFFFFFFu);
}

// ---------------- K7: out = attn @ v ---------------------------------------
// STORE_PAD: write padded [b][c][34][34] (for convT); else [pair][tok][d]
template <int STORE_PAD>
__global__ __launch_bounds__(256) void k_av(
    const float* __restrict__ S, const float* __restrict__ v,
    float* __restrict__ out, int pair0) {
  __shared__ float St[64][68];
  __shared__ float Vs[64][68];
  const int t = threadIdx.x;
  const int q0 = blockIdx.x * 64;
  const int lp = blockIdx.y;
  const int pair = pair0 + lp;
  const int ty = t >> 4, tx = t & 15;
  float acc[4][4] = {};
  for (int kc = 0; kc < 16; ++kc) {
    int kb = kc * 64;
#pragma unroll
    for (int j = 0; j < 4; ++j) {
      int e = t * 4 + j * 1024;
      int cc = e & 63, row = e >> 6;
      float4 sv = *(const float4*)&S[((size_t)lp * 1024 + q0 + row) * 1024 + kb + cc];
      St[cc + 0][row] = sv.x; St[cc + 1][row] = sv.y; St[cc + 2][row] = sv.z; St[cc + 3][row] = sv.w;
      float4 vv = *(const float4*)&v[((size_t)pair * 1024 + kb + row) * 64 + cc];
      *(float4*)&Vs[row][cc] = vv;
    }
    __syncthreads();
#pragma unroll 8
    for (int kk = 0; kk < 64; ++kk) {
      float4 a = *(const float4*)&St[kk][ty * 4];
      float4 b = *(const float4*)&Vs[kk][tx * 4];
      fma16(acc, a, b);
    }
    __syncthreads();
  }
  if (STORE_PAD) {
#pragma unroll
    for (int i = 0; i < 4; ++i)
#pragma unroll
      for (int j = 0; j < 4; ++j) St[tx * 4 + j][ty * 4 + i] = acc[i][j];
    __syncthreads();
    const int b = pair >> 2, h = pair & 3;
#pragma unroll
    for (int j2 = 0; j2 < 16; ++j2) {
      int e = t + j2 * 256;
      int d = e >> 6, ql = e & 63;
      int pix = q0 + ql;
      int tyy = pix >> 5, txx = pix & 31;
      out[((size_t)(b * 256 + h * 64 + d)) * 1156 + (tyy + 1) * 34 + (txx + 1)] = St[d][ql];
    }
  } else {
#pragma unroll
    for (int i = 0; i < 4; ++i) {
      int tok = q0 + ty * 4 + i;
      float4 o = make_float4(acc[i][0], acc[i][1], acc[i][2], acc[i][3]);
      *(float4*)&out[((size_t)pair * 1024 + tok) * 64 + tx * 4] = o;
    }
  }
}

// ---------------- K8a: repack w_up -> wt[class][k=ic*4+tap][oc] ------------
__global__ __launch_bounds__(256) void k_repack_wup(
    const float* __restrict__ w_up, float* __restrict__ wt) {
  int e = blockIdx.x * 256 + threadIdx.x;  // 4*1024*256 = 2^20
  int oc = e & 255;
  int kidx = (e >> 8) & 1023;
  int c = e >> 18;
  int ic = kidx >> 2, tap = kidx & 3, tk = tap >> 1, txi = tap & 1;
  int ry = c >> 1, rx = c & 1;
  int ky = (1 - ry) + 2 * tk, kx = (1 - rx) + 2 * txi;
  wt[e] = w_up[((size_t)(ic * 256 + oc) * 4 + ky) * 4 + kx];
}

// ---------------- K8: ConvTranspose k4 s2 p1 as 4 parity-class GEMMs -------
__global__ __launch_bounds__(256) void k_convT(
    const float* __restrict__ inp,  // padded [b][c][34][34]
    const float* __restrict__ wt,   // [class][k][oc]
    const float* __restrict__ bias, float* __restrict__ out) {  // [b][c][64][64]
  __shared__ float As[64][68];
  __shared__ float Bs[64][68];
  const int t = threadIdx.x;
  const int pix0 = blockIdx.x * 64;
  const int oc0 = blockIdx.y * 64;
  const int c = blockIdx.z;
  const int ry = c >> 1, rx = c & 1;
  const int bimg = pix0 >> 10;
  const int ty = t >> 4, tx = t & 15;
  const int pl = t & 63, ig = t >> 6;
  const int rem = (pix0 + pl) & 1023;
  const int tyy = rem >> 5, txx = rem & 31;
  const float* xb = inp + ((size_t)(bimg * 256 + ig * 4)) * 1156 +
                    (tyy + ry + 1) * 34 + (txx + rx + 1);
  const int akk = t >> 2, ac0 = (t & 3) * 16;
  const float* wr = wt + ((size_t)c * 1024 + akk) * 256 + oc0 + ac0;
  float acc[4][4] = {};
  for (int ch = 0; ch < 16; ++ch) {
    float4 w0 = *(const float4*)(wr + 0);
    float4 w1 = *(const float4*)(wr + 4);
    float4 w2 = *(const float4*)(wr + 8);
    float4 w3 = *(const float4*)(wr + 12);
    float bv[16];
#pragma unroll
    for (int i = 0; i < 4; ++i) {
      const float* p = xb + (size_t)i * 1156;
      bv[i * 4 + 0] = p[0];
      bv[i * 4 + 1] = p[-1];
      bv[i * 4 + 2] = p[-34];
      bv[i * 4 + 3] = p[-35];
    }
    __syncthreads();
    *(float4*)&As[akk][ac0 + 0] = w0;
    *(float4*)&As[akk][ac0 + 4] = w1;
    *(float4*)&As[akk][ac0 + 8] = w2;
    *(float4*)&As[akk][ac0 + 12] = w3;
#pragma unroll
    for (int i = 0; i < 16; ++i) Bs[ig * 16 + i][pl] = bv[i];
    __syncthreads();
#pragma unroll
    for (int kk = 0; kk < 64; ++kk) {
      float4 a = *(const float4*)&As[kk][ty * 4];
      float4 b = *(const float4*)&Bs[kk][tx * 4];
      fma16(acc, a, b);
    }
    __syncthreads();
    wr += 64 * 256;
    xb += 16 * 1156;
  }
#pragma unroll
  for (int i = 0; i < 4; ++i) {
    int oc = oc0 + ty * 4 + i;
    float bvs = bias[oc];
#pragma unroll
    for (int j = 0; j < 4; ++j) {
      int pix = pix0 + tx * 4 + j;
      int rem2 = pix & 1023;
      int ty2 = rem2 >> 5, tx2 = rem2 & 31;
      int y = ty2 * 2 + ry, xx = tx2 * 2 + rx;
      out[((size_t)(bimg * 256 + oc) * 64 + y) * 64 + xx] = acc[i][j] + bvs;
    }
  }
}

// ---------------- K11: scatter-add fine outputs into y ---------------------
__global__ __launch_bounds__(256) void k_scatter(
    const float* __restrict__ outf, const int* __restrict__ idx,
    float* __restrict__ y) {
  int g = blockIdx.x * 256 + threadIdx.x;  // 32*1024*64
  int pair = g >> 16;
  int rem = g & 65535;
  int tok = rem >> 6, d = rem & 63;
  int b = pair >> 2, h = pair & 3;
  int pp = idx[pair * 256 + (tok >> 2)];
  int py = (tok >> 1) & 1, px = tok & 1;
  int ry = (pp >> 5) * 2 + py, rx = (pp & 31) * 2 + px;
  y[((size_t)(b * 256 + h * 64 + d) * 64 + ry) * 64 + rx] += outf[g];
}

// ---------------- K12: depthwise 3x3 + BN + relu6 --------------------------
__global__ __launch_bounds__(256) void k_dwconv(
    const float* __restrict__ y, const float* __restrict__ wdw,
    const float* __restrict__ g, const float* __restrict__ bb,
    const float* __restrict__ m, const float* __restrict__ vv,
    float* __restrict__ yd) {
  int gi = blockIdx.x * 256 + threadIdx.x;  // 8*256*64*64
  int x = gi & 63, yy = (gi >> 6) & 63, ch = (gi >> 12) & 255, b = gi >> 20;
  const float* plane = y + (size_t)(b * 256 + ch) * 4096;
  const float* wc = wdw + ch * 9;
  float s = 0.f;
#pragma unroll
  for (int ky = 0; ky < 3; ++ky) {
    int iy = yy + ky - 1;
    if (iy < 0 || iy >= 64) continue;
#pragma unroll
    for (int kx = 0; kx < 3; ++kx) {
      int ix = x + kx - 1;
      if (ix < 0 || ix >= 64) continue;
      s = fmaf(plane[iy * 64 + ix], wc[ky * 3 + kx], s);
    }
  }
  float sc = g[ch] * rsqrtf(vv[ch] + EPS_);
  float val = s * sc + (bb[ch] - m[ch] * sc);
  yd[gi] = fminf(fmaxf(val, 0.f), 6.f);
}

// ---------------- K13: pointwise 1x1 GEMM + BN + relu6 ---------------------
__global__ __launch_bounds__(256) void k_pw(
    const float* __restrict__ yd, const float* __restrict__ w,
    const float* __restrict__ g, const float* __restrict__ bb,
    const float* __restrict__ m, const float* __restrict__ vv,
    float* __restrict__ out) {
  __shared__ float As[32][68];
  __shared__ float Bs[32][68];
  const int t = threadIdx.x;
  const int pix0 = blockIdx.x * 64;
  const int oc0 = blockIdx.y * 64;
  const int ty = t >> 4, tx = t & 15;
  const int bimg = pix0 >> 12, pos = pix0 & 4095;
  float acc[4][4] = {};
  for (int kc = 0; kc < 8; ++kc) {
    int ic0 = kc * 32;
#pragma unroll
    for (int j = 0; j < 2; ++j) {
      int e = t * 4 + j * 1024;
      int icl = e & 31, ocl = e >> 5;
      float4 wv = *(const float4*)&w[(size_t)(oc0 + ocl) * 256 + ic0 + icl];
      As[icl + 0][ocl] = wv.x; As[icl + 1][ocl] = wv.y;
      As[icl + 2][ocl] = wv.z; As[icl + 3][ocl] = wv.w;
      int pixl = e & 63, icl2 = e >> 6;
      float4 bv = *(const float4*)&yd[(size_t)(bimg * 256 + ic0 + icl2) * 4096 + pos + pixl];
      *(float4*)&Bs[icl2][pixl] = bv;
    }
    __syncthreads();
#pragma unroll 8
    for (int kk = 0; kk < 32; ++kk) {
      float4 a = *(const float4*)&As[kk][ty * 4];
      float4 b = *(const float4*)&Bs[kk][tx * 4];
      fma16(acc, a, b);
    }
    __syncthreads();
  }
#pragma unroll
  for (int i = 0; i < 4; ++i) {
    int oc = oc0 + ty * 4 + i;
    float sc = g[oc] * rsqrtf(vv[oc] + EPS_);
    float off = bb[oc] - m[oc] * sc;
    float4 o;
    o.x = fminf(fmaxf(acc[i][0] * sc + off, 0.f), 6.f);
    o.y = fminf(fmaxf(acc[i][1] * sc + off, 0.f), 6.f);
    o.z = fminf(fmaxf(acc[i][2] * sc + off, 0.f), 6.f);
    o.w = fminf(fmaxf(acc[i][3] * sc + off, 0.f), 6.f);
    *(float4*)&out[(size_t)(bimg * 256 + oc) * 4096 + pos + tx * 4] = o;
  }
}

// ---------------------------------------------------------------------------
extern "C" void kernel_launch(void* const* d_in, const int* in_sizes, int n_in,
                              void* d_out, int out_size, void* d_ws, size_t ws_size,
                              hipStream_t stream) {
  (void)in_sizes; (void)n_in; (void)out_size; (void)ws_size;
  const float* x       = (const float*)d_in[0];
  const float* w_down  = (const float*)d_in[1];
  const float* b_down  = (const float*)d_in[2];
  const float* w_qkv_c = (const float*)d_in[3];
  const float* b_qkv_c = (const float*)d_in[4];
  const float* w_up    = (const float*)d_in[5];
  const float* b_up    = (const float*)d_in[6];
  const float* w_qkv_f = (const float*)d_in[7];
  const float* b_qkv_f = (const float*)d_in[8];
  const float* w_dw    = (const float*)d_in[9];
  const float* bn_dw_g = (const float*)d_in[10];
  const float* bn_dw_b = (const float*)d_in[11];
  const float* bn_dw_m = (const float*)d_in[12];
  const float* bn_dw_v = (const float*)d_in[13];
  const float* w_pw    = (const float*)d_in[14];
  const float* bn_pw_g = (const float*)d_in[15];
  const float* bn_pw_b = (const float*)d_in[16];
  const float* bn_pw_m = (const float*)d_in[17];
  const float* bn_pw_v = (const float*)d_in[18];

  // workspace layout (floats), ~42.3M floats (~169 MB)
  float* ws = (float*)d_ws;
  float* S      = ws;                       // 16,777,216 (attn slice; xp early; yd late)
  float* qb     = ws + 16777216;            // 2,097,152
  float* kb     = qb + 2097152;
  float* vb     = kb + 2097152;
  float* xdp    = vb + 2097152;             // 4,194,304 (two K-halves)
  float* outcp  = xdp + 4194304;            // 2,367,488 padded [8][256][34][34]
  float* coarse = outcp + 2367488;          // 8,388,608 [b][c][64][64] -> becomes y
  float* outf   = coarse + 8388608;         // 2,097,152
  float* score  = outf + 2097152;           // 32,768
  float* wupt   = score + 32768;            // 1,048,576
  float* wdt    = wupt + 1048576;           // 1,048,576
  int*   idx    = (int*)(wdt + 1048576);    // 8,192 ints
  float* xp     = S;                        // 8,921,088 (dead before k_qk)
  float* yd     = S;                        // reuse after fine attention

  hipMemsetAsync(score, 0, 32768 * sizeof(float), stream);
  hipMemsetAsync(outcp, 0, (size_t)2367488 * sizeof(float), stream);
  k_pad_x<<<2048, 256, 0, stream>>>(x, xp);
  k_repack_wdt<<<4096, 256, 0, stream>>>(w_down, wdt);
  k_repack_wup<<<4096, 256, 0, stream>>>(w_up, wupt);
  k_conv_down<<<dim3(128, 4, 2), 256, 0, stream>>>(xp, wdt, xdp);
  k_qkv<0><<<dim3(16, 32), 256, 0, stream>>>(xdp, xdp + 2097152, b_down,
                                             w_qkv_c, b_qkv_c, nullptr, qb, kb, vb);
  // coarse attention, 2 slices of 16 pairs
  for (int s = 0; s < 2; ++s) {
    int pair0 = s * 16;
    k_qk<<<dim3(16, 16, 16), 256, 0, stream>>>(qb, kb, S, pair0);
    k_softmax<<<16384, 256, 0, stream>>>(S);
    k_score<<<dim3(4, 8, 16), 256, 0, stream>>>(S, score, pair0);
    k_av<1><<<dim3(16, 16), 256, 0, stream>>>(S, vb, outcp, pair0);
  }
  k_topk<<<32, 256, 0, stream>>>(score, idx);
  k_convT<<<dim3(128, 4, 4), 256, 0, stream>>>(outcp, wupt, b_up, coarse);

  // fine attention
  k_qkv<1><<<dim3(16, 32), 256, 0, stream>>>(coarse, nullptr, nullptr,
                                             w_qkv_f, b_qkv_f, idx, qb, kb, vb);
  for (int s = 0; s < 2; ++s) {
    int pair0 = s * 16;
    k_qk<<<dim3(16, 16, 16), 256, 0, stream>>>(qb, kb, S, pair0);
    k_softmax<<<16384, 256, 0, stream>>>(S);
    k_av<0><<<dim3(16, 16), 256, 0, stream>>>(S, vb, outf, pair0);
  }
  k_scatter<<<8192, 256, 0, stream>>>(outf, idx, coarse);
  k_dwconv<<<32768, 256, 0, stream>>>(coarse, w_dw, bn_dw_g, bn_dw_b, bn_dw_m, bn_dw_v, yd);
  k_pw<<<dim3(512, 4), 256, 0, stream>>>(yd, w_pw, bn_pw_g, bn_pw_b, bn_pw_m, bn_pw_v, (float*)d_out);
}

// Round 3
// 1216.302 us; speedup vs baseline: 1.3430x; 1.0738x over previous
//
#include <hip/hip_runtime.h>
#include <cstdint>
#include <cstddef>

// ---------------------------------------------------------------------------
// RegionSelectionAttention. Round 3: bf16x3 split-precision MFMA for all
// value-path GEMMs (convT, coarse AV, fine QK^T, fine AV, pointwise).
// Selection path (conv_down, coarse qkv/QK^T/softmax/score/topk) stays fp32.
// ---------------------------------------------------------------------------

#define SCALE_ 0.125f  // HD^-0.5 (exact power of 2 -> folded into fine q)
#define EPS_ 1e-5f

typedef short bf16x8_t __attribute__((ext_vector_type(8)));
typedef float f32x4_t __attribute__((ext_vector_type(4)));
#define MFMA16(a, b, c) __builtin_amdgcn_mfma_f32_16x16x32_bf16(a, b, c, 0, 0, 0)

__device__ __forceinline__ unsigned short f2bf(float f) {
  unsigned u = __float_as_uint(f);
  return (unsigned short)((u + 0x7FFF + ((u >> 16) & 1)) >> 16);
}
__device__ __forceinline__ float bf2f(unsigned short b) {
  return __uint_as_float(((unsigned)b) << 16);
}

__device__ __forceinline__ void fma16(float (&acc)[4][4], const float4 a, const float4 b) {
  acc[0][0] = fmaf(a.x, b.x, acc[0][0]); acc[0][1] = fmaf(a.x, b.y, acc[0][1]);
  acc[0][2] = fmaf(a.x, b.z, acc[0][2]); acc[0][3] = fmaf(a.x, b.w, acc[0][3]);
  acc[1][0] = fmaf(a.y, b.x, acc[1][0]); acc[1][1] = fmaf(a.y, b.y, acc[1][1]);
  acc[1][2] = fmaf(a.y, b.z, acc[1][2]); acc[1][3] = fmaf(a.y, b.w, acc[1][3]);
  acc[2][0] = fmaf(a.z, b.x, acc[2][0]); acc[2][1] = fmaf(a.z, b.y, acc[2][1]);
  acc[2][2] = fmaf(a.z, b.z, acc[2][2]); acc[2][3] = fmaf(a.z, b.w, acc[2][3]);
  acc[3][0] = fmaf(a.w, b.x, acc[3][0]); acc[3][1] = fmaf(a.w, b.y, acc[3][1]);
  acc[3][2] = fmaf(a.w, b.z, acc[3][2]); acc[3][3] = fmaf(a.w, b.w, acc[3][3]);
}

// ---------------- pad x -> xp[plane][66][66] (zero border) -----------------
__global__ __launch_bounds__(256) void k_pad_x(
    const float* __restrict__ x, float* __restrict__ xp) {
  const int plane = blockIdx.x;  // 2048
  const float* src = x + (size_t)plane * 4096;
  float* dst = xp + (size_t)plane * 4356;
  for (int e = threadIdx.x; e < 4356; e += 256) {
    int r = e / 66, cc = e - r * 66;
    float v = 0.f;
    if (r >= 1 && r <= 64 && cc >= 1 && cc <= 64) v = src[(r - 1) * 64 + (cc - 1)];
    dst[e] = v;
  }
}

// ---------------- repack w_down[oc][4096] -> wdt[k][oc] (fp32) -------------
__global__ __launch_bounds__(256) void k_repack_wdt(
    const float* __restrict__ w, float* __restrict__ wdt) {
  int e = blockIdx.x * 256 + threadIdx.x;  // 1048576
  int k = e & 4095, oc = e >> 12;
  wdt[(size_t)k * 256 + oc] = w[e];
}

// ---------------- K1: downsample conv k4 s2 p1, split-K z=2 (fp32) ---------
__global__ __launch_bounds__(256) void k_conv_down(
    const float* __restrict__ xp, const float* __restrict__ wdt,
    float* __restrict__ xdp) {
  __shared__ float As[64][68];
  __shared__ float Bs[64][68];
  const int t = threadIdx.x;
  const int pix0 = blockIdx.x * 64;
  const int oc0 = blockIdx.y * 64;
  const int z = blockIdx.z;
  const int bimg = pix0 >> 10, pos = pix0 & 1023;
  const int ty = t >> 4, tx = t & 15;
  const int pl = t & 63, icl = t >> 6;
  const int rem = (pix0 + pl) & 1023;
  const int oy = rem >> 5, ox = rem & 31;
  const float* xb = xp + ((size_t)(bimg * 256 + z * 128 + icl)) * 4356 + (oy * 2) * 66 + ox * 2;
  const int akk = t >> 2, ac0 = (t & 3) * 16;
  const float* wr = wdt + ((size_t)(z * 2048 + akk)) * 256 + oc0 + ac0;

  float acc[4][4] = {};
  for (int ch = 0; ch < 32; ++ch) {
    float4 w0 = *(const float4*)(wr + 0);
    float4 w1 = *(const float4*)(wr + 4);
    float4 w2 = *(const float4*)(wr + 8);
    float4 w3 = *(const float4*)(wr + 12);
    float bv[16];
#pragma unroll
    for (int tap = 0; tap < 16; ++tap)
      bv[tap] = xb[(tap >> 2) * 66 + (tap & 3)];
    __syncthreads();
    *(float4*)&As[akk][ac0 + 0] = w0;
    *(float4*)&As[akk][ac0 + 4] = w1;
    *(float4*)&As[akk][ac0 + 8] = w2;
    *(float4*)&As[akk][ac0 + 12] = w3;
#pragma unroll
    for (int tap = 0; tap < 16; ++tap) Bs[icl * 16 + tap][pl] = bv[tap];
    __syncthreads();
#pragma unroll
    for (int kk = 0; kk < 64; ++kk) {
      float4 a = *(const float4*)&As[kk][ty * 4];
      float4 b = *(const float4*)&Bs[kk][tx * 4];
      fma16(acc, a, b);
    }
    __syncthreads();
    wr += 64 * 256;
    xb += 4 * 4356;
  }
  float* outp = xdp + ((size_t)z * 8 + bimg) * 256 * 1024;
#pragma unroll
  for (int i = 0; i < 4; ++i) {
    int oc = oc0 + ty * 4 + i;
    *(float4*)&outp[(size_t)oc * 1024 + pos + tx * 4] =
        make_float4(acc[i][0], acc[i][1], acc[i][2], acc[i][3]);
  }
}

// ---------------- K2/K9: qkv projection (fp32) -----------------------------
template <int MODE>
__global__ __launch_bounds__(256) void k_qkv(
    const float* __restrict__ src, const float* __restrict__ src2,
    const float* __restrict__ cbias, const float* __restrict__ wq,
    const float* __restrict__ bq, const int* __restrict__ topk,
    float* __restrict__ qout, float* __restrict__ kout, float* __restrict__ vout) {
  __shared__ float tokT[64][68];
  const int t = threadIdx.x;
  const int tok0 = blockIdx.x * 64;
  const int pair = blockIdx.y;
  const int b = pair >> 2, h = pair & 3;
#pragma unroll
  for (int j = 0; j < 16; ++j) {
    int e = t + j * 256;
    int d = e >> 6, tl = e & 63;
    float v;
    if (MODE == 0) {
      size_t i = ((size_t)(b * 256 + h * 64 + d)) * 1024 + tok0 + tl;
      v = src[i] + src2[i] + cbias[h * 64 + d];
    } else {
      int tok = tok0 + tl;
      int pp = topk[pair * 256 + (tok >> 2)];
      int py = (tok >> 1) & 1, px = tok & 1;
      int ry = (pp >> 5) * 2 + py, rx = (pp & 31) * 2 + px;
      v = src[((size_t)(b * 256 + h * 64 + d) * 64 + ry) * 64 + rx];
    }
    tokT[d][tl] = v;
  }
  __syncthreads();
  const int col_g = t & 15;
  const int tok_g = t >> 4;
  float acc[4][12] = {};
  for (int d = 0; d < 64; ++d) {
    float4 tv4 = *(const float4*)&tokT[d][tok_g * 4];
    const float* wr = wq + d * 192 + col_g * 12;
    float wv[12];
#pragma unroll
    for (int c = 0; c < 12; c += 4) {
      float4 w4 = *(const float4*)&wr[c];
      wv[c] = w4.x; wv[c + 1] = w4.y; wv[c + 2] = w4.z; wv[c + 3] = w4.w;
    }
    float tvv[4] = {tv4.x, tv4.y, tv4.z, tv4.w};
#pragma unroll
    for (int i = 0; i < 4; ++i)
#pragma unroll
      for (int c = 0; c < 12; ++c) acc[i][c] = fmaf(tvv[i], wv[c], acc[i][c]);
  }
#pragma unroll
  for (int i = 0; i < 4; ++i) {
    int tok = tok0 + tok_g * 4 + i;
#pragma unroll
    for (int c = 0; c < 12; ++c) {
      int col = col_g * 12 + c;
      float val = acc[i][c] + bq[col];
      float* dst = (col < 64) ? qout : ((col < 128) ? kout : vout);
      dst[((size_t)pair * 1024 + tok) * 64 + (col & 63)] = val;
    }
  }
}

// ---------------- K3: coarse S = scale * q @ k^T (fp32, selection path) ----
__global__ __launch_bounds__(256) void k_qk(
    const float* __restrict__ q, const float* __restrict__ kmat,
    float* __restrict__ S, int pair0) {
  __shared__ float Qt[64][68];
  __shared__ float Kt[64][68];
  const int t = threadIdx.x;
  const int k0 = blockIdx.x * 64, q0 = blockIdx.y * 64;
  const int lp = blockIdx.z;
  const int pair = pair0 + lp;
#pragma unroll
  for (int j = 0; j < 4; ++j) {
    int e = t * 4 + j * 1024;
    int d = e & 63, row = e >> 6;
    float4 qv = *(const float4*)&q[((size_t)pair * 1024 + q0 + row) * 64 + d];
    Qt[d + 0][row] = qv.x; Qt[d + 1][row] = qv.y; Qt[d + 2][row] = qv.z; Qt[d + 3][row] = qv.w;
    float4 kv = *(const float4*)&kmat[((size_t)pair * 1024 + k0 + row) * 64 + d];
    Kt[d + 0][row] = kv.x; Kt[d + 1][row] = kv.y; Kt[d + 2][row] = kv.z; Kt[d + 3][row] = kv.w;
  }
  __syncthreads();
  const int ty = t >> 4, tx = t & 15;
  float acc[4][4] = {};
#pragma unroll 8
  for (int d = 0; d < 64; ++d) {
    float4 a = *(const float4*)&Qt[d][ty * 4];
    float4 b = *(const float4*)&Kt[d][tx * 4];
    fma16(acc, a, b);
  }
#pragma unroll
  for (int i = 0; i < 4; ++i) {
    float4 o = make_float4(acc[i][0] * SCALE_, acc[i][1] * SCALE_,
                           acc[i][2] * SCALE_, acc[i][3] * SCALE_);
    *(float4*)&S[((size_t)lp * 1024 + q0 + ty * 4 + i) * 1024 + k0 + tx * 4] = o;
  }
}

// ---------------- K4: row softmax; emits bf16 hi/lo P; opt fp32 writeback --
template <int WRITE_F32>
__global__ __launch_bounds__(256) void k_softmax(
    float* __restrict__ S, unsigned short* __restrict__ ph,
    unsigned short* __restrict__ pl) {
  const int row = blockIdx.x;
  float* r = S + (size_t)row * 1024;
  const int t = threadIdx.x;
  __shared__ float red[4];
  __shared__ float bcast;
  float4 v = *(const float4*)&r[t * 4];
  float m = fmaxf(fmaxf(v.x, v.y), fmaxf(v.z, v.w));
#pragma unroll
  for (int off = 32; off > 0; off >>= 1) m = fmaxf(m, __shfl_down(m, off));
  if ((t & 63) == 0) red[t >> 6] = m;
  __syncthreads();
  if (t == 0) bcast = fmaxf(fmaxf(red[0], red[1]), fmaxf(red[2], red[3]));
  __syncthreads();
  m = bcast;
  v.x = __expf(v.x - m); v.y = __expf(v.y - m);
  v.z = __expf(v.z - m); v.w = __expf(v.w - m);
  float s = v.x + v.y + v.z + v.w;
#pragma unroll
  for (int off = 32; off > 0; off >>= 1) s += __shfl_down(s, off);
  __syncthreads();
  if ((t & 63) == 0) red[t >> 6] = s;
  __syncthreads();
  if (t == 0) bcast = red[0] + red[1] + red[2] + red[3];
  __syncthreads();
  float inv = 1.0f / bcast;
  v.x *= inv; v.y *= inv; v.z *= inv; v.w *= inv;
  if (WRITE_F32) *(float4*)&r[t * 4] = v;
  float vv[4] = {v.x, v.y, v.z, v.w};
  unsigned short hs[4], ls[4];
#pragma unroll
  for (int j = 0; j < 4; ++j) {
    hs[j] = f2bf(vv[j]);
    ls[j] = f2bf(vv[j] - bf2f(hs[j]));
  }
  *(ushort4*)&ph[(size_t)row * 1024 + t * 4] = make_ushort4(hs[0], hs[1], hs[2], hs[3]);
  *(ushort4*)&pl[(size_t)row * 1024 + t * 4] = make_ushort4(ls[0], ls[1], ls[2], ls[3]);
}

// ---------------- K5: coarse_score[k] += sum_q attn[q][k] (fp32) -----------
__global__ __launch_bounds__(256) void k_score(
    const float* __restrict__ S, float* __restrict__ score, int pair0) {
  const int t = threadIdx.x;
  const int kbase = blockIdx.x * 256;
  const int qc = blockIdx.y;
  const int lp = blockIdx.z;
  float s = 0.f;
  const float* base = S + ((size_t)lp * 1024 + qc * 128) * 1024 + kbase + t;
  for (int qq = 0; qq < 128; ++qq) s += base[(size_t)qq * 1024];
  atomicAdd(&score[(pair0 + lp) * 1024 + kbase + t], s);
}

// ---------------- K6: per-pair top-256 via bitonic sort --------------------
__global__ __launch_bounds__(256) void k_topk(
    const float* __restrict__ score, int* __restrict__ idx) {
  __shared__ unsigned long long key[1024];
  const int pair = blockIdx.x;
  const int t = threadIdx.x;
#pragma unroll
  for (int j = 0; j < 4; ++j) {
    int i = t + j * 256;
    unsigned u = __float_as_uint(score[pair * 1024 + i]);
    u = u ^ ((u & 0x80000000u) ? 0xFFFFFFFFu : 0x80000000u);
    u = ~u;
    key[i] = ((unsigned long long)u << 32) | (unsigned)i;
  }
  __syncthreads();
  for (int k = 2; k <= 1024; k <<= 1) {
    for (int j = k >> 1; j > 0; j >>= 1) {
      for (int w = 0; w < 4; ++w) {
        int i = t + w * 256;
        int l = i ^ j;
        if (l > i) {
          bool up = ((i & k) == 0);
          unsigned long long a = key[i], b = key[l];
          if ((a > b) == up) { key[i] = b; key[l] = a; }
        }
      }
      __syncthreads();
    }
  }
  idx[pair * 256 + t] = (int)(key[t] & 0xFFFFFFFFu);
}

// ---------------- convert v -> vt hi/lo [pair][64 d][1024 tok] -------------
__global__ __launch_bounds__(256) void k_cvt_vt(
    const float* __restrict__ v, unsigned short* __restrict__ vth,
    unsigned short* __restrict__ vtl) {
  __shared__ float T[64][65];
  const int t = threadIdx.x;
  const int tok0 = blockIdx.x * 64;
  const int pair = blockIdx.y;
#pragma unroll
  for (int i = 0; i < 16; ++i) {
    int e = t + i * 256;
    int row = e >> 6, col = e & 63;
    T[row][col] = v[((size_t)pair * 1024 + tok0 + row) * 64 + col];
  }
  __syncthreads();
  const int d = t >> 2, tq = t & 3;
  unsigned short hs[16], ls[16];
#pragma unroll
  for (int j = 0; j < 16; ++j) {
    float f = T[tq * 16 + j][d];
    hs[j] = f2bf(f);
    ls[j] = f2bf(f - bf2f(hs[j]));
  }
  size_t base = ((size_t)pair * 64 + d) * 1024 + tok0 + tq * 16;
#pragma unroll
  for (int j = 0; j < 4; ++j) {
    *(ushort4*)&vth[base + j * 4] = make_ushort4(hs[j * 4], hs[j * 4 + 1], hs[j * 4 + 2], hs[j * 4 + 3]);
    *(ushort4*)&vtl[base + j * 4] = make_ushort4(ls[j * 4], ls[j * 4 + 1], ls[j * 4 + 2], ls[j * 4 + 3]);
  }
}

// ---------------- convert fine q (x scale), k -> bf16 hi/lo ----------------
__global__ __launch_bounds__(256) void k_cvt_qk(
    const float* __restrict__ q, const float* __restrict__ kk,
    unsigned short* __restrict__ qh, unsigned short* __restrict__ ql,
    unsigned short* __restrict__ kh, unsigned short* __restrict__ kl) {
  int e = blockIdx.x * 256 + threadIdx.x;  // 2,097,152
  float qs = q[e] * SCALE_;
  unsigned short h = f2bf(qs);
  qh[e] = h; ql[e] = f2bf(qs - bf2f(h));
  float kv = kk[e];
  h = f2bf(kv);
  kh[e] = h; kl[e] = f2bf(kv - bf2f(h));
}

// ---------------- w_up -> wt hi/lo [class][oc][k'=tap*256+ic] --------------
__global__ __launch_bounds__(256) void k_cvt_wup(
    const float* __restrict__ w_up, unsigned short* __restrict__ wth,
    unsigned short* __restrict__ wtl) {
  int e = blockIdx.x * 256 + threadIdx.x;  // 2^20: [class][oc][kp]
  int kp = e & 1023, oc = (e >> 10) & 255, c = e >> 18;
  int tap = kp >> 8, ic = kp & 255;
  int tk = tap >> 1, txi = tap & 1;
  int ry = c >> 1, rx = c & 1;
  int ky = (1 - ry) + 2 * tk, kx = (1 - rx) + 2 * txi;
  float f = w_up[((size_t)(ic * 256 + oc) * 4 + ky) * 4 + kx];
  unsigned short h = f2bf(f);
  wth[e] = h; wtl[e] = f2bf(f - bf2f(h));
}

// ---------------- w_pw -> hi/lo bf16 [oc][ic] ------------------------------
__global__ __launch_bounds__(256) void k_cvt_wpw(
    const float* __restrict__ w, unsigned short* __restrict__ wh,
    unsigned short* __restrict__ wl) {
  int e = blockIdx.x * 256 + threadIdx.x;  // 65536
  float f = w[e];
  unsigned short h = f2bf(f);
  wh[e] = h; wl[e] = f2bf(f - bf2f(h));
}

// ====================== bf16x3 MFMA GEMM kernels ===========================
// Block: 256 thr = 4 waves; block tile M=64 x N=64; wave = 16m x 64n.
// LDS tiles [64 rows][72 k] (rows = m or n, k contiguous). K-chunks of 64.

__device__ __forceinline__ void mfma_chunk(
    const unsigned short (*Ah)[72], const unsigned short (*Al)[72],
    const unsigned short (*Bh)[72], const unsigned short (*Bl)[72],
    f32x4_t (&acc)[4], int wm, int lane) {
  const int l16 = lane & 15, quad = lane >> 4;
#pragma unroll
  for (int ks = 0; ks < 2; ++ks) {
    int ko = ks * 32 + quad * 8;
    bf16x8_t ah = *(const bf16x8_t*)&Ah[wm + l16][ko];
    bf16x8_t al = *(const bf16x8_t*)&Al[wm + l16][ko];
#pragma unroll
    for (int nt = 0; nt < 4; ++nt) {
      bf16x8_t bh = *(const bf16x8_t*)&Bh[nt * 16 + l16][ko];
      bf16x8_t bl = *(const bf16x8_t*)&Bl[nt * 16 + l16][ko];
      acc[nt] = MFMA16(ah, bh, acc[nt]);
      acc[nt] = MFMA16(ah, bl, acc[nt]);
      acc[nt] = MFMA16(al, bh, acc[nt]);
    }
  }
}

// ---------------- fine QK^T: S = q' @ k^T (scale pre-folded) ---------------
__global__ __launch_bounds__(256) void k_qk_mfma(
    const unsigned short* __restrict__ qh, const unsigned short* __restrict__ ql,
    const unsigned short* __restrict__ kh, const unsigned short* __restrict__ kl,
    float* __restrict__ S, int pair0) {
  __shared__ unsigned short Ah[64][72], Al[64][72], Bh[64][72], Bl[64][72];
  const int t = threadIdx.x;
  const int k0 = blockIdx.x * 64, q0 = blockIdx.y * 64;
  const int lp = blockIdx.z;
  const int pair = pair0 + lp;
  const size_t qbase = ((size_t)pair * 1024 + q0) * 64;
  const size_t kbase = ((size_t)pair * 1024 + k0) * 64;
#pragma unroll
  for (int i = 0; i < 2; ++i) {
    int e = t + i * 256;
    int r = e >> 3, kc = (e & 7) * 8;
    *(bf16x8_t*)&Ah[r][kc] = *(const bf16x8_t*)(qh + qbase + (size_t)r * 64 + kc);
    *(bf16x8_t*)&Al[r][kc] = *(const bf16x8_t*)(ql + qbase + (size_t)r * 64 + kc);
    *(bf16x8_t*)&Bh[r][kc] = *(const bf16x8_t*)(kh + kbase + (size_t)r * 64 + kc);
    *(bf16x8_t*)&Bl[r][kc] = *(const bf16x8_t*)(kl + kbase + (size_t)r * 64 + kc);
  }
  __syncthreads();
  const int wave = t >> 6, lane = t & 63;
  f32x4_t acc[4] = {};
  mfma_chunk(Ah, Al, Bh, Bl, acc, wave * 16, lane);
  const int l16 = lane & 15, quad = lane >> 4;
#pragma unroll
  for (int nt = 0; nt < 4; ++nt)
#pragma unroll
    for (int r = 0; r < 4; ++r) {
      int qm = q0 + wave * 16 + quad * 4 + r;
      int kn = k0 + nt * 16 + l16;
      S[((size_t)lp * 1024 + qm) * 1024 + kn] = acc[nt][r];
    }
}

// ---------------- AV: out = P @ V  (A = P hi/lo rows, B = vt hi/lo) --------
// COARSE=1: write padded fp32 outcp [b][c][34][34]; else outf [pair][tok][d]
template <int COARSE>
__global__ __launch_bounds__(256) void k_av_mfma(
    const unsigned short* __restrict__ ph, const unsigned short* __restrict__ pl,
    const unsigned short* __restrict__ vth, const unsigned short* __restrict__ vtl,
    float* __restrict__ out, int pair0) {
  __shared__ unsigned short Ah[64][72], Al[64][72], Bh[64][72], Bl[64][72];
  __shared__ float Tr[64][68];
  const int t = threadIdx.x;
  const int q0 = blockIdx.x * 64;
  const int lp = blockIdx.y;
  const int pair = pair0 + lp;
  const int wave = t >> 6, lane = t & 63;
  const int l16 = lane & 15, quad = lane >> 4;
  f32x4_t acc[4] = {};
  const size_t abase = ((size_t)lp * 1024 + q0) * 1024;
  const size_t bbase = (size_t)pair * 64 * 1024;
  for (int kb = 0; kb < 1024; kb += 64) {
#pragma unroll
    for (int i = 0; i < 2; ++i) {
      int e = t + i * 256;
      int r = e >> 3, kc = (e & 7) * 8;
      *(bf16x8_t*)&Ah[r][kc] = *(const bf16x8_t*)(ph + abase + (size_t)r * 1024 + kb + kc);
      *(bf16x8_t*)&Al[r][kc] = *(const bf16x8_t*)(pl + abase + (size_t)r * 1024 + kb + kc);
      *(bf16x8_t*)&Bh[r][kc] = *(const bf16x8_t*)(vth + bbase + (size_t)r * 1024 + kb + kc);
      *(bf16x8_t*)&Bl[r][kc] = *(const bf16x8_t*)(vtl + bbase + (size_t)r * 1024 + kb + kc);
    }
    __syncthreads();
    mfma_chunk(Ah, Al, Bh, Bl, acc, wave * 16, lane);
    __syncthreads();
  }
  if (COARSE) {
#pragma unroll
    for (int nt = 0; nt < 4; ++nt)
#pragma unroll
      for (int r = 0; r < 4; ++r)
        Tr[nt * 16 + l16][wave * 16 + quad * 4 + r] = acc[nt][r];
    __syncthreads();
    const int b = pair >> 2, h = pair & 3;
#pragma unroll
    for (int i = 0; i < 16; ++i) {
      int e = t + i * 256;
      int d = e >> 6, ql_ = e & 63;
      int pix = q0 + ql_;
      int iy = (pix >> 5) + 1, ix = (pix & 31) + 1;
      out[((size_t)(b * 256 + h * 64 + d)) * 1156 + iy * 34 + ix] = Tr[d][ql_];
    }
  } else {
#pragma unroll
    for (int nt = 0; nt < 4; ++nt)
#pragma unroll
      for (int r = 0; r < 4; ++r) {
        int qm = q0 + wave * 16 + quad * 4 + r;
        int dn = nt * 16 + l16;
        out[((size_t)pair * 1024 + qm) * 64 + dn] = acc[nt][r];
      }
  }
}

// ---------------- convT as 4-class GEMM, bf16x3 MFMA -----------------------
// A = wt hi/lo [class][oc][k'], B staged from padded fp32 outcp w/ fused cvt
__global__ __launch_bounds__(256) void k_convT_mfma(
    const float* __restrict__ inp, const unsigned short* __restrict__ wth,
    const unsigned short* __restrict__ wtl, const float* __restrict__ bias,
    float* __restrict__ out) {
  __shared__ unsigned short Ah[64][72], Al[64][72], Bh[64][72], Bl[64][72];
  const int t = threadIdx.x;
  const int pix0 = blockIdx.x * 64;
  const int oc0 = blockIdx.y * 64;
  const int cls = blockIdx.z;
  const int ry = cls >> 1, rx = cls & 1;
  const int b = pix0 >> 10;
  const int wave = t >> 6, lane = t & 63;
  const int l16 = lane & 15, quad = lane >> 4;
  f32x4_t acc[4] = {};
  const size_t wbase = ((size_t)cls * 256 + oc0) * 1024;
  for (int kb = 0; kb < 1024; kb += 64) {
    const int tap = kb >> 8, ic0 = kb & 255;
    const int tk = tap >> 1, txi = tap & 1;
#pragma unroll
    for (int i = 0; i < 2; ++i) {
      int e = t + i * 256;
      int r = e >> 3, kc = (e & 7) * 8;
      *(bf16x8_t*)&Ah[r][kc] = *(const bf16x8_t*)(wth + wbase + (size_t)r * 1024 + kb + kc);
      *(bf16x8_t*)&Al[r][kc] = *(const bf16x8_t*)(wtl + wbase + (size_t)r * 1024 + kb + kc);
    }
#pragma unroll
    for (int i = 0; i < 16; ++i) {
      int e = t + i * 256;
      int icl = e >> 6, pixl = e & 63;
      int rem = (pix0 + pixl) & 1023;
      int tyy = rem >> 5, txx = rem & 31;
      int iy = tyy + ry + 1 - tk, ix = txx + rx + 1 - txi;
      float f = inp[(size_t)(b * 256 + ic0 + icl) * 1156 + iy * 34 + ix];
      unsigned short h = f2bf(f);
      Bh[pixl][icl] = h;
      Bl[pixl][icl] = f2bf(f - bf2f(h));
    }
    __syncthreads();
    mfma_chunk(Ah, Al, Bh, Bl, acc, wave * 16, lane);
    __syncthreads();
  }
#pragma unroll
  for (int r = 0; r < 4; ++r) {
    int oc = oc0 + wave * 16 + quad * 4 + r;
    float bv = bias[oc];
#pragma unroll
    for (int nt = 0; nt < 4; ++nt) {
      int pix = pix0 + nt * 16 + l16;
      int rem = pix & 1023;
      int y = (rem >> 5) * 2 + ry, xx = (rem & 31) * 2 + rx;
      out[((size_t)(b * 256 + oc) * 64 + y) * 64 + xx] = acc[nt][r] + bv;
    }
  }
}

// ---------------- pointwise 1x1 + BN + relu6, bf16x3 MFMA ------------------
__global__ __launch_bounds__(256) void k_pw_mfma(
    const float* __restrict__ yd, const unsigned short* __restrict__ wh,
    const unsigned short* __restrict__ wl, const float* __restrict__ g,
    const float* __restrict__ bb, const float* __restrict__ m,
    const float* __restrict__ vv, float* __restrict__ out) {
  __shared__ unsigned short Ah[64][72], Al[64][72], Bh[64][72], Bl[64][72];
  const int t = threadIdx.x;
  const int pix0 = blockIdx.x * 64;  // 32768 pixels
  const int oc0 = blockIdx.y * 64;
  const int b = pix0 >> 12, pos0 = pix0 & 4095;
  const int wave = t >> 6, lane = t & 63;
  const int l16 = lane & 15, quad = lane >> 4;
  f32x4_t acc[4] = {};
  for (int kb = 0; kb < 256; kb += 64) {
#pragma unroll
    for (int i = 0; i < 2; ++i) {
      int e = t + i * 256;
      int r = e >> 3, kc = (e & 7) * 8;
      *(bf16x8_t*)&Ah[r][kc] = *(const bf16x8_t*)(wh + (size_t)(oc0 + r) * 256 + kb + kc);
      *(bf16x8_t*)&Al[r][kc] = *(const bf16x8_t*)(wl + (size_t)(oc0 + r) * 256 + kb + kc);
    }
#pragma unroll
    for (int i = 0; i < 16; ++i) {
      int e = t + i * 256;
      int icl = e >> 6, pixl = e & 63;
      float f = yd[(size_t)(b * 256 + kb + icl) * 4096 + pos0 + pixl];
      unsigned short h = f2bf(f);
      Bh[pixl][icl] = h;
      Bl[pixl][icl] = f2bf(f - bf2f(h));
    }
    __syncthreads();
    mfma_chunk(Ah, Al, Bh, Bl, acc, wave * 16, lane);
    __syncthreads();
  }
#pragma unroll
  for (int r = 0; r < 4; ++r) {
    int oc = oc0 + wave * 16 + quad * 4 + r;
    float sc = g[oc] * rsqrtf(vv[oc] + EPS_);
    float off = bb[oc] - m[oc] * sc;
#pragma unroll
    for (int nt = 0; nt < 4; ++nt) {
      int pix = pos0 + nt * 16 + l16;
      float val = fminf(fmaxf(acc[nt][r] * sc + off, 0.f), 6.f);
      out[(size_t)(b * 256 + oc) * 4096 + pix] = val;
    }
  }
}

// ---------------- K11: scatter-add fine outputs into y ---------------------
__global__ __launch_bounds__(256) void k_scatter(
    const float* __restrict__ outf, const int* __restrict__ idx,
    float* __restrict__ y) {
  int g = blockIdx.x * 256 + threadIdx.x;
  int pair = g >> 16;
  int rem = g & 65535;
  int tok = rem >> 6, d = rem & 63;
  int b = pair >> 2, h = pair & 3;
  int pp = idx[pair * 256 + (tok >> 2)];
  int py = (tok >> 1) & 1, px = tok & 1;
  int ry = (pp >> 5) * 2 + py, rx = (pp & 31) * 2 + px;
  y[((size_t)(b * 256 + h * 64 + d) * 64 + ry) * 64 + rx] += outf[g];
}

// ---------------- K12: depthwise 3x3 + BN + relu6 (fp32) -------------------
__global__ __launch_bounds__(256) void k_dwconv(
    const float* __restrict__ y, const float* __restrict__ wdw,
    const float* __restrict__ g, const float* __restrict__ bb,
    const float* __restrict__ m, const float* __restrict__ vv,
    float* __restrict__ yd) {
  int gi = blockIdx.x * 256 + threadIdx.x;
  int x = gi & 63, yy = (gi >> 6) & 63, ch = (gi >> 12) & 255, b = gi >> 20;
  const float* plane = y + (size_t)(b * 256 + ch) * 4096;
  const float* wc = wdw + ch * 9;
  float s = 0.f;
#pragma unroll
  for (int ky = 0; ky < 3; ++ky) {
    int iy = yy + ky - 1;
    if (iy < 0 || iy >= 64) continue;
#pragma unroll
    for (int kx = 0; kx < 3; ++kx) {
      int ix = x + kx - 1;
      if (ix < 0 || ix >= 64) continue;
      s = fmaf(plane[iy * 64 + ix], wc[ky * 3 + kx], s);
    }
  }
  float sc = g[ch] * rsqrtf(vv[ch] + EPS_);
  float val = s * sc + (bb[ch] - m[ch] * sc);
  yd[gi] = fminf(fmaxf(val, 0.f), 6.f);
}

// ---------------------------------------------------------------------------
extern "C" void kernel_launch(void* const* d_in, const int* in_sizes, int n_in,
                              void* d_out, int out_size, void* d_ws, size_t ws_size,
                              hipStream_t stream) {
  (void)in_sizes; (void)n_in; (void)out_size; (void)ws_size;
  const float* x       = (const float*)d_in[0];
  const float* w_down  = (const float*)d_in[1];
  const float* b_down  = (const float*)d_in[2];
  const float* w_qkv_c = (const float*)d_in[3];
  const float* b_qkv_c = (const float*)d_in[4];
  const float* w_up    = (const float*)d_in[5];
  const float* b_up    = (const float*)d_in[6];
  const float* w_qkv_f = (const float*)d_in[7];
  const float* b_qkv_f = (const float*)d_in[8];
  const float* w_dw    = (const float*)d_in[9];
  const float* bn_dw_g = (const float*)d_in[10];
  const float* bn_dw_b = (const float*)d_in[11];
  const float* bn_dw_m = (const float*)d_in[12];
  const float* bn_dw_v = (const float*)d_in[13];
  const float* w_pw    = (const float*)d_in[14];
  const float* bn_pw_g = (const float*)d_in[15];
  const float* bn_pw_b = (const float*)d_in[16];
  const float* bn_pw_m = (const float*)d_in[17];
  const float* bn_pw_v = (const float*)d_in[18];

  // workspace layout (float units), ~236 MB total
  float* ws = (float*)d_ws;
  float*          S     = ws;                          // 16,777,216 f (alias: xp, yd)
  unsigned short* S_hi  = (unsigned short*)(ws + 16777216);  // 16M ushort
  unsigned short* S_lo  = (unsigned short*)(ws + 25165824);
  float*          qb    = ws + 33554432;               // 2,097,152 f (alias: outf)
  float*          kb    = ws + 35651584;
  float*          vb    = ws + 37748736;
  float*          xdp   = ws + 39845888;               // 4,194,304 f (alias: q/k hi-lo)
  unsigned short* q_hi  = (unsigned short*)(ws + 39845888);
  unsigned short* q_lo  = (unsigned short*)(ws + 40894464);
  unsigned short* k_hi  = (unsigned short*)(ws + 41943040);
  unsigned short* k_lo  = (unsigned short*)(ws + 42991616);
  unsigned short* vt_hi = (unsigned short*)(ws + 44040192);
  unsigned short* vt_lo = (unsigned short*)(ws + 45088768);
  float*          outcp = ws + 46137344;               // 2,367,488 f padded [8][256][34][34]
  float*          coarse= ws + 48504832;               // 8,388,608 f
  float*          score = ws + 56893440;               // 32,768 f
  unsigned short* wt_hi = (unsigned short*)(ws + 56926208);  // 2^20 ushort
  unsigned short* wt_lo = (unsigned short*)(ws + 57450496);
  float*          wdt   = ws + 57974784;               // 1,048,576 f
  unsigned short* wpw_hi= (unsigned short*)(ws + 59023360);
  unsigned short* wpw_lo= (unsigned short*)(ws + 59056128);
  int*            idx   = (int*)(ws + 59088896);       // 8,192 int
  float*          xp    = S;                           // 8,921,088 f (dead before qk)
  float*          outf  = qb;                          // fine av out (q fp32 dead)
  float*          yd    = S;                           // dwconv out (S fp32 dead)

  hipMemsetAsync(score, 0, 32768 * sizeof(float), stream);
  hipMemsetAsync(outcp, 0, (size_t)2367488 * sizeof(float), stream);
  k_pad_x<<<2048, 256, 0, stream>>>(x, xp);
  k_repack_wdt<<<4096, 256, 0, stream>>>(w_down, wdt);
  k_cvt_wup<<<4096, 256, 0, stream>>>(w_up, wt_hi, wt_lo);
  k_cvt_wpw<<<256, 256, 0, stream>>>(w_pw, wpw_hi, wpw_lo);
  k_conv_down<<<dim3(128, 4, 2), 256, 0, stream>>>(xp, wdt, xdp);
  k_qkv<0><<<dim3(16, 32), 256, 0, stream>>>(xdp, xdp + 2097152, b_down,
                                             w_qkv_c, b_qkv_c, nullptr, qb, kb, vb);
  k_cvt_vt<<<dim3(16, 32), 256, 0, stream>>>(vb, vt_hi, vt_lo);
  // coarse attention: fp32 QK/softmax/score (selection), MFMA AV (value)
  for (int s = 0; s < 2; ++s) {
    int pair0 = s * 16;
    k_qk<<<dim3(16, 16, 16), 256, 0, stream>>>(qb, kb, S, pair0);
    k_softmax<1><<<16384, 256, 0, stream>>>(S, S_hi, S_lo);
    k_score<<<dim3(4, 8, 16), 256, 0, stream>>>(S, score, pair0);
    k_av_mfma<1><<<dim3(16, 16), 256, 0, stream>>>(S_hi, S_lo, vt_hi, vt_lo, outcp, pair0);
  }
  k_topk<<<32, 256, 0, stream>>>(score, idx);
  k_convT_mfma<<<dim3(128, 4, 4), 256, 0, stream>>>(outcp, wt_hi, wt_lo, b_up, coarse);

  // fine attention (all MFMA)
  k_qkv<1><<<dim3(16, 32), 256, 0, stream>>>(coarse, nullptr, nullptr,
                                             w_qkv_f, b_qkv_f, idx, qb, kb, vb);
  k_cvt_qk<<<8192, 256, 0, stream>>>(qb, kb, q_hi, q_lo, k_hi, k_lo);
  k_cvt_vt<<<dim3(16, 32), 256, 0, stream>>>(vb, vt_hi, vt_lo);
  for (int s = 0; s < 2; ++s) {
    int pair0 = s * 16;
    k_qk_mfma<<<dim3(16, 16, 16), 256, 0, stream>>>(q_hi, q_lo, k_hi, k_lo, S, pair0);
    k_softmax<0><<<16384, 256, 0, stream>>>(S, S_hi, S_lo);
    k_av_mfma<0><<<dim3(16, 16), 256, 0, stream>>>(S_hi, S_lo, vt_hi, vt_lo, outf, pair0);
  }
  k_scatter<<<8192, 256, 0, stream>>>(outf, idx, coarse);
  k_dwconv<<<32768, 256, 0, stream>>>(coarse, w_dw, bn_dw_g, bn_dw_b, bn_dw_m, bn_dw_v, yd);
  k_pw_mfma<<<dim3(512, 4), 256, 0, stream>>>(yd, wpw_hi, wpw_lo, bn_pw_g, bn_pw_b,
                                              bn_pw_m, bn_pw_v, (float*)d_out);
}

// Round 4
// 817.330 us; speedup vs baseline: 1.9985x; 1.4881x over previous
//
#include <hip/hip_runtime.h>
#include <cstdint>
#include <cstddef>

// ---------------------------------------------------------------------------
// RegionSelectionAttention. Round 4: everything matmul-shaped on bf16x3 MFMA.
// bf16x3: D = hi*hi + hi*lo + lo*hi, rel err ~2^-17 ~= fp32 reorder noise.
// Selection path risk analyzed: perturbation same class as rounds 1-3 reorder.
// ---------------------------------------------------------------------------

#define EPS_ 1e-5f

typedef short bf16x8_t __attribute__((ext_vector_type(8)));
typedef float f32x4_t __attribute__((ext_vector_type(4)));
#define MFMA16(a, b, c) __builtin_amdgcn_mfma_f32_16x16x32_bf16(a, b, c, 0, 0, 0)

// hi = RNE bf16, lo = trunc bf16 of residual (residual exact in fp32)
__device__ __forceinline__ void cvt1(float f, unsigned short& h, unsigned short& l) {
  unsigned u = __float_as_uint(f);
  unsigned r = u + 0x7FFFu + ((u >> 16) & 1u);
  h = (unsigned short)(r >> 16);
  float lo = f - __uint_as_float(r & 0xFFFF0000u);
  l = (unsigned short)(__float_as_uint(lo) >> 16);
}
// packed pair: hpack = bf16(f0) | bf16(f1)<<16 ; lpack likewise
__device__ __forceinline__ void cvt2(float f0, float f1, unsigned& hpack, unsigned& lpack) {
  unsigned u0 = __float_as_uint(f0), u1 = __float_as_uint(f1);
  unsigned r0 = u0 + 0x7FFFu + ((u0 >> 16) & 1u);
  unsigned r1 = u1 + 0x7FFFu + ((u1 >> 16) & 1u);
  hpack = (r0 >> 16) | (r1 & 0xFFFF0000u);
  float l0 = f0 - __uint_as_float(r0 & 0xFFFF0000u);
  float l1 = f1 - __uint_as_float(r1 & 0xFFFF0000u);
  lpack = (__float_as_uint(l0) >> 16) | (__float_as_uint(l1) & 0xFFFF0000u);
}
__device__ __forceinline__ float bfh(unsigned short b) {
  return __uint_as_float(((unsigned)b) << 16);
}

// ---------------- pad x -> xp[plane][66][66] (zero border) -----------------
__global__ __launch_bounds__(256) void k_pad_x(
    const float* __restrict__ x, float* __restrict__ xp) {
  const int plane = blockIdx.x;  // 2048
  const float* src = x + (size_t)plane * 4096;
  float* dst = xp + (size_t)plane * 4356;
  for (int e = threadIdx.x; e < 4356; e += 256) {
    int r = e / 66, cc = e - r * 66;
    float v = 0.f;
    if (r >= 1 && r <= 64 && cc >= 1 && cc <= 64) v = src[(r - 1) * 64 + (cc - 1)];
    dst[e] = v;
  }
}

// ---------------- weight conversions ---------------------------------------
__global__ __launch_bounds__(256) void k_cvt_wdown(
    const float* __restrict__ w, unsigned short* __restrict__ wh,
    unsigned short* __restrict__ wl) {
  int e = blockIdx.x * 256 + threadIdx.x;  // 1,048,576: [oc][4096] native
  cvt1(w[e], wh[e], wl[e]);
}

__global__ __launch_bounds__(256) void k_cvt_wqkv(
    const float* __restrict__ wq, unsigned short* __restrict__ wh,
    unsigned short* __restrict__ wl) {
  int e = blockIdx.x * 256 + threadIdx.x;  // 12288: [col][d]
  int col = e >> 6, d = e & 63;
  float f = wq[d * 192 + col];
  if (col < 64) f *= 0.125f;  // fold attn scale into q (pow2: exact)
  cvt1(f, wh[e], wl[e]);
}

__global__ __launch_bounds__(256) void k_cvt_wup(
    const float* __restrict__ w_up, unsigned short* __restrict__ wth,
    unsigned short* __restrict__ wtl) {
  int e = blockIdx.x * 256 + threadIdx.x;  // 2^20: [class][oc][kp=tap*256+ic]
  int kp = e & 1023, oc = (e >> 10) & 255, c = e >> 18;
  int tap = kp >> 8, ic = kp & 255;
  int tk = tap >> 1, txi = tap & 1;
  int ry = c >> 1, rx = c & 1;
  int ky = (1 - ry) + 2 * tk, kx = (1 - rx) + 2 * txi;
  cvt1(w_up[((size_t)(ic * 256 + oc) * 4 + ky) * 4 + kx], wth[e], wtl[e]);
}

__global__ __launch_bounds__(256) void k_cvt_wpw(
    const float* __restrict__ w, unsigned short* __restrict__ wh,
    unsigned short* __restrict__ wl) {
  int e = blockIdx.x * 256 + threadIdx.x;  // 65536 [oc][ic]
  cvt1(w[e], wh[e], wl[e]);
}

// ====================== bf16x3 MFMA core ===================================
__device__ __forceinline__ void mfma_chunk(
    const unsigned short (*Ah)[72], const unsigned short (*Al)[72],
    const unsigned short (*Bh)[72], const unsigned short (*Bl)[72],
    f32x4_t (&acc)[4], int wm, int lane) {
  const int l16 = lane & 15, quad = lane >> 4;
#pragma unroll
  for (int ks = 0; ks < 2; ++ks) {
    int ko = ks * 32 + quad * 8;
    bf16x8_t ah = *(const bf16x8_t*)&Ah[wm + l16][ko];
    bf16x8_t al = *(const bf16x8_t*)&Al[wm + l16][ko];
#pragma unroll
    for (int nt = 0; nt < 4; ++nt) {
      bf16x8_t bh = *(const bf16x8_t*)&Bh[nt * 16 + l16][ko];
      bf16x8_t bl = *(const bf16x8_t*)&Bl[nt * 16 + l16][ko];
      acc[nt] = MFMA16(ah, bh, acc[nt]);
      acc[nt] = MFMA16(ah, bl, acc[nt]);
      acc[nt] = MFMA16(al, bh, acc[nt]);
    }
  }
}

// ---------------- conv down k4 s2 p1 as implicit GEMM, K=4096 --------------
__global__ __launch_bounds__(256) void k_conv_down_mfma(
    const float* __restrict__ xp, const unsigned short* __restrict__ wdh,
    const unsigned short* __restrict__ wdl, float* __restrict__ xd) {
  __shared__ unsigned short Ah[64][72], Al[64][72], Bh[64][72], Bl[64][72];
  const int t = threadIdx.x;
  const int pix0 = blockIdx.x * 64, oc0 = blockIdx.y * 64;
  const int bimg = pix0 >> 10, pos = pix0 & 1023;
  const int pl = t & 63, icg = t >> 6;
  const int rem = (pix0 + pl) & 1023;
  const int oy = rem >> 5, ox = rem & 31;
  const float* xb = xp + ((size_t)bimg * 256 + icg) * 4356 + (oy * 2) * 66 + ox * 2;
  const int wave = t >> 6, lane = t & 63, l16 = lane & 15, quad = lane >> 4;
  const int ar = t >> 3, akc = (t & 7) * 8;
  f32x4_t acc[4] = {};
  for (int kb = 0; kb < 4096; kb += 64) {
    bf16x8_t a0h = *(const bf16x8_t*)(wdh + (size_t)(oc0 + ar) * 4096 + kb + akc);
    bf16x8_t a0l = *(const bf16x8_t*)(wdl + (size_t)(oc0 + ar) * 4096 + kb + akc);
    bf16x8_t a1h = *(const bf16x8_t*)(wdh + (size_t)(oc0 + 32 + ar) * 4096 + kb + akc);
    bf16x8_t a1l = *(const bf16x8_t*)(wdl + (size_t)(oc0 + 32 + ar) * 4096 + kb + akc);
    float fv[16];
#pragma unroll
    for (int tap = 0; tap < 16; ++tap) fv[tap] = xb[(tap >> 2) * 66 + (tap & 3)];
    unsigned hp[8], lp[8];
#pragma unroll
    for (int j = 0; j < 8; ++j) cvt2(fv[2 * j], fv[2 * j + 1], hp[j], lp[j]);
    __syncthreads();  // previous chunk's MFMA done
    *(bf16x8_t*)&Ah[ar][akc] = a0h;      *(bf16x8_t*)&Al[ar][akc] = a0l;
    *(bf16x8_t*)&Ah[ar + 32][akc] = a1h; *(bf16x8_t*)&Al[ar + 32][akc] = a1l;
    *(uint4*)&Bh[pl][icg * 16] = make_uint4(hp[0], hp[1], hp[2], hp[3]);
    *(uint4*)&Bh[pl][icg * 16 + 8] = make_uint4(hp[4], hp[5], hp[6], hp[7]);
    *(uint4*)&Bl[pl][icg * 16] = make_uint4(lp[0], lp[1], lp[2], lp[3]);
    *(uint4*)&Bl[pl][icg * 16 + 8] = make_uint4(lp[4], lp[5], lp[6], lp[7]);
    __syncthreads();
    mfma_chunk(Ah, Al, Bh, Bl, acc, wave * 16, lane);
    xb += 4 * 4356;
  }
#pragma unroll
  for (int r = 0; r < 4; ++r) {
    int oc = oc0 + wave * 16 + quad * 4 + r;
#pragma unroll
    for (int nt = 0; nt < 4; ++nt)
      xd[((size_t)(bimg * 256 + oc)) * 1024 + pos + nt * 16 + l16] = acc[nt][r];
  }
}

// ---------------- qkv projection: emits q/k hi-lo + v transposed hi-lo -----
// MODE0: coarse (src=xd + cbias fused). MODE1: fine gather via topk.
template <int MODE>
__global__ __launch_bounds__(256) void k_qkv_mfma(
    const float* __restrict__ src, const float* __restrict__ cbias,
    const unsigned short* __restrict__ wh, const unsigned short* __restrict__ wl,
    const float* __restrict__ bq, const int* __restrict__ topk,
    unsigned short* __restrict__ qh, unsigned short* __restrict__ ql,
    unsigned short* __restrict__ kh, unsigned short* __restrict__ kl,
    unsigned short* __restrict__ vth, unsigned short* __restrict__ vtl) {
  __shared__ unsigned short Ah[64][72], Al[64][72];
  const int t = threadIdx.x;
  const int tok0 = blockIdx.x * 64;
  const int pair = blockIdx.y;
  const int b = pair >> 2, h = pair & 3;
  const int tokl = t & 63, dg = t >> 6;
  float fv[16];
  if (MODE == 0) {
    const float* base = src + ((size_t)(b * 256 + h * 64 + dg * 16)) * 1024 + tok0 + tokl;
    const float* cb = cbias + h * 64 + dg * 16;
#pragma unroll
    for (int j = 0; j < 16; ++j) fv[j] = base[(size_t)j * 1024] + cb[j];
  } else {
    int tok = tok0 + tokl;
    int pp = topk[pair * 256 + (tok >> 2)];
    int py = (tok >> 1) & 1, px = tok & 1;
    int ry = (pp >> 5) * 2 + py, rx = (pp & 31) * 2 + px;
    const float* base = src + ((size_t)(b * 256 + h * 64 + dg * 16)) * 4096 + ry * 64 + rx;
#pragma unroll
    for (int j = 0; j < 16; ++j) fv[j] = base[(size_t)j * 4096];
  }
  unsigned hp[8], lp[8];
#pragma unroll
  for (int j = 0; j < 8; ++j) cvt2(fv[2 * j], fv[2 * j + 1], hp[j], lp[j]);
  *(uint4*)&Ah[tokl][dg * 16] = make_uint4(hp[0], hp[1], hp[2], hp[3]);
  *(uint4*)&Ah[tokl][dg * 16 + 8] = make_uint4(hp[4], hp[5], hp[6], hp[7]);
  *(uint4*)&Al[tokl][dg * 16] = make_uint4(lp[0], lp[1], lp[2], lp[3]);
  *(uint4*)&Al[tokl][dg * 16 + 8] = make_uint4(lp[4], lp[5], lp[6], lp[7]);
  __syncthreads();
  const int wave = t >> 6, lane = t & 63, l16 = lane & 15, quad = lane >> 4;
  f32x4_t acc[4][3] = {};
#pragma unroll
  for (int ks = 0; ks < 2; ++ks) {
    int ko = ks * 32 + quad * 8;
    bf16x8_t bh0[3], bl0[3];
#pragma unroll
    for (int nt = 0; nt < 3; ++nt) {
      int col = wave * 48 + nt * 16 + l16;
      bh0[nt] = *(const bf16x8_t*)(wh + col * 64 + ko);
      bl0[nt] = *(const bf16x8_t*)(wl + col * 64 + ko);
    }
#pragma unroll
    for (int mt = 0; mt < 4; ++mt) {
      bf16x8_t ah = *(const bf16x8_t*)&Ah[mt * 16 + l16][ko];
      bf16x8_t al = *(const bf16x8_t*)&Al[mt * 16 + l16][ko];
#pragma unroll
      for (int nt = 0; nt < 3; ++nt) {
        acc[mt][nt] = MFMA16(ah, bh0[nt], acc[mt][nt]);
        acc[mt][nt] = MFMA16(ah, bl0[nt], acc[mt][nt]);
        acc[mt][nt] = MFMA16(al, bh0[nt], acc[mt][nt]);
      }
    }
  }
#pragma unroll
  for (int nt = 0; nt < 3; ++nt) {
    int col = wave * 48 + nt * 16 + l16;
    float bqv = bq[col];
    if (col < 64) bqv *= 0.125f;
#pragma unroll
    for (int mt = 0; mt < 4; ++mt) {
#pragma unroll
      for (int r = 0; r < 4; ++r) {
        int tok = tok0 + mt * 16 + quad * 4 + r;
        float val = acc[mt][nt][r] + bqv;
        unsigned short hh, ll;
        cvt1(val, hh, ll);
        if (col < 64) {
          size_t o = ((size_t)pair * 1024 + tok) * 64 + col;
          qh[o] = hh; ql[o] = ll;
        } else if (col < 128) {
          size_t o = ((size_t)pair * 1024 + tok) * 64 + (col - 64);
          kh[o] = hh; kl[o] = ll;
        } else {
          size_t o = ((size_t)pair * 64 + (col - 128)) * 1024 + tok;
          vth[o] = hh; vtl[o] = ll;
        }
      }
    }
  }
}

// ---------------- S = q' @ k^T (scale pre-folded), fp32 out ----------------
__global__ __launch_bounds__(256) void k_qk_mfma(
    const unsigned short* __restrict__ qh, const unsigned short* __restrict__ ql,
    const unsigned short* __restrict__ kh, const unsigned short* __restrict__ kl,
    float* __restrict__ S, int pair0) {
  __shared__ unsigned short Ah[64][72], Al[64][72], Bh[64][72], Bl[64][72];
  const int t = threadIdx.x;
  const int k0 = blockIdx.x * 64, q0 = blockIdx.y * 64;
  const int lp = blockIdx.z;
  const int pair = pair0 + lp;
  const size_t qbase = ((size_t)pair * 1024 + q0) * 64;
  const size_t kbase = ((size_t)pair * 1024 + k0) * 64;
#pragma unroll
  for (int i = 0; i < 2; ++i) {
    int e = t + i * 256;
    int r = e >> 3, kc = (e & 7) * 8;
    *(bf16x8_t*)&Ah[r][kc] = *(const bf16x8_t*)(qh + qbase + (size_t)r * 64 + kc);
    *(bf16x8_t*)&Al[r][kc] = *(const bf16x8_t*)(ql + qbase + (size_t)r * 64 + kc);
    *(bf16x8_t*)&Bh[r][kc] = *(const bf16x8_t*)(kh + kbase + (size_t)r * 64 + kc);
    *(bf16x8_t*)&Bl[r][kc] = *(const bf16x8_t*)(kl + kbase + (size_t)r * 64 + kc);
  }
  __syncthreads();
  const int wave = t >> 6, lane = t & 63;
  f32x4_t acc[4] = {};
  mfma_chunk(Ah, Al, Bh, Bl, acc, wave * 16, lane);
  const int l16 = lane & 15, quad = lane >> 4;
#pragma unroll
  for (int nt = 0; nt < 4; ++nt)
#pragma unroll
    for (int r = 0; r < 4; ++r) {
      int qm = q0 + wave * 16 + quad * 4 + r;
      int kn = k0 + nt * 16 + l16;
      S[((size_t)lp * 1024 + qm) * 1024 + kn] = acc[nt][r];
    }
}

// ---------------- row softmax -> bf16 hi/lo P ------------------------------
__global__ __launch_bounds__(256) void k_softmax(
    const float* __restrict__ S, unsigned short* __restrict__ ph,
    unsigned short* __restrict__ pl) {
  const int row = blockIdx.x;
  const float* r = S + (size_t)row * 1024;
  const int t = threadIdx.x;
  __shared__ float red[4];
  __shared__ float bcast;
  float4 v = *(const float4*)&r[t * 4];
  float m = fmaxf(fmaxf(v.x, v.y), fmaxf(v.z, v.w));
#pragma unroll
  for (int off = 32; off > 0; off >>= 1) m = fmaxf(m, __shfl_down(m, off));
  if ((t & 63) == 0) red[t >> 6] = m;
  __syncthreads();
  if (t == 0) bcast = fmaxf(fmaxf(red[0], red[1]), fmaxf(red[2], red[3]));
  __syncthreads();
  m = bcast;
  v.x = __expf(v.x - m); v.y = __expf(v.y - m);
  v.z = __expf(v.z - m); v.w = __expf(v.w - m);
  float s = v.x + v.y + v.z + v.w;
#pragma unroll
  for (int off = 32; off > 0; off >>= 1) s += __shfl_down(s, off);
  __syncthreads();
  if ((t & 63) == 0) red[t >> 6] = s;
  __syncthreads();
  if (t == 0) bcast = red[0] + red[1] + red[2] + red[3];
  __syncthreads();
  float inv = 1.0f / bcast;
  v.x *= inv; v.y *= inv; v.z *= inv; v.w *= inv;
  unsigned h0, l0, h1, l1;
  cvt2(v.x, v.y, h0, l0);
  cvt2(v.z, v.w, h1, l1);
  *(uint2*)&ph[(size_t)row * 1024 + t * 4] = make_uint2(h0, h1);
  *(uint2*)&pl[(size_t)row * 1024 + t * 4] = make_uint2(l0, l1);
}

// ---------------- coarse_score[k] += sum_q P[q][k] (from hi/lo) ------------
__global__ __launch_bounds__(256) void k_score_hl(
    const unsigned short* __restrict__ ph, const unsigned short* __restrict__ pl,
    float* __restrict__ score, int pair0) {
  const int t = threadIdx.x;
  const int kbase = blockIdx.x * 256;
  const int qc = blockIdx.y;
  const int lp = blockIdx.z;
  const unsigned short* bh = ph + ((size_t)lp * 1024 + qc * 128) * 1024 + kbase + t;
  const unsigned short* bl = pl + ((size_t)lp * 1024 + qc * 128) * 1024 + kbase + t;
  float s = 0.f;
  for (int qq = 0; qq < 128; ++qq)
    s += bfh(bh[(size_t)qq * 1024]) + bfh(bl[(size_t)qq * 1024]);
  atomicAdd(&score[(pair0 + lp) * 1024 + kbase + t], s);
}

// ---------------- per-pair top-256 via bitonic sort ------------------------
__global__ __launch_bounds__(256) void k_topk(
    const float* __restrict__ score, int* __restrict__ idx) {
  __shared__ unsigned long long key[1024];
  const int pair = blockIdx.x;
  const int t = threadIdx.x;
#pragma unroll
  for (int j = 0; j < 4; ++j) {
    int i = t + j * 256;
    unsigned u = __float_as_uint(score[pair * 1024 + i]);
    u = u ^ ((u & 0x80000000u) ? 0xFFFFFFFFu : 0x80000000u);
    u = ~u;
    key[i] = ((unsigned long long)u << 32) | (unsigned)i;
  }
  __syncthreads();
  for (int k = 2; k <= 1024; k <<= 1) {
    for (int j = k >> 1; j > 0; j >>= 1) {
      for (int w = 0; w < 4; ++w) {
        int i = t + w * 256;
        int l = i ^ j;
        if (l > i) {
          bool up = ((i & k) == 0);
          unsigned long long a = key[i], b = key[l];
          if ((a > b) == up) { key[i] = b; key[l] = a; }
        }
      }
      __syncthreads();
    }
  }
  idx[pair * 256 + t] = (int)(key[t] & 0xFFFFFFFFu);
}

// ---------------- AV: out = P @ V ------------------------------------------
template <int COARSE>
__global__ __launch_bounds__(256) void k_av_mfma(
    const unsigned short* __restrict__ ph, const unsigned short* __restrict__ pl,
    const unsigned short* __restrict__ vth, const unsigned short* __restrict__ vtl,
    float* __restrict__ out, int pair0) {
  __shared__ unsigned short Ah[64][72], Al[64][72], Bh[64][72], Bl[64][72];
  __shared__ float Tr[64][68];
  const int t = threadIdx.x;
  const int q0 = blockIdx.x * 64;
  const int lp = blockIdx.y;
  const int pair = pair0 + lp;
  const int wave = t >> 6, lane = t & 63;
  const int l16 = lane & 15, quad = lane >> 4;
  f32x4_t acc[4] = {};
  const size_t abase = ((size_t)lp * 1024 + q0) * 1024;
  const size_t bbase = (size_t)pair * 64 * 1024;
  for (int kb = 0; kb < 1024; kb += 64) {
#pragma unroll
    for (int i = 0; i < 2; ++i) {
      int e = t + i * 256;
      int r = e >> 3, kc = (e & 7) * 8;
      *(bf16x8_t*)&Ah[r][kc] = *(const bf16x8_t*)(ph + abase + (size_t)r * 1024 + kb + kc);
      *(bf16x8_t*)&Al[r][kc] = *(const bf16x8_t*)(pl + abase + (size_t)r * 1024 + kb + kc);
      *(bf16x8_t*)&Bh[r][kc] = *(const bf16x8_t*)(vth + bbase + (size_t)r * 1024 + kb + kc);
      *(bf16x8_t*)&Bl[r][kc] = *(const bf16x8_t*)(vtl + bbase + (size_t)r * 1024 + kb + kc);
    }
    __syncthreads();
    mfma_chunk(Ah, Al, Bh, Bl, acc, wave * 16, lane);
    __syncthreads();
  }
  if (COARSE) {
#pragma unroll
    for (int nt = 0; nt < 4; ++nt)
#pragma unroll
      for (int r = 0; r < 4; ++r)
        Tr[nt * 16 + l16][wave * 16 + quad * 4 + r] = acc[nt][r];
    __syncthreads();
    const int b = pair >> 2, h = pair & 3;
#pragma unroll
    for (int i = 0; i < 16; ++i) {
      int e = t + i * 256;
      int d = e >> 6, ql_ = e & 63;
      int pix = q0 + ql_;
      int iy = (pix >> 5) + 1, ix = (pix & 31) + 1;
      out[((size_t)(b * 256 + h * 64 + d)) * 1156 + iy * 34 + ix] = Tr[d][ql_];
    }
  } else {
#pragma unroll
    for (int nt = 0; nt < 4; ++nt)
#pragma unroll
      for (int r = 0; r < 4; ++r) {
        int qm = q0 + wave * 16 + quad * 4 + r;
        int dn = nt * 16 + l16;
        out[((size_t)pair * 1024 + qm) * 64 + dn] = acc[nt][r];
      }
  }
}

// ---------------- convT as 4-class GEMM ------------------------------------
__global__ __launch_bounds__(256) void k_convT_mfma(
    const float* __restrict__ inp, const unsigned short* __restrict__ wth,
    const unsigned short* __restrict__ wtl, const float* __restrict__ bias,
    float* __restrict__ out) {
  __shared__ unsigned short Ah[64][72], Al[64][72], Bh[64][72], Bl[64][72];
  const int t = threadIdx.x;
  const int pix0 = blockIdx.x * 64;
  const int oc0 = blockIdx.y * 64;
  const int cls = blockIdx.z;
  const int ry = cls >> 1, rx = cls & 1;
  const int b = pix0 >> 10;
  const int wave = t >> 6, lane = t & 63;
  const int l16 = lane & 15, quad = lane >> 4;
  const int pixl = t & 63, icg = t >> 6;
  const int remg = (pix0 + pixl) & 1023;
  const int tyy = remg >> 5, txx = remg & 31;
  f32x4_t acc[4] = {};
  const size_t wbase = ((size_t)cls * 256 + oc0) * 1024;
  for (int kb = 0; kb < 1024; kb += 64) {
    const int tap = kb >> 8, ic0 = kb & 255;
    const int tk = tap >> 1, txi = tap & 1;
    const int iy = tyy + ry + 1 - tk, ix = txx + rx + 1 - txi;
    const float* p = inp + (size_t)(b * 256 + ic0 + icg * 16) * 1156 + iy * 34 + ix;
    float fv[16];
#pragma unroll
    for (int j = 0; j < 16; ++j) fv[j] = p[(size_t)j * 1156];
    unsigned hp[8], lpk[8];
#pragma unroll
    for (int j = 0; j < 8; ++j) cvt2(fv[2 * j], fv[2 * j + 1], hp[j], lpk[j]);
    bf16x8_t a0h, a0l, a1h, a1l;
    {
      int r = t >> 3, kc = (t & 7) * 8;
      a0h = *(const bf16x8_t*)(wth + wbase + (size_t)r * 1024 + kb + kc);
      a0l = *(const bf16x8_t*)(wtl + wbase + (size_t)r * 1024 + kb + kc);
      a1h = *(const bf16x8_t*)(wth + wbase + (size_t)(r + 32) * 1024 + kb + kc);
      a1l = *(const bf16x8_t*)(wtl + wbase + (size_t)(r + 32) * 1024 + kb + kc);
    }
    __syncthreads();
    {
      int r = t >> 3, kc = (t & 7) * 8;
      *(bf16x8_t*)&Ah[r][kc] = a0h;      *(bf16x8_t*)&Al[r][kc] = a0l;
      *(bf16x8_t*)&Ah[r + 32][kc] = a1h; *(bf16x8_t*)&Al[r + 32][kc] = a1l;
    }
    *(uint4*)&Bh[pixl][icg * 16] = make_uint4(hp[0], hp[1], hp[2], hp[3]);
    *(uint4*)&Bh[pixl][icg * 16 + 8] = make_uint4(hp[4], hp[5], hp[6], hp[7]);
    *(uint4*)&Bl[pixl][icg * 16] = make_uint4(lpk[0], lpk[1], lpk[2], lpk[3]);
    *(uint4*)&Bl[pixl][icg * 16 + 8] = make_uint4(lpk[4], lpk[5], lpk[6], lpk[7]);
    __syncthreads();
    mfma_chunk(Ah, Al, Bh, Bl, acc, wave * 16, lane);
  }
  __syncthreads();
#pragma unroll
  for (int r = 0; r < 4; ++r) {
    int oc = oc0 + wave * 16 + quad * 4 + r;
    float bvs = bias[oc];
#pragma unroll
    for (int nt = 0; nt < 4; ++nt) {
      int pix = pix0 + nt * 16 + l16;
      int rem2 = pix & 1023;
      int y = (rem2 >> 5) * 2 + ry, xx = (rem2 & 31) * 2 + rx;
      out[((size_t)(b * 256 + oc) * 64 + y) * 64 + xx] = acc[nt][r] + bvs;
    }
  }
}

// ---------------- scatter fine outputs into y ------------------------------
__global__ __launch_bounds__(256) void k_scatter(
    const float* __restrict__ outf, const int* __restrict__ idx,
    float* __restrict__ y) {
  int g = blockIdx.x * 256 + threadIdx.x;
  int pair = g >> 16;
  int rem = g & 65535;
  int tok = rem >> 6, d = rem & 63;
  int b = pair >> 2, h = pair & 3;
  int pp = idx[pair * 256 + (tok >> 2)];
  int py = (tok >> 1) & 1, px = tok & 1;
  int ry = (pp >> 5) * 2 + py, rx = (pp & 31) * 2 + px;
  y[((size_t)(b * 256 + h * 64 + d) * 64 + ry) * 64 + rx] += outf[g];
}

// ---------------- depthwise 3x3 + BN + relu6 (fp32) ------------------------
__global__ __launch_bounds__(256) void k_dwconv(
    const float* __restrict__ y, const float* __restrict__ wdw,
    const float* __restrict__ g, const float* __restrict__ bb,
    const float* __restrict__ m, const float* __restrict__ vv,
    float* __restrict__ yd) {
  int gi = blockIdx.x * 256 + threadIdx.x;
  int x = gi & 63, yy = (gi >> 6) & 63, ch = (gi >> 12) & 255, b = gi >> 20;
  const float* plane = y + (size_t)(b * 256 + ch) * 4096;
  const float* wc = wdw + ch * 9;
  float s = 0.f;
#pragma unroll
  for (int ky = 0; ky < 3; ++ky) {
    int iy = yy + ky - 1;
    if (iy < 0 || iy >= 64) continue;
#pragma unroll
    for (int kx = 0; kx < 3; ++kx) {
      int ix = x + kx - 1;
      if (ix < 0 || ix >= 64) continue;
      s = fmaf(plane[iy * 64 + ix], wc[ky * 3 + kx], s);
    }
  }
  float sc = g[ch] * rsqrtf(vv[ch] + EPS_);
  float val = s * sc + (bb[ch] - m[ch] * sc);
  yd[gi] = fminf(fmaxf(val, 0.f), 6.f);
}

// ---------------- pointwise 1x1 + BN + relu6 -------------------------------
__global__ __launch_bounds__(256) void k_pw_mfma(
    const float* __restrict__ yd, const unsigned short* __restrict__ wh,
    const unsigned short* __restrict__ wl, const float* __restrict__ g,
    const float* __restrict__ bb, const float* __restrict__ m,
    const float* __restrict__ vv, float* __restrict__ out) {
  __shared__ unsigned short Ah[64][72], Al[64][72], Bh[64][72], Bl[64][72];
  const int t = threadIdx.x;
  const int pix0 = blockIdx.x * 64;
  const int oc0 = blockIdx.y * 64;
  const int b = pix0 >> 12, pos0 = pix0 & 4095;
  const int wave = t >> 6, lane = t & 63;
  const int l16 = lane & 15, quad = lane >> 4;
  const int pixl = t & 63, icg = t >> 6;
  f32x4_t acc[4] = {};
  for (int kb = 0; kb < 256; kb += 64) {
    float fv[16];
#pragma unroll
    for (int j = 0; j < 16; ++j)
      fv[j] = yd[(size_t)(b * 256 + kb + icg * 16 + j) * 4096 + pos0 + pixl];
    unsigned hp[8], lpk[8];
#pragma unroll
    for (int j = 0; j < 8; ++j) cvt2(fv[2 * j], fv[2 * j + 1], hp[j], lpk[j]);
    bf16x8_t a0h, a0l, a1h, a1l;
    {
      int r = t >> 3, kc = (t & 7) * 8;
      a0h = *(const bf16x8_t*)(wh + (size_t)(oc0 + r) * 256 + kb + kc);
      a0l = *(const bf16x8_t*)(wl + (size_t)(oc0 + r) * 256 + kb + kc);
      a1h = *(const bf16x8_t*)(wh + (size_t)(oc0 + r + 32) * 256 + kb + kc);
      a1l = *(const bf16x8_t*)(wl + (size_t)(oc0 + r + 32) * 256 + kb + kc);
    }
    __syncthreads();
    {
      int r = t >> 3, kc = (t & 7) * 8;
      *(bf16x8_t*)&Ah[r][kc] = a0h;      *(bf16x8_t*)&Al[r][kc] = a0l;
      *(bf16x8_t*)&Ah[r + 32][kc] = a1h; *(bf16x8_t*)&Al[r + 32][kc] = a1l;
    }
    *(uint4*)&Bh[pixl][icg * 16] = make_uint4(hp[0], hp[1], hp[2], hp[3]);
    *(uint4*)&Bh[pixl][icg * 16 + 8] = make_uint4(hp[4], hp[5], hp[6], hp[7]);
    *(uint4*)&Bl[pixl][icg * 16] = make_uint4(lpk[0], lpk[1], lpk[2], lpk[3]);
    *(uint4*)&Bl[pixl][icg * 16 + 8] = make_uint4(lpk[4], lpk[5], lpk[6], lpk[7]);
    __syncthreads();
    mfma_chunk(Ah, Al, Bh, Bl, acc, wave * 16, lane);
    __syncthreads();
  }
#pragma unroll
  for (int r = 0; r < 4; ++r) {
    int oc = oc0 + wave * 16 + quad * 4 + r;
    float sc = g[oc] * rsqrtf(vv[oc] + EPS_);
    float off = bb[oc] - m[oc] * sc;
#pragma unroll
    for (int nt = 0; nt < 4; ++nt) {
      int pix = pos0 + nt * 16 + l16;
      float val = fminf(fmaxf(acc[nt][r] * sc + off, 0.f), 6.f);
      out[(size_t)(b * 256 + oc) * 4096 + pix] = val;
    }
  }
}

// ---------------------------------------------------------------------------
extern "C" void kernel_launch(void* const* d_in, const int* in_sizes, int n_in,
                              void* d_out, int out_size, void* d_ws, size_t ws_size,
                              hipStream_t stream) {
  (void)in_sizes; (void)n_in; (void)out_size; (void)ws_size;
  const float* x       = (const float*)d_in[0];
  const float* w_down  = (const float*)d_in[1];
  const float* b_down  = (const float*)d_in[2];
  const float* w_qkv_c = (const float*)d_in[3];
  const float* b_qkv_c = (const float*)d_in[4];
  const float* w_up    = (const float*)d_in[5];
  const float* b_up    = (const float*)d_in[6];
  const float* w_qkv_f = (const float*)d_in[7];
  const float* b_qkv_f = (const float*)d_in[8];
  const float* w_dw    = (const float*)d_in[9];
  const float* bn_dw_g = (const float*)d_in[10];
  const float* bn_dw_b = (const float*)d_in[11];
  const float* bn_dw_m = (const float*)d_in[12];
  const float* bn_dw_v = (const float*)d_in[13];
  const float* w_pw    = (const float*)d_in[14];
  const float* bn_pw_g = (const float*)d_in[15];
  const float* bn_pw_b = (const float*)d_in[16];
  const float* bn_pw_m = (const float*)d_in[17];
  const float* bn_pw_v = (const float*)d_in[18];

  float* ws = (float*)d_ws;  // offsets in float units, ~228 MB total
  float*          S      = ws;                              // 16,777,216 f (alias xp, yd)
  unsigned short* S_hi   = (unsigned short*)(ws + 16777216);
  unsigned short* S_lo   = (unsigned short*)(ws + 25165824);
  unsigned short* qh     = (unsigned short*)(ws + 33554432);
  unsigned short* ql     = (unsigned short*)(ws + 34603008);
  unsigned short* kh     = (unsigned short*)(ws + 35651584);
  unsigned short* kl     = (unsigned short*)(ws + 36700160);
  unsigned short* vth    = (unsigned short*)(ws + 37748736);
  unsigned short* vtl    = (unsigned short*)(ws + 38797312);
  float*          xd     = ws + 39845888;                   // 2,097,152 f
  float*          outcp  = ws + 41943040;                   // 2,367,488 f
  float*          coarse = ws + 44310528;                   // 8,388,608 f
  float*          outf   = ws + 52699136;                   // 2,097,152 f
  float*          score  = ws + 54796288;                   // 32,768 f
  unsigned short* wdh    = (unsigned short*)(ws + 54829056);
  unsigned short* wdl    = (unsigned short*)(ws + 55353344);
  unsigned short* wt_hi  = (unsigned short*)(ws + 55877632);
  unsigned short* wt_lo  = (unsigned short*)(ws + 56401920);
  unsigned short* wpw_hi = (unsigned short*)(ws + 56926208);
  unsigned short* wpw_lo = (unsigned short*)(ws + 56958976);
  unsigned short* wqh_c  = (unsigned short*)(ws + 56991744);
  unsigned short* wql_c  = (unsigned short*)(ws + 56997888);
  unsigned short* wqh_f  = (unsigned short*)(ws + 57004032);
  unsigned short* wql_f  = (unsigned short*)(ws + 57010176);
  int*            idx    = (int*)(ws + 57016320);           // 8,192 int
  float*          xp     = S;                               // dead before coarse qk
  float*          yd     = S;                               // dead after fine softmax

  hipMemsetAsync(score, 0, 32768 * sizeof(float), stream);
  hipMemsetAsync(outcp, 0, (size_t)2367488 * sizeof(float), stream);
  k_pad_x<<<2048, 256, 0, stream>>>(x, xp);
  k_cvt_wdown<<<4096, 256, 0, stream>>>(w_down, wdh, wdl);
  k_cvt_wqkv<<<48, 256, 0, stream>>>(w_qkv_c, wqh_c, wql_c);
  k_cvt_wqkv<<<48, 256, 0, stream>>>(w_qkv_f, wqh_f, wql_f);
  k_cvt_wup<<<4096, 256, 0, stream>>>(w_up, wt_hi, wt_lo);
  k_cvt_wpw<<<256, 256, 0, stream>>>(w_pw, wpw_hi, wpw_lo);

  k_conv_down_mfma<<<dim3(128, 4), 256, 0, stream>>>(xp, wdh, wdl, xd);
  k_qkv_mfma<0><<<dim3(16, 32), 256, 0, stream>>>(xd, b_down, wqh_c, wql_c, b_qkv_c,
                                                  nullptr, qh, ql, kh, kl, vth, vtl);
  for (int s = 0; s < 2; ++s) {
    int pair0 = s * 16;
    k_qk_mfma<<<dim3(16, 16, 16), 256, 0, stream>>>(qh, ql, kh, kl, S, pair0);
    k_softmax<<<16384, 256, 0, stream>>>(S, S_hi, S_lo);
    k_score_hl<<<dim3(4, 8, 16), 256, 0, stream>>>(S_hi, S_lo, score, pair0);
    k_av_mfma<1><<<dim3(16, 16), 256, 0, stream>>>(S_hi, S_lo, vth, vtl, outcp, pair0);
  }
  k_topk<<<32, 256, 0, stream>>>(score, idx);
  k_convT_mfma<<<dim3(128, 4, 4), 256, 0, stream>>>(outcp, wt_hi, wt_lo, b_up, coarse);

  k_qkv_mfma<1><<<dim3(16, 32), 256, 0, stream>>>(coarse, nullptr, wqh_f, wql_f, b_qkv_f,
                                                  idx, qh, ql, kh, kl, vth, vtl);
  for (int s = 0; s < 2; ++s) {
    int pair0 = s * 16;
    k_qk_mfma<<<dim3(16, 16, 16), 256, 0, stream>>>(qh, ql, kh, kl, S, pair0);
    k_softmax<<<16384, 256, 0, stream>>>(S, S_hi, S_lo);
    k_av_mfma<0><<<dim3(16, 16), 256, 0, stream>>>(S_hi, S_lo, vth, vtl, outf, pair0);
  }
  k_scatter<<<8192, 256, 0, stream>>>(outf, idx, coarse);
  k_dwconv<<<32768, 256, 0, stream>>>(coarse, w_dw, bn_dw_g, bn_dw_b, bn_dw_m, bn_dw_v, yd);
  k_pw_mfma<<<dim3(512, 4), 256, 0, stream>>>(yd, wpw_hi, wpw_lo, bn_pw_g, bn_pw_b,
                                              bn_pw_m, bn_pw_v, (float*)d_out);
}

// Round 5
// 638.407 us; speedup vs baseline: 2.5587x; 1.2803x over previous
//
#include <hip/hip_runtime.h>
#include <cstdint>
#include <cstddef>

// ---------------------------------------------------------------------------
// RegionSelectionAttention. Round 5: flash-fused attention (QK^T + online
// softmax + colsum + PV in one kernel per phase). All GEMMs bf16x3 MFMA.
// ---------------------------------------------------------------------------

#define EPS_ 1e-5f

typedef short bf16x8_t __attribute__((ext_vector_type(8)));
typedef float f32x4_t __attribute__((ext_vector_type(4)));
#define MFMA16(a, b, c) __builtin_amdgcn_mfma_f32_16x16x32_bf16(a, b, c, 0, 0, 0)

__device__ __forceinline__ void cvt1(float f, unsigned short& h, unsigned short& l) {
  unsigned u = __float_as_uint(f);
  unsigned r = u + 0x7FFFu + ((u >> 16) & 1u);
  h = (unsigned short)(r >> 16);
  float lo = f - __uint_as_float(r & 0xFFFF0000u);
  l = (unsigned short)(__float_as_uint(lo) >> 16);
}
__device__ __forceinline__ void cvt2(float f0, float f1, unsigned& hpack, unsigned& lpack) {
  unsigned u0 = __float_as_uint(f0), u1 = __float_as_uint(f1);
  unsigned r0 = u0 + 0x7FFFu + ((u0 >> 16) & 1u);
  unsigned r1 = u1 + 0x7FFFu + ((u1 >> 16) & 1u);
  hpack = (r0 >> 16) | (r1 & 0xFFFF0000u);
  float l0 = f0 - __uint_as_float(r0 & 0xFFFF0000u);
  float l1 = f1 - __uint_as_float(r1 & 0xFFFF0000u);
  lpack = (__float_as_uint(l0) >> 16) | (__float_as_uint(l1) & 0xFFFF0000u);
}

// ---------------- pad x -> xp[plane][66][66] (zero border) -----------------
__global__ __launch_bounds__(256) void k_pad_x(
    const float* __restrict__ x, float* __restrict__ xp) {
  const int plane = blockIdx.x;  // 2048
  const float* src = x + (size_t)plane * 4096;
  float* dst = xp + (size_t)plane * 4356;
  for (int e = threadIdx.x; e < 4356; e += 256) {
    int r = e / 66, cc = e - r * 66;
    float v = 0.f;
    if (r >= 1 && r <= 64 && cc >= 1 && cc <= 64) v = src[(r - 1) * 64 + (cc - 1)];
    dst[e] = v;
  }
}

// ---------------- weight conversions ---------------------------------------
__global__ __launch_bounds__(256) void k_cvt_wdown(
    const float* __restrict__ w, unsigned short* __restrict__ wh,
    unsigned short* __restrict__ wl) {
  int e = blockIdx.x * 256 + threadIdx.x;  // 1,048,576: [oc][4096]
  cvt1(w[e], wh[e], wl[e]);
}

__global__ __launch_bounds__(256) void k_cvt_wqkv(
    const float* __restrict__ wq, unsigned short* __restrict__ wh,
    unsigned short* __restrict__ wl) {
  int e = blockIdx.x * 256 + threadIdx.x;  // 12288: [col][d]
  int col = e >> 6, d = e & 63;
  float f = wq[d * 192 + col];
  if (col < 64) f *= 0.125f;  // fold attn scale into q (pow2: exact)
  cvt1(f, wh[e], wl[e]);
}

__global__ __launch_bounds__(256) void k_cvt_wup(
    const float* __restrict__ w_up, unsigned short* __restrict__ wth,
    unsigned short* __restrict__ wtl) {
  int e = blockIdx.x * 256 + threadIdx.x;  // 2^20: [class][oc][kp=tap*256+ic]
  int kp = e & 1023, oc = (e >> 10) & 255, c = e >> 18;
  int tap = kp >> 8, ic = kp & 255;
  int tk = tap >> 1, txi = tap & 1;
  int ry = c >> 1, rx = c & 1;
  int ky = (1 - ry) + 2 * tk, kx = (1 - rx) + 2 * txi;
  cvt1(w_up[((size_t)(ic * 256 + oc) * 4 + ky) * 4 + kx], wth[e], wtl[e]);
}

__global__ __launch_bounds__(256) void k_cvt_wpw(
    const float* __restrict__ w, unsigned short* __restrict__ wh,
    unsigned short* __restrict__ wl) {
  int e = blockIdx.x * 256 + threadIdx.x;  // 65536 [oc][ic]
  cvt1(w[e], wh[e], wl[e]);
}

// ====================== bf16x3 MFMA core ===================================
__device__ __forceinline__ void mfma_chunk(
    const unsigned short (*Ah)[72], const unsigned short (*Al)[72],
    const unsigned short (*Bh)[72], const unsigned short (*Bl)[72],
    f32x4_t (&acc)[4], int wm, int lane) {
  const int l16 = lane & 15, quad = lane >> 4;
#pragma unroll
  for (int ks = 0; ks < 2; ++ks) {
    int ko = ks * 32 + quad * 8;
    bf16x8_t ah = *(const bf16x8_t*)&Ah[wm + l16][ko];
    bf16x8_t al = *(const bf16x8_t*)&Al[wm + l16][ko];
#pragma unroll
    for (int nt = 0; nt < 4; ++nt) {
      bf16x8_t bh = *(const bf16x8_t*)&Bh[nt * 16 + l16][ko];
      bf16x8_t bl = *(const bf16x8_t*)&Bl[nt * 16 + l16][ko];
      acc[nt] = MFMA16(ah, bh, acc[nt]);
      acc[nt] = MFMA16(ah, bl, acc[nt]);
      acc[nt] = MFMA16(al, bh, acc[nt]);
    }
  }
}

// ---------------- conv down k4 s2 p1 as implicit GEMM, K=4096 --------------
__global__ __launch_bounds__(256) void k_conv_down_mfma(
    const float* __restrict__ xp, const unsigned short* __restrict__ wdh,
    const unsigned short* __restrict__ wdl, float* __restrict__ xd) {
  __shared__ unsigned short Ah[64][72], Al[64][72], Bh[64][72], Bl[64][72];
  const int t = threadIdx.x;
  const int pix0 = blockIdx.x * 64, oc0 = blockIdx.y * 64;
  const int bimg = pix0 >> 10, pos = pix0 & 1023;
  const int pl = t & 63, icg = t >> 6;
  const int rem = (pix0 + pl) & 1023;
  const int oy = rem >> 5, ox = rem & 31;
  const float* xb = xp + ((size_t)bimg * 256 + icg) * 4356 + (oy * 2) * 66 + ox * 2;
  const int wave = t >> 6, lane = t & 63, l16 = lane & 15, quad = lane >> 4;
  const int ar = t >> 3, akc = (t & 7) * 8;
  f32x4_t acc[4] = {};
  for (int kb = 0; kb < 4096; kb += 64) {
    bf16x8_t a0h = *(const bf16x8_t*)(wdh + (size_t)(oc0 + ar) * 4096 + kb + akc);
    bf16x8_t a0l = *(const bf16x8_t*)(wdl + (size_t)(oc0 + ar) * 4096 + kb + akc);
    bf16x8_t a1h = *(const bf16x8_t*)(wdh + (size_t)(oc0 + 32 + ar) * 4096 + kb + akc);
    bf16x8_t a1l = *(const bf16x8_t*)(wdl + (size_t)(oc0 + 32 + ar) * 4096 + kb + akc);
    float fv[16];
#pragma unroll
    for (int tap = 0; tap < 16; ++tap) fv[tap] = xb[(tap >> 2) * 66 + (tap & 3)];
    unsigned hp[8], lp[8];
#pragma unroll
    for (int j = 0; j < 8; ++j) cvt2(fv[2 * j], fv[2 * j + 1], hp[j], lp[j]);
    __syncthreads();
    *(bf16x8_t*)&Ah[ar][akc] = a0h;      *(bf16x8_t*)&Al[ar][akc] = a0l;
    *(bf16x8_t*)&Ah[ar + 32][akc] = a1h; *(bf16x8_t*)&Al[ar + 32][akc] = a1l;
    *(uint4*)&Bh[pl][icg * 16] = make_uint4(hp[0], hp[1], hp[2], hp[3]);
    *(uint4*)&Bh[pl][icg * 16 + 8] = make_uint4(hp[4], hp[5], hp[6], hp[7]);
    *(uint4*)&Bl[pl][icg * 16] = make_uint4(lp[0], lp[1], lp[2], lp[3]);
    *(uint4*)&Bl[pl][icg * 16 + 8] = make_uint4(lp[4], lp[5], lp[6], lp[7]);
    __syncthreads();
    mfma_chunk(Ah, Al, Bh, Bl, acc, wave * 16, lane);
    xb += 4 * 4356;
  }
#pragma unroll
  for (int r = 0; r < 4; ++r) {
    int oc = oc0 + wave * 16 + quad * 4 + r;
#pragma unroll
    for (int nt = 0; nt < 4; ++nt)
      xd[((size_t)(bimg * 256 + oc)) * 1024 + pos + nt * 16 + l16] = acc[nt][r];
  }
}

// ---------------- qkv projection: emits q/k hi-lo + v transposed hi-lo -----
template <int MODE>
__global__ __launch_bounds__(256) void k_qkv_mfma(
    const float* __restrict__ src, const float* __restrict__ cbias,
    const unsigned short* __restrict__ wh, const unsigned short* __restrict__ wl,
    const float* __restrict__ bq, const int* __restrict__ topk,
    unsigned short* __restrict__ qh, unsigned short* __restrict__ ql,
    unsigned short* __restrict__ kh, unsigned short* __restrict__ kl,
    unsigned short* __restrict__ vth, unsigned short* __restrict__ vtl) {
  __shared__ unsigned short Ah[64][72], Al[64][72];
  const int t = threadIdx.x;
  const int tok0 = blockIdx.x * 64;
  const int pair = blockIdx.y;
  const int b = pair >> 2, h = pair & 3;
  const int tokl = t & 63, dg = t >> 6;
  float fv[16];
  if (MODE == 0) {
    const float* base = src + ((size_t)(b * 256 + h * 64 + dg * 16)) * 1024 + tok0 + tokl;
    const float* cb = cbias + h * 64 + dg * 16;
#pragma unroll
    for (int j = 0; j < 16; ++j) fv[j] = base[(size_t)j * 1024] + cb[j];
  } else {
    int tok = tok0 + tokl;
    int pp = topk[pair * 256 + (tok >> 2)];
    int py = (tok >> 1) & 1, px = tok & 1;
    int ry = (pp >> 5) * 2 + py, rx = (pp & 31) * 2 + px;
    const float* base = src + ((size_t)(b * 256 + h * 64 + dg * 16)) * 4096 + ry * 64 + rx;
#pragma unroll
    for (int j = 0; j < 16; ++j) fv[j] = base[(size_t)j * 4096];
  }
  unsigned hp[8], lp[8];
#pragma unroll
  for (int j = 0; j < 8; ++j) cvt2(fv[2 * j], fv[2 * j + 1], hp[j], lp[j]);
  *(uint4*)&Ah[tokl][dg * 16] = make_uint4(hp[0], hp[1], hp[2], hp[3]);
  *(uint4*)&Ah[tokl][dg * 16 + 8] = make_uint4(hp[4], hp[5], hp[6], hp[7]);
  *(uint4*)&Al[tokl][dg * 16] = make_uint4(lp[0], lp[1], lp[2], lp[3]);
  *(uint4*)&Al[tokl][dg * 16 + 8] = make_uint4(lp[4], lp[5], lp[6], lp[7]);
  __syncthreads();
  const int wave = t >> 6, lane = t & 63, l16 = lane & 15, quad = lane >> 4;
  f32x4_t acc[4][3] = {};
#pragma unroll
  for (int ks = 0; ks < 2; ++ks) {
    int ko = ks * 32 + quad * 8;
    bf16x8_t bh0[3], bl0[3];
#pragma unroll
    for (int nt = 0; nt < 3; ++nt) {
      int col = wave * 48 + nt * 16 + l16;
      bh0[nt] = *(const bf16x8_t*)(wh + col * 64 + ko);
      bl0[nt] = *(const bf16x8_t*)(wl + col * 64 + ko);
    }
#pragma unroll
    for (int mt = 0; mt < 4; ++mt) {
      bf16x8_t ah = *(const bf16x8_t*)&Ah[mt * 16 + l16][ko];
      bf16x8_t al = *(const bf16x8_t*)&Al[mt * 16 + l16][ko];
#pragma unroll
      for (int nt = 0; nt < 3; ++nt) {
        acc[mt][nt] = MFMA16(ah, bh0[nt], acc[mt][nt]);
        acc[mt][nt] = MFMA16(ah, bl0[nt], acc[mt][nt]);
        acc[mt][nt] = MFMA16(al, bh0[nt], acc[mt][nt]);
      }
    }
  }
#pragma unroll
  for (int nt = 0; nt < 3; ++nt) {
    int col = wave * 48 + nt * 16 + l16;
    float bqv = bq[col];
    if (col < 64) bqv *= 0.125f;
#pragma unroll
    for (int mt = 0; mt < 4; ++mt) {
#pragma unroll
      for (int r = 0; r < 4; ++r) {
        int tok = tok0 + mt * 16 + quad * 4 + r;
        float val = acc[mt][nt][r] + bqv;
        unsigned short hh, ll;
        cvt1(val, hh, ll);
        if (col < 64) {
          size_t o = ((size_t)pair * 1024 + tok) * 64 + col;
          qh[o] = hh; ql[o] = ll;
        } else if (col < 128) {
          size_t o = ((size_t)pair * 1024 + tok) * 64 + (col - 64);
          kh[o] = hh; kl[o] = ll;
        } else {
          size_t o = ((size_t)pair * 64 + (col - 128)) * 1024 + tok;
          vth[o] = hh; vtl[o] = ll;
        }
      }
    }
  }
}

// ---------------- fused flash attention ------------------------------------
// Computes S^T = K·Q^T per tile (so P exits k-row-major -> b64 LDS writes),
// two passes: (1) online (m,l), (2) normalized P + colsum + PV accumulate.
// COARSE=1: out = padded CHW [b][c][34][34], plus colsum -> score atomics.
// COARSE=0: out = [pair][tok][d].
template <int COARSE>
__global__ __launch_bounds__(256) void k_attn(
    const unsigned short* __restrict__ qh, const unsigned short* __restrict__ ql,
    const unsigned short* __restrict__ kh, const unsigned short* __restrict__ kl,
    const unsigned short* __restrict__ vth, const unsigned short* __restrict__ vtl,
    float* __restrict__ score, float* __restrict__ out) {
  __shared__ __align__(16) unsigned short Qb[2][64][72];
  __shared__ __align__(16) unsigned short Kb[2][64][72];  // K tile, then V tile
  __shared__ __align__(16) unsigned short Pb[2][64][72];  // P tile; Tr at end
  __shared__ float mlW[4][2][64];
  __shared__ float mC[64], lC[64];
  __shared__ float colsum[1024];
  const int t = threadIdx.x;
  const int q0 = blockIdx.x * 64;
  const int pair = blockIdx.y;
  const int wave = t >> 6, lane = t & 63;
  const int l16 = lane & 15, quad = lane >> 4;
  const int wm = wave * 16;
  const int sr = t >> 3, skc = (t & 7) * 8;  // staging: row, k-offset

  // stage Q (rows q0..q0+63, d 0..63)
  const size_t qbase = ((size_t)pair * 1024 + q0) * 64;
#pragma unroll
  for (int i = 0; i < 2; ++i) {
    int r = sr + i * 32;
    *(bf16x8_t*)&Qb[0][r][skc] = *(const bf16x8_t*)(qh + qbase + (size_t)r * 64 + skc);
    *(bf16x8_t*)&Qb[1][r][skc] = *(const bf16x8_t*)(ql + qbase + (size_t)r * 64 + skc);
  }
  if (COARSE) {
#pragma unroll
    for (int i = 0; i < 4; ++i) colsum[t + i * 256] = 0.f;
  }

  const size_t kmbase = (size_t)pair * 1024 * 64;
  const size_t vbase = (size_t)pair * 64 * 1024;

  // ---- pass 1: online (m,l) per q-col ----
  float mrun[4] = {-1e30f, -1e30f, -1e30f, -1e30f};
  float lrun[4] = {0.f, 0.f, 0.f, 0.f};
  for (int kb = 0; kb < 1024; kb += 64) {
    __syncthreads();
#pragma unroll
    for (int i = 0; i < 2; ++i) {
      int r = sr + i * 32;
      *(bf16x8_t*)&Kb[0][r][skc] = *(const bf16x8_t*)(kh + kmbase + (size_t)(kb + r) * 64 + skc);
      *(bf16x8_t*)&Kb[1][r][skc] = *(const bf16x8_t*)(kl + kmbase + (size_t)(kb + r) * 64 + skc);
    }
    __syncthreads();
    f32x4_t acc[4] = {};
    mfma_chunk(Kb[0], Kb[1], Qb[0], Qb[1], acc, wm, lane);  // S^T tile
#pragma unroll
    for (int nt = 0; nt < 4; ++nt) {
      float m0 = fmaxf(fmaxf(acc[nt][0], acc[nt][1]), fmaxf(acc[nt][2], acc[nt][3]));
      m0 = fmaxf(m0, __shfl_xor(m0, 16));
      m0 = fmaxf(m0, __shfl_xor(m0, 32));
      float mn = fmaxf(mrun[nt], m0);
      float s0 = __expf(acc[nt][0] - mn) + __expf(acc[nt][1] - mn) +
                 __expf(acc[nt][2] - mn) + __expf(acc[nt][3] - mn);
      s0 += __shfl_xor(s0, 16);
      s0 += __shfl_xor(s0, 32);
      lrun[nt] = lrun[nt] * __expf(mrun[nt] - mn) + s0;
      mrun[nt] = mn;
    }
  }
  __syncthreads();
  if (quad == 0) {
#pragma unroll
    for (int nt = 0; nt < 4; ++nt) {
      mlW[wave][0][nt * 16 + l16] = mrun[nt];
      mlW[wave][1][nt * 16 + l16] = lrun[nt];
    }
  }
  __syncthreads();
  if (t < 64) {
    float m0 = mlW[0][0][t], m1 = mlW[1][0][t], m2 = mlW[2][0][t], m3 = mlW[3][0][t];
    float mm = fmaxf(fmaxf(m0, m1), fmaxf(m2, m3));
    float ll = mlW[0][1][t] * __expf(m0 - mm) + mlW[1][1][t] * __expf(m1 - mm) +
               mlW[2][1][t] * __expf(m2 - mm) + mlW[3][1][t] * __expf(m3 - mm);
    mC[t] = mm;
    lC[t] = 1.0f / ll;
  }
  __syncthreads();
  float mq[4], il[4];
#pragma unroll
  for (int nt = 0; nt < 4; ++nt) {
    mq[nt] = mC[nt * 16 + l16];
    il[nt] = lC[nt * 16 + l16];
  }

  // ---- pass 2: recompute S^T, normalized P, colsum, PV accumulate ----
  f32x4_t accO[4] = {};
  for (int kb = 0; kb < 1024; kb += 64) {
    __syncthreads();  // prev AV reads of Pb/Kb done
#pragma unroll
    for (int i = 0; i < 2; ++i) {
      int r = sr + i * 32;
      *(bf16x8_t*)&Kb[0][r][skc] = *(const bf16x8_t*)(kh + kmbase + (size_t)(kb + r) * 64 + skc);
      *(bf16x8_t*)&Kb[1][r][skc] = *(const bf16x8_t*)(kl + kmbase + (size_t)(kb + r) * 64 + skc);
    }
    __syncthreads();
    f32x4_t acc[4] = {};
    mfma_chunk(Kb[0], Kb[1], Qb[0], Qb[1], acc, wm, lane);
    float P[4][4];
#pragma unroll
    for (int nt = 0; nt < 4; ++nt)
#pragma unroll
      for (int r = 0; r < 4; ++r) P[nt][r] = __expf(acc[nt][r] - mq[nt]) * il[nt];
    if (COARSE) {
#pragma unroll
      for (int r = 0; r < 4; ++r) {
        float cs = P[0][r] + P[1][r] + P[2][r] + P[3][r];
        cs += __shfl_xor(cs, 1);
        cs += __shfl_xor(cs, 2);
        cs += __shfl_xor(cs, 4);
        cs += __shfl_xor(cs, 8);
        if (l16 == 0) colsum[kb + wm + quad * 4 + r] += cs;
      }
    }
    __syncthreads();  // QK reads of Kb done -> safe to restage V; prev Pb readers done
    // write P (A-layout: rows q, k contiguous) + stage V into Kb
#pragma unroll
    for (int nt = 0; nt < 4; ++nt) {
      unsigned h01, l01, h23, l23;
      cvt2(P[nt][0], P[nt][1], h01, l01);
      cvt2(P[nt][2], P[nt][3], h23, l23);
      *(uint2*)&Pb[0][nt * 16 + l16][wm + quad * 4] = make_uint2(h01, h23);
      *(uint2*)&Pb[1][nt * 16 + l16][wm + quad * 4] = make_uint2(l01, l23);
    }
#pragma unroll
    for (int i = 0; i < 2; ++i) {
      int r = sr + i * 32;
      *(bf16x8_t*)&Kb[0][r][skc] = *(const bf16x8_t*)(vth + vbase + (size_t)r * 1024 + kb + skc);
      *(bf16x8_t*)&Kb[1][r][skc] = *(const bf16x8_t*)(vtl + vbase + (size_t)r * 1024 + kb + skc);
    }
    __syncthreads();
    mfma_chunk(Pb[0], Pb[1], Kb[0], Kb[1], accO, wm, lane);  // O += P @ V
  }
  __syncthreads();

  if (COARSE) {
#pragma unroll
    for (int i = 0; i < 4; ++i)
      atomicAdd(&score[pair * 1024 + t + i * 256], colsum[t + i * 256]);
    // transpose O via LDS (alias Pb) then write padded CHW
    float (*Tr)[68] = reinterpret_cast<float(*)[68]>(&Pb[0][0][0]);
#pragma unroll
    for (int nt = 0; nt < 4; ++nt)
#pragma unroll
      for (int r = 0; r < 4; ++r)
        Tr[nt * 16 + l16][wm + quad * 4 + r] = accO[nt][r];
    __syncthreads();
    const int b = pair >> 2, h = pair & 3;
#pragma unroll
    for (int i = 0; i < 16; ++i) {
      int e = t + i * 256;
      int d = e >> 6, ql_ = e & 63;
      int pix = q0 + ql_;
      int iy = (pix >> 5) + 1, ix = (pix & 31) + 1;
      out[((size_t)(b * 256 + h * 64 + d)) * 1156 + iy * 34 + ix] = Tr[d][ql_];
    }
  } else {
#pragma unroll
    for (int nt = 0; nt < 4; ++nt)
#pragma unroll
      for (int r = 0; r < 4; ++r) {
        int qm = q0 + wm + quad * 4 + r;
        out[((size_t)pair * 1024 + qm) * 64 + nt * 16 + l16] = accO[nt][r];
      }
  }
}

// ---------------- per-pair top-256 via bitonic sort ------------------------
__global__ __launch_bounds__(256) void k_topk(
    const float* __restrict__ score, int* __restrict__ idx) {
  __shared__ unsigned long long key[1024];
  const int pair = blockIdx.x;
  const int t = threadIdx.x;
#pragma unroll
  for (int j = 0; j < 4; ++j) {
    int i = t + j * 256;
    unsigned u = __float_as_uint(score[pair * 1024 + i]);
    u = u ^ ((u & 0x80000000u) ? 0xFFFFFFFFu : 0x80000000u);
    u = ~u;
    key[i] = ((unsigned long long)u << 32) | (unsigned)i;
  }
  __syncthreads();
  for (int k = 2; k <= 1024; k <<= 1) {
    for (int j = k >> 1; j > 0; j >>= 1) {
      for (int w = 0; w < 4; ++w) {
        int i = t + w * 256;
        int l = i ^ j;
        if (l > i) {
          bool up = ((i & k) == 0);
          unsigned long long a = key[i], b = key[l];
          if ((a > b) == up) { key[i] = b; key[l] = a; }
        }
      }
      __syncthreads();
    }
  }
  idx[pair * 256 + t] = (int)(key[t] & 0xFFFFFFFFu);
}

// ---------------- convT as 4-class GEMM ------------------------------------
__global__ __launch_bounds__(256) void k_convT_mfma(
    const float* __restrict__ inp, const unsigned short* __restrict__ wth,
    const unsigned short* __restrict__ wtl, const float* __restrict__ bias,
    float* __restrict__ out) {
  __shared__ unsigned short Ah[64][72], Al[64][72], Bh[64][72], Bl[64][72];
  const int t = threadIdx.x;
  const int pix0 = blockIdx.x * 64;
  const int oc0 = blockIdx.y * 64;
  const int cls = blockIdx.z;
  const int ry = cls >> 1, rx = cls & 1;
  const int b = pix0 >> 10;
  const int wave = t >> 6, lane = t & 63;
  const int l16 = lane & 15, quad = lane >> 4;
  const int pixl = t & 63, icg = t >> 6;
  const int remg = (pix0 + pixl) & 1023;
  const int tyy = remg >> 5, txx = remg & 31;
  f32x4_t acc[4] = {};
  const size_t wbase = ((size_t)cls * 256 + oc0) * 1024;
  for (int kb = 0; kb < 1024; kb += 64) {
    const int tap = kb >> 8, ic0 = kb & 255;
    const int tk = tap >> 1, txi = tap & 1;
    const int iy = tyy + ry + 1 - tk, ix = txx + rx + 1 - txi;
    const float* p = inp + (size_t)(b * 256 + ic0 + icg * 16) * 1156 + iy * 34 + ix;
    float fv[16];
#pragma unroll
    for (int j = 0; j < 16; ++j) fv[j] = p[(size_t)j * 1156];
    unsigned hp[8], lpk[8];
#pragma unroll
    for (int j = 0; j < 8; ++j) cvt2(fv[2 * j], fv[2 * j + 1], hp[j], lpk[j]);
    bf16x8_t a0h, a0l, a1h, a1l;
    {
      int r = t >> 3, kc = (t & 7) * 8;
      a0h = *(const bf16x8_t*)(wth + wbase + (size_t)r * 1024 + kb + kc);
      a0l = *(const bf16x8_t*)(wtl + wbase + (size_t)r * 1024 + kb + kc);
      a1h = *(const bf16x8_t*)(wth + wbase + (size_t)(r + 32) * 1024 + kb + kc);
      a1l = *(const bf16x8_t*)(wtl + wbase + (size_t)(r + 32) * 1024 + kb + kc);
    }
    __syncthreads();
    {
      int r = t >> 3, kc = (t & 7) * 8;
      *(bf16x8_t*)&Ah[r][kc] = a0h;      *(bf16x8_t*)&Al[r][kc] = a0l;
      *(bf16x8_t*)&Ah[r + 32][kc] = a1h; *(bf16x8_t*)&Al[r + 32][kc] = a1l;
    }
    *(uint4*)&Bh[pixl][icg * 16] = make_uint4(hp[0], hp[1], hp[2], hp[3]);
    *(uint4*)&Bh[pixl][icg * 16 + 8] = make_uint4(hp[4], hp[5], hp[6], hp[7]);
    *(uint4*)&Bl[pixl][icg * 16] = make_uint4(lpk[0], lpk[1], lpk[2], lpk[3]);
    *(uint4*)&Bl[pixl][icg * 16 + 8] = make_uint4(lpk[4], lpk[5], lpk[6], lpk[7]);
    __syncthreads();
    mfma_chunk(Ah, Al, Bh, Bl, acc, wave * 16, lane);
  }
  __syncthreads();
#pragma unroll
  for (int r = 0; r < 4; ++r) {
    int oc = oc0 + wave * 16 + quad * 4 + r;
    float bvs = bias[oc];
#pragma unroll
    for (int nt = 0; nt < 4; ++nt) {
      int pix = pix0 + nt * 16 + l16;
      int rem2 = pix & 1023;
      int y = (rem2 >> 5) * 2 + ry, xx = (rem2 & 31) * 2 + rx;
      out[((size_t)(b * 256 + oc) * 64 + y) * 64 + xx] = acc[nt][r] + bvs;
    }
  }
}

// ---------------- scatter fine outputs into y ------------------------------
__global__ __launch_bounds__(256) void k_scatter(
    const float* __restrict__ outf, const int* __restrict__ idx,
    float* __restrict__ y) {
  int g = blockIdx.x * 256 + threadIdx.x;
  int pair = g >> 16;
  int rem = g & 65535;
  int tok = rem >> 6, d = rem & 63;
  int b = pair >> 2, h = pair & 3;
  int pp = idx[pair * 256 + (tok >> 2)];
  int py = (tok >> 1) & 1, px = tok & 1;
  int ry = (pp >> 5) * 2 + py, rx = (pp & 31) * 2 + px;
  y[((size_t)(b * 256 + h * 64 + d) * 64 + ry) * 64 + rx] += outf[g];
}

// ---------------- depthwise 3x3 + BN + relu6 (fp32) ------------------------
__global__ __launch_bounds__(256) void k_dwconv(
    const float* __restrict__ y, const float* __restrict__ wdw,
    const float* __restrict__ g, const float* __restrict__ bb,
    const float* __restrict__ m, const float* __restrict__ vv,
    float* __restrict__ yd) {
  int gi = blockIdx.x * 256 + threadIdx.x;
  int x = gi & 63, yy = (gi >> 6) & 63, ch = (gi >> 12) & 255, b = gi >> 20;
  const float* plane = y + (size_t)(b * 256 + ch) * 4096;
  const float* wc = wdw + ch * 9;
  float s = 0.f;
#pragma unroll
  for (int ky = 0; ky < 3; ++ky) {
    int iy = yy + ky - 1;
    if (iy < 0 || iy >= 64) continue;
#pragma unroll
    for (int kx = 0; kx < 3; ++kx) {
      int ix = x + kx - 1;
      if (ix < 0 || ix >= 64) continue;
      s = fmaf(plane[iy * 64 + ix], wc[ky * 3 + kx], s);
    }
  }
  float sc = g[ch] * rsqrtf(vv[ch] + EPS_);
  float val = s * sc + (bb[ch] - m[ch] * sc);
  yd[gi] = fminf(fmaxf(val, 0.f), 6.f);
}

// ---------------- pointwise 1x1 + BN + relu6 -------------------------------
__global__ __launch_bounds__(256) void k_pw_mfma(
    const float* __restrict__ yd, const unsigned short* __restrict__ wh,
    const unsigned short* __restrict__ wl, const float* __restrict__ g,
    const float* __restrict__ bb, const float* __restrict__ m,
    const float* __restrict__ vv, float* __restrict__ out) {
  __shared__ unsigned short Ah[64][72], Al[64][72], Bh[64][72], Bl[64][72];
  const int t = threadIdx.x;
  const int pix0 = blockIdx.x * 64;
  const int oc0 = blockIdx.y * 64;
  const int b = pix0 >> 12, pos0 = pix0 & 4095;
  const int wave = t >> 6, lane = t & 63;
  const int l16 = lane & 15, quad = lane >> 4;
  const int pixl = t & 63, icg = t >> 6;
  f32x4_t acc[4] = {};
  for (int kb = 0; kb < 256; kb += 64) {
    float fv[16];
#pragma unroll
    for (int j = 0; j < 16; ++j)
      fv[j] = yd[(size_t)(b * 256 + kb + icg * 16 + j) * 4096 + pos0 + pixl];
    unsigned hp[8], lpk[8];
#pragma unroll
    for (int j = 0; j < 8; ++j) cvt2(fv[2 * j], fv[2 * j + 1], hp[j], lpk[j]);
    bf16x8_t a0h, a0l, a1h, a1l;
    {
      int r = t >> 3, kc = (t & 7) * 8;
      a0h = *(const bf16x8_t*)(wh + (size_t)(oc0 + r) * 256 + kb + kc);
      a0l = *(const bf16x8_t*)(wl + (size_t)(oc0 + r) * 256 + kb + kc);
      a1h = *(const bf16x8_t*)(wh + (size_t)(oc0 + r + 32) * 256 + kb + kc);
      a1l = *(const bf16x8_t*)(wl + (size_t)(oc0 + r + 32) * 256 + kb + kc);
    }
    __syncthreads();
    {
      int r = t >> 3, kc = (t & 7) * 8;
      *(bf16x8_t*)&Ah[r][kc] = a0h;      *(bf16x8_t*)&Al[r][kc] = a0l;
      *(bf16x8_t*)&Ah[r + 32][kc] = a1h; *(bf16x8_t*)&Al[r + 32][kc] = a1l;
    }
    *(uint4*)&Bh[pixl][icg * 16] = make_uint4(hp[0], hp[1], hp[2], hp[3]);
    *(uint4*)&Bh[pixl][icg * 16 + 8] = make_uint4(hp[4], hp[5], hp[6], hp[7]);
    *(uint4*)&Bl[pixl][icg * 16] = make_uint4(lpk[0], lpk[1], lpk[2], lpk[3]);
    *(uint4*)&Bl[pixl][icg * 16 + 8] = make_uint4(lpk[4], lpk[5], lpk[6], lpk[7]);
    __syncthreads();
    mfma_chunk(Ah, Al, Bh, Bl, acc, wave * 16, lane);
    __syncthreads();
  }
#pragma unroll
  for (int r = 0; r < 4; ++r) {
    int oc = oc0 + wave * 16 + quad * 4 + r;
    float sc = g[oc] * rsqrtf(vv[oc] + EPS_);
    float off = bb[oc] - m[oc] * sc;
#pragma unroll
    for (int nt = 0; nt < 4; ++nt) {
      int pix = pos0 + nt * 16 + l16;
      float val = fminf(fmaxf(acc[nt][r] * sc + off, 0.f), 6.f);
      out[(size_t)(b * 256 + oc) * 4096 + pix] = val;
    }
  }
}

// ---------------------------------------------------------------------------
extern "C" void kernel_launch(void* const* d_in, const int* in_sizes, int n_in,
                              void* d_out, int out_size, void* d_ws, size_t ws_size,
                              hipStream_t stream) {
  (void)in_sizes; (void)n_in; (void)out_size; (void)ws_size;
  const float* x       = (const float*)d_in[0];
  const float* w_down  = (const float*)d_in[1];
  const float* b_down  = (const float*)d_in[2];
  const float* w_qkv_c = (const float*)d_in[3];
  const float* b_qkv_c = (const float*)d_in[4];
  const float* w_up    = (const float*)d_in[5];
  const float* b_up    = (const float*)d_in[6];
  const float* w_qkv_f = (const float*)d_in[7];
  const float* b_qkv_f = (const float*)d_in[8];
  const float* w_dw    = (const float*)d_in[9];
  const float* bn_dw_g = (const float*)d_in[10];
  const float* bn_dw_b = (const float*)d_in[11];
  const float* bn_dw_m = (const float*)d_in[12];
  const float* bn_dw_v = (const float*)d_in[13];
  const float* w_pw    = (const float*)d_in[14];
  const float* bn_pw_g = (const float*)d_in[15];
  const float* bn_pw_b = (const float*)d_in[16];
  const float* bn_pw_m = (const float*)d_in[17];
  const float* bn_pw_v = (const float*)d_in[18];

  float* ws = (float*)d_ws;  // offsets in float units
  float*          scratch= ws;                              // 16,777,216 f (xp / yd alias)
  unsigned short* qh     = (unsigned short*)(ws + 33554432);
  unsigned short* ql     = (unsigned short*)(ws + 34603008);
  unsigned short* kh     = (unsigned short*)(ws + 35651584);
  unsigned short* kl     = (unsigned short*)(ws + 36700160);
  unsigned short* vth    = (unsigned short*)(ws + 37748736);
  unsigned short* vtl    = (unsigned short*)(ws + 38797312);
  float*          xd     = ws + 39845888;                   // 2,097,152 f
  float*          outcp  = ws + 41943040;                   // 2,367,488 f
  float*          coarse = ws + 44310528;                   // 8,388,608 f
  float*          outf   = ws + 52699136;                   // 2,097,152 f
  float*          score  = ws + 54796288;                   // 32,768 f
  unsigned short* wdh    = (unsigned short*)(ws + 54829056);
  unsigned short* wdl    = (unsigned short*)(ws + 55353344);
  unsigned short* wt_hi  = (unsigned short*)(ws + 55877632);
  unsigned short* wt_lo  = (unsigned short*)(ws + 56401920);
  unsigned short* wpw_hi = (unsigned short*)(ws + 56926208);
  unsigned short* wpw_lo = (unsigned short*)(ws + 56958976);
  unsigned short* wqh_c  = (unsigned short*)(ws + 56991744);
  unsigned short* wql_c  = (unsigned short*)(ws + 56997888);
  unsigned short* wqh_f  = (unsigned short*)(ws + 57004032);
  unsigned short* wql_f  = (unsigned short*)(ws + 57010176);
  int*            idx    = (int*)(ws + 57016320);           // 8,192 int
  float*          xp     = scratch;                         // 8,921,088 f
  float*          yd     = scratch;

  hipMemsetAsync(score, 0, 32768 * sizeof(float), stream);
  hipMemsetAsync(outcp, 0, (size_t)2367488 * sizeof(float), stream);
  k_pad_x<<<2048, 256, 0, stream>>>(x, xp);
  k_cvt_wdown<<<4096, 256, 0, stream>>>(w_down, wdh, wdl);
  k_cvt_wqkv<<<48, 256, 0, stream>>>(w_qkv_c, wqh_c, wql_c);
  k_cvt_wqkv<<<48, 256, 0, stream>>>(w_qkv_f, wqh_f, wql_f);
  k_cvt_wup<<<4096, 256, 0, stream>>>(w_up, wt_hi, wt_lo);
  k_cvt_wpw<<<256, 256, 0, stream>>>(w_pw, wpw_hi, wpw_lo);

  k_conv_down_mfma<<<dim3(128, 4), 256, 0, stream>>>(xp, wdh, wdl, xd);
  k_qkv_mfma<0><<<dim3(16, 32), 256, 0, stream>>>(xd, b_down, wqh_c, wql_c, b_qkv_c,
                                                  nullptr, qh, ql, kh, kl, vth, vtl);
  k_attn<1><<<dim3(16, 32), 256, 0, stream>>>(qh, ql, kh, kl, vth, vtl, score, outcp);
  k_topk<<<32, 256, 0, stream>>>(score, idx);
  k_convT_mfma<<<dim3(128, 4, 4), 256, 0, stream>>>(outcp, wt_hi, wt_lo, b_up, coarse);

  k_qkv_mfma<1><<<dim3(16, 32), 256, 0, stream>>>(coarse, nullptr, wqh_f, wql_f, b_qkv_f,
                                                  idx, qh, ql, kh, kl, vth, vtl);
  k_attn<0><<<dim3(16, 32), 256, 0, stream>>>(qh, ql, kh, kl, vth, vtl, nullptr, outf);
  k_scatter<<<8192, 256, 0, stream>>>(outf, idx, coarse);
  k_dwconv<<<32768, 256, 0, stream>>>(coarse, w_dw, bn_dw_g, bn_dw_b, bn_dw_m, bn_dw_v, yd);
  k_pw_mfma<<<dim3(512, 4), 256, 0, stream>>>(yd, wpw_hi, wpw_lo, bn_pw_g, bn_pw_b,
                                              bn_pw_m, bn_pw_v, (float*)d_out);
}

// Round 6
// 627.368 us; speedup vs baseline: 2.6037x; 1.0176x over previous
//
#include <hip/hip_runtime.h>
#include <cstdint>
#include <cstddef>

// ---------------------------------------------------------------------------
// RegionSelectionAttention. Round 6: producer-side hi/lo packing. All
// activations consumed by MFMA GEMMs are stored packed (h | l<<16) so the
// staging loops do loads + v_perm packing only — no repeated float->bf16x2
// conversion. Values bit-identical to round 5.
// ---------------------------------------------------------------------------

#define EPS_ 1e-5f

typedef short bf16x8_t __attribute__((ext_vector_type(8)));
typedef float f32x4_t __attribute__((ext_vector_type(4)));
#define MFMA16(a, b, c) __builtin_amdgcn_mfma_f32_16x16x32_bf16(a, b, c, 0, 0, 0)

__device__ __forceinline__ void cvt1(float f, unsigned short& h, unsigned short& l) {
  unsigned u = __float_as_uint(f);
  unsigned r = u + 0x7FFFu + ((u >> 16) & 1u);
  h = (unsigned short)(r >> 16);
  float lo = f - __uint_as_float(r & 0xFFFF0000u);
  l = (unsigned short)(__float_as_uint(lo) >> 16);
}
__device__ __forceinline__ unsigned cvtpack(float f) {
  unsigned short h, l;
  cvt1(f, h, l);
  return (unsigned)h | ((unsigned)l << 16);
}
__device__ __forceinline__ void cvt2(float f0, float f1, unsigned& hpack, unsigned& lpack) {
  unsigned u0 = __float_as_uint(f0), u1 = __float_as_uint(f1);
  unsigned r0 = u0 + 0x7FFFu + ((u0 >> 16) & 1u);
  unsigned r1 = u1 + 0x7FFFu + ((u1 >> 16) & 1u);
  hpack = (r0 >> 16) | (r1 & 0xFFFF0000u);
  float l0 = f0 - __uint_as_float(r0 & 0xFFFF0000u);
  float l1 = f1 - __uint_as_float(r1 & 0xFFFF0000u);
  lpack = (__float_as_uint(l0) >> 16) | (__float_as_uint(l1) & 0xFFFF0000u);
}
// from two packed (h|l<<16) words -> h-pair and l-pair words
__device__ __forceinline__ unsigned pk_h(unsigned a, unsigned b) {
  return (a & 0xFFFFu) | (b << 16);
}
__device__ __forceinline__ unsigned pk_l(unsigned a, unsigned b) {
  return (a >> 16) | (b & 0xFFFF0000u);
}

// ---------------- pad x -> packed xphl[plane][66 rows x stride 68] ---------
__global__ __launch_bounds__(256) void k_pad_x(
    const float* __restrict__ x, unsigned* __restrict__ xphl) {
  const int plane = blockIdx.x;  // 2048
  const float* src = x + (size_t)plane * 4096;
  unsigned* dst = xphl + (size_t)plane * 4488;
  for (int e = threadIdx.x; e < 4356; e += 256) {
    int r = e / 66, cc = e - r * 66;
    float v = 0.f;
    if (r >= 1 && r <= 64 && cc >= 1 && cc <= 64) v = src[(r - 1) * 64 + (cc - 1)];
    dst[r * 68 + cc] = cvtpack(v);
  }
}

// ---------------- weight conversions ---------------------------------------
__global__ __launch_bounds__(256) void k_cvt_wdown(
    const float* __restrict__ w, unsigned short* __restrict__ wh,
    unsigned short* __restrict__ wl) {
  int e = blockIdx.x * 256 + threadIdx.x;  // 1,048,576: [oc][4096]
  cvt1(w[e], wh[e], wl[e]);
}

__global__ __launch_bounds__(256) void k_cvt_wqkv(
    const float* __restrict__ wq, unsigned short* __restrict__ wh,
    unsigned short* __restrict__ wl) {
  int e = blockIdx.x * 256 + threadIdx.x;  // 12288: [col][d]
  int col = e >> 6, d = e & 63;
  float f = wq[d * 192 + col];
  if (col < 64) f *= 0.125f;  // fold attn scale into q (pow2: exact)
  cvt1(f, wh[e], wl[e]);
}

__global__ __launch_bounds__(256) void k_cvt_wup(
    const float* __restrict__ w_up, unsigned short* __restrict__ wth,
    unsigned short* __restrict__ wtl) {
  int e = blockIdx.x * 256 + threadIdx.x;  // 2^20: [class][oc][kp=tap*256+ic]
  int kp = e & 1023, oc = (e >> 10) & 255, c = e >> 18;
  int tap = kp >> 8, ic = kp & 255;
  int tk = tap >> 1, txi = tap & 1;
  int ry = c >> 1, rx = c & 1;
  int ky = (1 - ry) + 2 * tk, kx = (1 - rx) + 2 * txi;
  cvt1(w_up[((size_t)(ic * 256 + oc) * 4 + ky) * 4 + kx], wth[e], wtl[e]);
}

__global__ __launch_bounds__(256) void k_cvt_wpw(
    const float* __restrict__ w, unsigned short* __restrict__ wh,
    unsigned short* __restrict__ wl) {
  int e = blockIdx.x * 256 + threadIdx.x;  // 65536 [oc][ic]
  cvt1(w[e], wh[e], wl[e]);
}

// ====================== bf16x3 MFMA core ===================================
__device__ __forceinline__ void mfma_chunk(
    const unsigned short (*Ah)[72], const unsigned short (*Al)[72],
    const unsigned short (*Bh)[72], const unsigned short (*Bl)[72],
    f32x4_t (&acc)[4], int wm, int lane) {
  const int l16 = lane & 15, quad = lane >> 4;
#pragma unroll
  for (int ks = 0; ks < 2; ++ks) {
    int ko = ks * 32 + quad * 8;
    bf16x8_t ah = *(const bf16x8_t*)&Ah[wm + l16][ko];
    bf16x8_t al = *(const bf16x8_t*)&Al[wm + l16][ko];
#pragma unroll
    for (int nt = 0; nt < 4; ++nt) {
      bf16x8_t bh = *(const bf16x8_t*)&Bh[nt * 16 + l16][ko];
      bf16x8_t bl = *(const bf16x8_t*)&Bl[nt * 16 + l16][ko];
      acc[nt] = MFMA16(ah, bh, acc[nt]);
      acc[nt] = MFMA16(ah, bl, acc[nt]);
      acc[nt] = MFMA16(al, bh, acc[nt]);
    }
  }
}

// ---------------- conv down k4 s2 p1 as implicit GEMM, K=4096 --------------
// B from packed xphl; epilogue adds bias and emits packed xdhl.
__global__ __launch_bounds__(256) void k_conv_down_mfma(
    const unsigned* __restrict__ xphl, const unsigned short* __restrict__ wdh,
    const unsigned short* __restrict__ wdl, const float* __restrict__ bias,
    unsigned* __restrict__ xdhl) {
  __shared__ unsigned short Ah[64][72], Al[64][72], Bh[64][72], Bl[64][72];
  const int t = threadIdx.x;
  const int pix0 = blockIdx.x * 64, oc0 = blockIdx.y * 64;
  const int bimg = pix0 >> 10, pos = pix0 & 1023;
  const int pl = t & 63, icg = t >> 6;
  const int rem = (pix0 + pl) & 1023;
  const int oy = rem >> 5, ox = rem & 31;
  const unsigned* xb = xphl + ((size_t)bimg * 256 + icg) * 4488 + (oy * 2) * 68 + ox * 2;
  const int wave = t >> 6, lane = t & 63, l16 = lane & 15, quad = lane >> 4;
  const int ar = t >> 3, akc = (t & 7) * 8;
  f32x4_t acc[4] = {};
  for (int kb = 0; kb < 4096; kb += 64) {
    bf16x8_t a0h = *(const bf16x8_t*)(wdh + (size_t)(oc0 + ar) * 4096 + kb + akc);
    bf16x8_t a0l = *(const bf16x8_t*)(wdl + (size_t)(oc0 + ar) * 4096 + kb + akc);
    bf16x8_t a1h = *(const bf16x8_t*)(wdh + (size_t)(oc0 + 32 + ar) * 4096 + kb + akc);
    bf16x8_t a1l = *(const bf16x8_t*)(wdl + (size_t)(oc0 + 32 + ar) * 4096 + kb + akc);
    unsigned hA[8], lA[8];
#pragma unroll
    for (int r = 0; r < 4; ++r) {
      uint2 u01 = *(const uint2*)(xb + r * 68);
      uint2 u23 = *(const uint2*)(xb + r * 68 + 2);
      hA[2 * r] = pk_h(u01.x, u01.y); hA[2 * r + 1] = pk_h(u23.x, u23.y);
      lA[2 * r] = pk_l(u01.x, u01.y); lA[2 * r + 1] = pk_l(u23.x, u23.y);
    }
    __syncthreads();
    *(bf16x8_t*)&Ah[ar][akc] = a0h;      *(bf16x8_t*)&Al[ar][akc] = a0l;
    *(bf16x8_t*)&Ah[ar + 32][akc] = a1h; *(bf16x8_t*)&Al[ar + 32][akc] = a1l;
    *(uint4*)&Bh[pl][icg * 16] = make_uint4(hA[0], hA[1], hA[2], hA[3]);
    *(uint4*)&Bh[pl][icg * 16 + 8] = make_uint4(hA[4], hA[5], hA[6], hA[7]);
    *(uint4*)&Bl[pl][icg * 16] = make_uint4(lA[0], lA[1], lA[2], lA[3]);
    *(uint4*)&Bl[pl][icg * 16 + 8] = make_uint4(lA[4], lA[5], lA[6], lA[7]);
    __syncthreads();
    mfma_chunk(Ah, Al, Bh, Bl, acc, wave * 16, lane);
    xb += 4 * 4488;
  }
#pragma unroll
  for (int r = 0; r < 4; ++r) {
    int oc = oc0 + wave * 16 + quad * 4 + r;
    float bv = bias[oc];
#pragma unroll
    for (int nt = 0; nt < 4; ++nt)
      xdhl[((size_t)(bimg * 256 + oc)) * 1024 + pos + nt * 16 + l16] =
          cvtpack(acc[nt][r] + bv);
  }
}

// ---------------- qkv projection: emits q/k hi-lo + v transposed hi-lo -----
// MODE0: coarse, reads packed xdhl (bias already applied by conv_down).
// MODE1: fine gather from fp32 coarse via topk.
template <int MODE>
__global__ __launch_bounds__(256) void k_qkv_mfma(
    const unsigned* __restrict__ srcp, const float* __restrict__ srcf,
    const unsigned short* __restrict__ wh, const unsigned short* __restrict__ wl,
    const float* __restrict__ bq, const int* __restrict__ topk,
    unsigned short* __restrict__ qh, unsigned short* __restrict__ ql,
    unsigned short* __restrict__ kh, unsigned short* __restrict__ kl,
    unsigned short* __restrict__ vth, unsigned short* __restrict__ vtl) {
  __shared__ unsigned short Ah[64][72], Al[64][72];
  const int t = threadIdx.x;
  const int tok0 = blockIdx.x * 64;
  const int pair = blockIdx.y;
  const int b = pair >> 2, h = pair & 3;
  const int tokl = t & 63, dg = t >> 6;
  unsigned hp[8], lp[8];
  if (MODE == 0) {
    const unsigned* base = srcp + ((size_t)(b * 256 + h * 64 + dg * 16)) * 1024 + tok0 + tokl;
    unsigned u[16];
#pragma unroll
    for (int j = 0; j < 16; ++j) u[j] = base[(size_t)j * 1024];
#pragma unroll
    for (int j = 0; j < 8; ++j) {
      hp[j] = pk_h(u[2 * j], u[2 * j + 1]);
      lp[j] = pk_l(u[2 * j], u[2 * j + 1]);
    }
  } else {
    int tok = tok0 + tokl;
    int pp = topk[pair * 256 + (tok >> 2)];
    int py = (tok >> 1) & 1, px = tok & 1;
    int ry = (pp >> 5) * 2 + py, rx = (pp & 31) * 2 + px;
    const float* base = srcf + ((size_t)(b * 256 + h * 64 + dg * 16)) * 4096 + ry * 64 + rx;
    float fv[16];
#pragma unroll
    for (int j = 0; j < 16; ++j) fv[j] = base[(size_t)j * 4096];
#pragma unroll
    for (int j = 0; j < 8; ++j) cvt2(fv[2 * j], fv[2 * j + 1], hp[j], lp[j]);
  }
  *(uint4*)&Ah[tokl][dg * 16] = make_uint4(hp[0], hp[1], hp[2], hp[3]);
  *(uint4*)&Ah[tokl][dg * 16 + 8] = make_uint4(hp[4], hp[5], hp[6], hp[7]);
  *(uint4*)&Al[tokl][dg * 16] = make_uint4(lp[0], lp[1], lp[2], lp[3]);
  *(uint4*)&Al[tokl][dg * 16 + 8] = make_uint4(lp[4], lp[5], lp[6], lp[7]);
  __syncthreads();
  const int wave = t >> 6, lane = t & 63, l16 = lane & 15, quad = lane >> 4;
  f32x4_t acc[4][3] = {};
#pragma unroll
  for (int ks = 0; ks < 2; ++ks) {
    int ko = ks * 32 + quad * 8;
    bf16x8_t bh0[3], bl0[3];
#pragma unroll
    for (int nt = 0; nt < 3; ++nt) {
      int col = wave * 48 + nt * 16 + l16;
      bh0[nt] = *(const bf16x8_t*)(wh + col * 64 + ko);
      bl0[nt] = *(const bf16x8_t*)(wl + col * 64 + ko);
    }
#pragma unroll
    for (int mt = 0; mt < 4; ++mt) {
      bf16x8_t ah = *(const bf16x8_t*)&Ah[mt * 16 + l16][ko];
      bf16x8_t al = *(const bf16x8_t*)&Al[mt * 16 + l16][ko];
#pragma unroll
      for (int nt = 0; nt < 3; ++nt) {
        acc[mt][nt] = MFMA16(ah, bh0[nt], acc[mt][nt]);
        acc[mt][nt] = MFMA16(ah, bl0[nt], acc[mt][nt]);
        acc[mt][nt] = MFMA16(al, bh0[nt], acc[mt][nt]);
      }
    }
  }
#pragma unroll
  for (int nt = 0; nt < 3; ++nt) {
    int col = wave * 48 + nt * 16 + l16;
    float bqv = bq[col];
    if (col < 64) bqv *= 0.125f;
#pragma unroll
    for (int mt = 0; mt < 4; ++mt) {
#pragma unroll
      for (int r = 0; r < 4; ++r) {
        int tok = tok0 + mt * 16 + quad * 4 + r;
        float val = acc[mt][nt][r] + bqv;
        unsigned short hh, ll;
        cvt1(val, hh, ll);
        if (col < 64) {
          size_t o = ((size_t)pair * 1024 + tok) * 64 + col;
          qh[o] = hh; ql[o] = ll;
        } else if (col < 128) {
          size_t o = ((size_t)pair * 1024 + tok) * 64 + (col - 64);
          kh[o] = hh; kl[o] = ll;
        } else {
          size_t o = ((size_t)pair * 64 + (col - 128)) * 1024 + tok;
          vth[o] = hh; vtl[o] = ll;
        }
      }
    }
  }
}

// ---------------- fused flash attention ------------------------------------
// COARSE=1: packed hi/lo CHW out (outc) + colsum -> score. COARSE=0: fp32 outf.
template <int COARSE>
__global__ __launch_bounds__(256) void k_attn(
    const unsigned short* __restrict__ qh, const unsigned short* __restrict__ ql,
    const unsigned short* __restrict__ kh, const unsigned short* __restrict__ kl,
    const unsigned short* __restrict__ vth, const unsigned short* __restrict__ vtl,
    float* __restrict__ score, unsigned* __restrict__ outc,
    float* __restrict__ outf) {
  __shared__ __align__(16) unsigned short Qb[2][64][72];
  __shared__ __align__(16) unsigned short Kb[2][64][72];
  __shared__ __align__(16) unsigned short Pb[2][64][72];
  __shared__ float mlW[4][2][64];
  __shared__ float mC[64], lC[64];
  __shared__ float colsum[1024];
  const int t = threadIdx.x;
  const int q0 = blockIdx.x * 64;
  const int pair = blockIdx.y;
  const int wave = t >> 6, lane = t & 63;
  const int l16 = lane & 15, quad = lane >> 4;
  const int wm = wave * 16;
  const int sr = t >> 3, skc = (t & 7) * 8;

  const size_t qbase = ((size_t)pair * 1024 + q0) * 64;
#pragma unroll
  for (int i = 0; i < 2; ++i) {
    int r = sr + i * 32;
    *(bf16x8_t*)&Qb[0][r][skc] = *(const bf16x8_t*)(qh + qbase + (size_t)r * 64 + skc);
    *(bf16x8_t*)&Qb[1][r][skc] = *(const bf16x8_t*)(ql + qbase + (size_t)r * 64 + skc);
  }
  if (COARSE) {
#pragma unroll
    for (int i = 0; i < 4; ++i) colsum[t + i * 256] = 0.f;
  }

  const size_t kmbase = (size_t)pair * 1024 * 64;
  const size_t vbase = (size_t)pair * 64 * 1024;

  // ---- pass 1: online (m,l) ----
  float mrun[4] = {-1e30f, -1e30f, -1e30f, -1e30f};
  float lrun[4] = {0.f, 0.f, 0.f, 0.f};
  for (int kb = 0; kb < 1024; kb += 64) {
    __syncthreads();
#pragma unroll
    for (int i = 0; i < 2; ++i) {
      int r = sr + i * 32;
      *(bf16x8_t*)&Kb[0][r][skc] = *(const bf16x8_t*)(kh + kmbase + (size_t)(kb + r) * 64 + skc);
      *(bf16x8_t*)&Kb[1][r][skc] = *(const bf16x8_t*)(kl + kmbase + (size_t)(kb + r) * 64 + skc);
    }
    __syncthreads();
    f32x4_t acc[4] = {};
    mfma_chunk(Kb[0], Kb[1], Qb[0], Qb[1], acc, wm, lane);
#pragma unroll
    for (int nt = 0; nt < 4; ++nt) {
      float m0 = fmaxf(fmaxf(acc[nt][0], acc[nt][1]), fmaxf(acc[nt][2], acc[nt][3]));
      m0 = fmaxf(m0, __shfl_xor(m0, 16));
      m0 = fmaxf(m0, __shfl_xor(m0, 32));
      float mn = fmaxf(mrun[nt], m0);
      float s0 = __expf(acc[nt][0] - mn) + __expf(acc[nt][1] - mn) +
                 __expf(acc[nt][2] - mn) + __expf(acc[nt][3] - mn);
      s0 += __shfl_xor(s0, 16);
      s0 += __shfl_xor(s0, 32);
      lrun[nt] = lrun[nt] * __expf(mrun[nt] - mn) + s0;
      mrun[nt] = mn;
    }
  }
  __syncthreads();
  if (quad == 0) {
#pragma unroll
    for (int nt = 0; nt < 4; ++nt) {
      mlW[wave][0][nt * 16 + l16] = mrun[nt];
      mlW[wave][1][nt * 16 + l16] = lrun[nt];
    }
  }
  __syncthreads();
  if (t < 64) {
    float m0 = mlW[0][0][t], m1 = mlW[1][0][t], m2 = mlW[2][0][t], m3 = mlW[3][0][t];
    float mm = fmaxf(fmaxf(m0, m1), fmaxf(m2, m3));
    float ll = mlW[0][1][t] * __expf(m0 - mm) + mlW[1][1][t] * __expf(m1 - mm) +
               mlW[2][1][t] * __expf(m2 - mm) + mlW[3][1][t] * __expf(m3 - mm);
    mC[t] = mm;
    lC[t] = 1.0f / ll;
  }
  __syncthreads();
  float mq[4], il[4];
#pragma unroll
  for (int nt = 0; nt < 4; ++nt) {
    mq[nt] = mC[nt * 16 + l16];
    il[nt] = lC[nt * 16 + l16];
  }

  // ---- pass 2 ----
  f32x4_t accO[4] = {};
  for (int kb = 0; kb < 1024; kb += 64) {
    __syncthreads();
#pragma unroll
    for (int i = 0; i < 2; ++i) {
      int r = sr + i * 32;
      *(bf16x8_t*)&Kb[0][r][skc] = *(const bf16x8_t*)(kh + kmbase + (size_t)(kb + r) * 64 + skc);
      *(bf16x8_t*)&Kb[1][r][skc] = *(const bf16x8_t*)(kl + kmbase + (size_t)(kb + r) * 64 + skc);
    }
    __syncthreads();
    f32x4_t acc[4] = {};
    mfma_chunk(Kb[0], Kb[1], Qb[0], Qb[1], acc, wm, lane);
    float P[4][4];
#pragma unroll
    for (int nt = 0; nt < 4; ++nt)
#pragma unroll
      for (int r = 0; r < 4; ++r) P[nt][r] = __expf(acc[nt][r] - mq[nt]) * il[nt];
    if (COARSE) {
#pragma unroll
      for (int r = 0; r < 4; ++r) {
        float cs = P[0][r] + P[1][r] + P[2][r] + P[3][r];
        cs += __shfl_xor(cs, 1);
        cs += __shfl_xor(cs, 2);
        cs += __shfl_xor(cs, 4);
        cs += __shfl_xor(cs, 8);
        if (l16 == 0) colsum[kb + wm + quad * 4 + r] += cs;
      }
    }
    __syncthreads();
#pragma unroll
    for (int nt = 0; nt < 4; ++nt) {
      unsigned h01, l01, h23, l23;
      cvt2(P[nt][0], P[nt][1], h01, l01);
      cvt2(P[nt][2], P[nt][3], h23, l23);
      *(uint2*)&Pb[0][nt * 16 + l16][wm + quad * 4] = make_uint2(h01, h23);
      *(uint2*)&Pb[1][nt * 16 + l16][wm + quad * 4] = make_uint2(l01, l23);
    }
#pragma unroll
    for (int i = 0; i < 2; ++i) {
      int r = sr + i * 32;
      *(bf16x8_t*)&Kb[0][r][skc] = *(const bf16x8_t*)(vth + vbase + (size_t)r * 1024 + kb + skc);
      *(bf16x8_t*)&Kb[1][r][skc] = *(const bf16x8_t*)(vtl + vbase + (size_t)r * 1024 + kb + skc);
    }
    __syncthreads();
    mfma_chunk(Pb[0], Pb[1], Kb[0], Kb[1], accO, wm, lane);
  }
  __syncthreads();

  if (COARSE) {
#pragma unroll
    for (int i = 0; i < 4; ++i)
      atomicAdd(&score[pair * 1024 + t + i * 256], colsum[t + i * 256]);
    float (*Tr)[68] = reinterpret_cast<float(*)[68]>(&Pb[0][0][0]);
#pragma unroll
    for (int nt = 0; nt < 4; ++nt)
#pragma unroll
      for (int r = 0; r < 4; ++r)
        Tr[nt * 16 + l16][wm + quad * 4 + r] = accO[nt][r];
    __syncthreads();
    const int b = pair >> 2, h = pair & 3;
#pragma unroll
    for (int i = 0; i < 16; ++i) {
      int e = t + i * 256;
      int d = e >> 6, ql_ = e & 63;
      int pix = q0 + ql_;
      int iy = (pix >> 5) + 1, ix = (pix & 31) + 1;
      outc[((size_t)(b * 256 + h * 64 + d)) * 1156 + iy * 34 + ix] = cvtpack(Tr[d][ql_]);
    }
  } else {
#pragma unroll
    for (int nt = 0; nt < 4; ++nt)
#pragma unroll
      for (int r = 0; r < 4; ++r) {
        int qm = q0 + wm + quad * 4 + r;
        outf[((size_t)pair * 1024 + qm) * 64 + nt * 16 + l16] = accO[nt][r];
      }
  }
}

// ---------------- per-pair top-256 via bitonic sort ------------------------
__global__ __launch_bounds__(256) void k_topk(
    const float* __restrict__ score, int* __restrict__ idx) {
  __shared__ unsigned long long key[1024];
  const int pair = blockIdx.x;
  const int t = threadIdx.x;
#pragma unroll
  for (int j = 0; j < 4; ++j) {
    int i = t + j * 256;
    unsigned u = __float_as_uint(score[pair * 1024 + i]);
    u = u ^ ((u & 0x80000000u) ? 0xFFFFFFFFu : 0x80000000u);
    u = ~u;
    key[i] = ((unsigned long long)u << 32) | (unsigned)i;
  }
  __syncthreads();
  for (int k = 2; k <= 1024; k <<= 1) {
    for (int j = k >> 1; j > 0; j >>= 1) {
      for (int w = 0; w < 4; ++w) {
        int i = t + w * 256;
        int l = i ^ j;
        if (l > i) {
          bool up = ((i & k) == 0);
          unsigned long long a = key[i], b = key[l];
          if ((a > b) == up) { key[i] = b; key[l] = a; }
        }
      }
      __syncthreads();
    }
  }
  idx[pair * 256 + t] = (int)(key[t] & 0xFFFFFFFFu);
}

// ---------------- convT as 4-class GEMM (packed input) ---------------------
__global__ __launch_bounds__(256) void k_convT_mfma(
    const unsigned* __restrict__ inp, const unsigned short* __restrict__ wth,
    const unsigned short* __restrict__ wtl, const float* __restrict__ bias,
    float* __restrict__ out) {
  __shared__ unsigned short Ah[64][72], Al[64][72], Bh[64][72], Bl[64][72];
  const int t = threadIdx.x;
  const int pix0 = blockIdx.x * 64;
  const int oc0 = blockIdx.y * 64;
  const int cls = blockIdx.z;
  const int ry = cls >> 1, rx = cls & 1;
  const int b = pix0 >> 10;
  const int wave = t >> 6, lane = t & 63;
  const int l16 = lane & 15, quad = lane >> 4;
  const int pixl = t & 63, icg = t >> 6;
  const int remg = (pix0 + pixl) & 1023;
  const int tyy = remg >> 5, txx = remg & 31;
  f32x4_t acc[4] = {};
  const size_t wbase = ((size_t)cls * 256 + oc0) * 1024;
  for (int kb = 0; kb < 1024; kb += 64) {
    const int tap = kb >> 8, ic0 = kb & 255;
    const int tk = tap >> 1, txi = tap & 1;
    const int iy = tyy + ry + 1 - tk, ix = txx + rx + 1 - txi;
    const unsigned* p = inp + (size_t)(b * 256 + ic0 + icg * 16) * 1156 + iy * 34 + ix;
    unsigned u[16];
#pragma unroll
    for (int j = 0; j < 16; ++j) u[j] = p[(size_t)j * 1156];
    unsigned hp[8], lpk[8];
#pragma unroll
    for (int j = 0; j < 8; ++j) {
      hp[j] = pk_h(u[2 * j], u[2 * j + 1]);
      lpk[j] = pk_l(u[2 * j], u[2 * j + 1]);
    }
    bf16x8_t a0h, a0l, a1h, a1l;
    {
      int r = t >> 3, kc = (t & 7) * 8;
      a0h = *(const bf16x8_t*)(wth + wbase + (size_t)r * 1024 + kb + kc);
      a0l = *(const bf16x8_t*)(wtl + wbase + (size_t)r * 1024 + kb + kc);
      a1h = *(const bf16x8_t*)(wth + wbase + (size_t)(r + 32) * 1024 + kb + kc);
      a1l = *(const bf16x8_t*)(wtl + wbase + (size_t)(r + 32) * 1024 + kb + kc);
    }
    __syncthreads();
    {
      int r = t >> 3, kc = (t & 7) * 8;
      *(bf16x8_t*)&Ah[r][kc] = a0h;      *(bf16x8_t*)&Al[r][kc] = a0l;
      *(bf16x8_t*)&Ah[r + 32][kc] = a1h; *(bf16x8_t*)&Al[r + 32][kc] = a1l;
    }
    *(uint4*)&Bh[pixl][icg * 16] = make_uint4(hp[0], hp[1], hp[2], hp[3]);
    *(uint4*)&Bh[pixl][icg * 16 + 8] = make_uint4(hp[4], hp[5], hp[6], hp[7]);
    *(uint4*)&Bl[pixl][icg * 16] = make_uint4(lpk[0], lpk[1], lpk[2], lpk[3]);
    *(uint4*)&Bl[pixl][icg * 16 + 8] = make_uint4(lpk[4], lpk[5], lpk[6], lpk[7]);
    __syncthreads();
    mfma_chunk(Ah, Al, Bh, Bl, acc, wave * 16, lane);
  }
  __syncthreads();
#pragma unroll
  for (int r = 0; r < 4; ++r) {
    int oc = oc0 + wave * 16 + quad * 4 + r;
    float bvs = bias[oc];
#pragma unroll
    for (int nt = 0; nt < 4; ++nt) {
      int pix = pix0 + nt * 16 + l16;
      int rem2 = pix & 1023;
      int y = (rem2 >> 5) * 2 + ry, xx = (rem2 & 31) * 2 + rx;
      out[((size_t)(b * 256 + oc) * 64 + y) * 64 + xx] = acc[nt][r] + bvs;
    }
  }
}

// ---------------- scatter fine outputs into y ------------------------------
__global__ __launch_bounds__(256) void k_scatter(
    const float* __restrict__ outf, const int* __restrict__ idx,
    float* __restrict__ y) {
  int g = blockIdx.x * 256 + threadIdx.x;
  int pair = g >> 16;
  int rem = g & 65535;
  int tok = rem >> 6, d = rem & 63;
  int b = pair >> 2, h = pair & 3;
  int pp = idx[pair * 256 + (tok >> 2)];
  int py = (tok >> 1) & 1, px = tok & 1;
  int ry = (pp >> 5) * 2 + py, rx = (pp & 31) * 2 + px;
  y[((size_t)(b * 256 + h * 64 + d) * 64 + ry) * 64 + rx] += outf[g];
}

// ---------------- depthwise 3x3 + BN + relu6 -> packed yd ------------------
__global__ __launch_bounds__(256) void k_dwconv(
    const float* __restrict__ y, const float* __restrict__ wdw,
    const float* __restrict__ g, const float* __restrict__ bb,
    const float* __restrict__ m, const float* __restrict__ vv,
    unsigned* __restrict__ ydhl) {
  int gi = blockIdx.x * 256 + threadIdx.x;
  int x = gi & 63, yy = (gi >> 6) & 63, ch = (gi >> 12) & 255, b = gi >> 20;
  const float* plane = y + (size_t)(b * 256 + ch) * 4096;
  const float* wc = wdw + ch * 9;
  float s = 0.f;
#pragma unroll
  for (int ky = 0; ky < 3; ++ky) {
    int iy = yy + ky - 1;
    if (iy < 0 || iy >= 64) continue;
#pragma unroll
    for (int kx = 0; kx < 3; ++kx) {
      int ix = x + kx - 1;
      if (ix < 0 || ix >= 64) continue;
      s = fmaf(plane[iy * 64 + ix], wc[ky * 3 + kx], s);
    }
  }
  float sc = g[ch] * rsqrtf(vv[ch] + EPS_);
  float val = s * sc + (bb[ch] - m[ch] * sc);
  ydhl[gi] = cvtpack(fminf(fmaxf(val, 0.f), 6.f));
}

// ---------------- pointwise 1x1 + BN + relu6 (packed input) ----------------
__global__ __launch_bounds__(256) void k_pw_mfma(
    const unsigned* __restrict__ ydhl, const unsigned short* __restrict__ wh,
    const unsigned short* __restrict__ wl, const float* __restrict__ g,
    const float* __restrict__ bb, const float* __restrict__ m,
    const float* __restrict__ vv, float* __restrict__ out) {
  __shared__ unsigned short Ah[64][72], Al[64][72], Bh[64][72], Bl[64][72];
  const int t = threadIdx.x;
  const int pix0 = blockIdx.x * 64;
  const int oc0 = blockIdx.y * 64;
  const int b = pix0 >> 12, pos0 = pix0 & 4095;
  const int wave = t >> 6, lane = t & 63;
  const int l16 = lane & 15, quad = lane >> 4;
  const int pixl = t & 63, icg = t >> 6;
  f32x4_t acc[4] = {};
  for (int kb = 0; kb < 256; kb += 64) {
    unsigned u[16];
#pragma unroll
    for (int j = 0; j < 16; ++j)
      u[j] = ydhl[(size_t)(b * 256 + kb + icg * 16 + j) * 4096 + pos0 + pixl];
    unsigned hp[8], lpk[8];
#pragma unroll
    for (int j = 0; j < 8; ++j) {
      hp[j] = pk_h(u[2 * j], u[2 * j + 1]);
      lpk[j] = pk_l(u[2 * j], u[2 * j + 1]);
    }
    bf16x8_t a0h, a0l, a1h, a1l;
    {
      int r = t >> 3, kc = (t & 7) * 8;
      a0h = *(const bf16x8_t*)(wh + (size_t)(oc0 + r) * 256 + kb + kc);
      a0l = *(const bf16x8_t*)(wl + (size_t)(oc0 + r) * 256 + kb + kc);
      a1h = *(const bf16x8_t*)(wh + (size_t)(oc0 + r + 32) * 256 + kb + kc);
      a1l = *(const bf16x8_t*)(wl + (size_t)(oc0 + r + 32) * 256 + kb + kc);
    }
    __syncthreads();
    {
      int r = t >> 3, kc = (t & 7) * 8;
      *(bf16x8_t*)&Ah[r][kc] = a0h;      *(bf16x8_t*)&Al[r][kc] = a0l;
      *(bf16x8_t*)&Ah[r + 32][kc] = a1h; *(bf16x8_t*)&Al[r + 32][kc] = a1l;
    }
    *(uint4*)&Bh[pixl][icg * 16] = make_uint4(hp[0], hp[1], hp[2], hp[3]);
    *(uint4*)&Bh[pixl][icg * 16 + 8] = make_uint4(hp[4], hp[5], hp[6], hp[7]);
    *(uint4*)&Bl[pixl][icg * 16] = make_uint4(lpk[0], lpk[1], lpk[2], lpk[3]);
    *(uint4*)&Bl[pixl][icg * 16 + 8] = make_uint4(lpk[4], lpk[5], lpk[6], lpk[7]);
    __syncthreads();
    mfma_chunk(Ah, Al, Bh, Bl, acc, wave * 16, lane);
    __syncthreads();
  }
#pragma unroll
  for (int r = 0; r < 4; ++r) {
    int oc = oc0 + wave * 16 + quad * 4 + r;
    float sc = g[oc] * rsqrtf(vv[oc] + EPS_);
    float off = bb[oc] - m[oc] * sc;
#pragma unroll
    for (int nt = 0; nt < 4; ++nt) {
      int pix = pos0 + nt * 16 + l16;
      float val = fminf(fmaxf(acc[nt][r] * sc + off, 0.f), 6.f);
      out[(size_t)(b * 256 + oc) * 4096 + pix] = val;
    }
  }
}

// ---------------------------------------------------------------------------
extern "C" void kernel_launch(void* const* d_in, const int* in_sizes, int n_in,
                              void* d_out, int out_size, void* d_ws, size_t ws_size,
                              hipStream_t stream) {
  (void)in_sizes; (void)n_in; (void)out_size; (void)ws_size;
  const float* x       = (const float*)d_in[0];
  const float* w_down  = (const float*)d_in[1];
  const float* b_down  = (const float*)d_in[2];
  const float* w_qkv_c = (const float*)d_in[3];
  const float* b_qkv_c = (const float*)d_in[4];
  const float* w_up    = (const float*)d_in[5];
  const float* b_up    = (const float*)d_in[6];
  const float* w_qkv_f = (const float*)d_in[7];
  const float* b_qkv_f = (const float*)d_in[8];
  const float* w_dw    = (const float*)d_in[9];
  const float* bn_dw_g = (const float*)d_in[10];
  const float* bn_dw_b = (const float*)d_in[11];
  const float* bn_dw_m = (const float*)d_in[12];
  const float* bn_dw_v = (const float*)d_in[13];
  const float* w_pw    = (const float*)d_in[14];
  const float* bn_pw_g = (const float*)d_in[15];
  const float* bn_pw_b = (const float*)d_in[16];
  const float* bn_pw_m = (const float*)d_in[17];
  const float* bn_pw_v = (const float*)d_in[18];

  float* ws = (float*)d_ws;  // offsets in 4-byte units
  unsigned*       xphl   = (unsigned*)ws;                   // 9,191,424 u (scratch)
  unsigned*       ydhl   = (unsigned*)ws;                   // 2,097,152 u (alias, later)
  unsigned short* qh     = (unsigned short*)(ws + 33554432);
  unsigned short* ql     = (unsigned short*)(ws + 34603008);
  unsigned short* kh     = (unsigned short*)(ws + 35651584);
  unsigned short* kl     = (unsigned short*)(ws + 36700160);
  unsigned short* vth    = (unsigned short*)(ws + 37748736);
  unsigned short* vtl    = (unsigned short*)(ws + 38797312);
  unsigned*       xdhl   = (unsigned*)(ws + 39845888);      // 2,097,152 u
  unsigned*       outcphl= (unsigned*)(ws + 41943040);      // 2,367,488 u
  float*          coarse = ws + 44310528;                   // 8,388,608 f
  float*          outf   = ws + 52699136;                   // 2,097,152 f
  float*          score  = ws + 54796288;                   // 32,768 f
  unsigned short* wdh    = (unsigned short*)(ws + 54829056);
  unsigned short* wdl    = (unsigned short*)(ws + 55353344);
  unsigned short* wt_hi  = (unsigned short*)(ws + 55877632);
  unsigned short* wt_lo  = (unsigned short*)(ws + 56401920);
  unsigned short* wpw_hi = (unsigned short*)(ws + 56926208);
  unsigned short* wpw_lo = (unsigned short*)(ws + 56958976);
  unsigned short* wqh_c  = (unsigned short*)(ws + 56991744);
  unsigned short* wql_c  = (unsigned short*)(ws + 56997888);
  unsigned short* wqh_f  = (unsigned short*)(ws + 57004032);
  unsigned short* wql_f  = (unsigned short*)(ws + 57010176);
  int*            idx    = (int*)(ws + 57016320);           // 8,192 int

  hipMemsetAsync(score, 0, 32768 * sizeof(float), stream);
  hipMemsetAsync(outcphl, 0, (size_t)2367488 * sizeof(unsigned), stream);
  k_pad_x<<<2048, 256, 0, stream>>>(x, xphl);
  k_cvt_wdown<<<4096, 256, 0, stream>>>(w_down, wdh, wdl);
  k_cvt_wqkv<<<48, 256, 0, stream>>>(w_qkv_c, wqh_c, wql_c);
  k_cvt_wqkv<<<48, 256, 0, stream>>>(w_qkv_f, wqh_f, wql_f);
  k_cvt_wup<<<4096, 256, 0, stream>>>(w_up, wt_hi, wt_lo);
  k_cvt_wpw<<<256, 256, 0, stream>>>(w_pw, wpw_hi, wpw_lo);

  k_conv_down_mfma<<<dim3(128, 4), 256, 0, stream>>>(xphl, wdh, wdl, b_down, xdhl);
  k_qkv_mfma<0><<<dim3(16, 32), 256, 0, stream>>>(xdhl, nullptr, wqh_c, wql_c, b_qkv_c,
                                                  nullptr, qh, ql, kh, kl, vth, vtl);
  k_attn<1><<<dim3(16, 32), 256, 0, stream>>>(qh, ql, kh, kl, vth, vtl, score,
                                              outcphl, nullptr);
  k_topk<<<32, 256, 0, stream>>>(score, idx);
  k_convT_mfma<<<dim3(128, 4, 4), 256, 0, stream>>>(outcphl, wt_hi, wt_lo, b_up, coarse);

  k_qkv_mfma<1><<<dim3(16, 32), 256, 0, stream>>>(nullptr, coarse, wqh_f, wql_f, b_qkv_f,
                                                  idx, qh, ql, kh, kl, vth, vtl);
  k_attn<0><<<dim3(16, 32), 256, 0, stream>>>(qh, ql, kh, kl, vth, vtl, nullptr,
                                              nullptr, outf);
  k_scatter<<<8192, 256, 0, stream>>>(outf, idx, coarse);
  k_dwconv<<<32768, 256, 0, stream>>>(coarse, w_dw, bn_dw_g, bn_dw_b, bn_dw_m, bn_dw_v, ydhl);
  k_pw_mfma<<<dim3(512, 4), 256, 0, stream>>>(ydhl, wpw_hi, wpw_lo, bn_pw_g, bn_pw_b,
                                              bn_pw_m, bn_pw_v, (float*)d_out);
}

// Round 8
// 616.961 us; speedup vs baseline: 2.6476x; 1.0169x over previous
//
#include <hip/hip_runtime.h>
#include <cstdint>
#include <cstddef>

// ---------------------------------------------------------------------------
// RegionSelectionAttention. Round 8: register-blocked GEMM tiles kept from
// round 7, but score-path numerics reverted to round 6 exactly (single-K
// conv_down with packed bf16 output; packed handoff to qkv). Round 7's
// split-K + fp32 handoff flipped one top-256 selection (absmax 0.166).
// ---------------------------------------------------------------------------

#define EPS_ 1e-5f

typedef short bf16x8_t __attribute__((ext_vector_type(8)));
typedef float f32x4_t __attribute__((ext_vector_type(4)));
#define MFMA16(a, b, c) __builtin_amdgcn_mfma_f32_16x16x32_bf16(a, b, c, 0, 0, 0)

__device__ __forceinline__ void cvt1(float f, unsigned short& h, unsigned short& l) {
  unsigned u = __float_as_uint(f);
  unsigned r = u + 0x7FFFu + ((u >> 16) & 1u);
  h = (unsigned short)(r >> 16);
  float lo = f - __uint_as_float(r & 0xFFFF0000u);
  l = (unsigned short)(__float_as_uint(lo) >> 16);
}
__device__ __forceinline__ unsigned cvtpack(float f) {
  unsigned short h, l;
  cvt1(f, h, l);
  return (unsigned)h | ((unsigned)l << 16);
}
__device__ __forceinline__ void cvt2(float f0, float f1, unsigned& hpack, unsigned& lpack) {
  unsigned u0 = __float_as_uint(f0), u1 = __float_as_uint(f1);
  unsigned r0 = u0 + 0x7FFFu + ((u0 >> 16) & 1u);
  unsigned r1 = u1 + 0x7FFFu + ((u1 >> 16) & 1u);
  hpack = (r0 >> 16) | (r1 & 0xFFFF0000u);
  float l0 = f0 - __uint_as_float(r0 & 0xFFFF0000u);
  float l1 = f1 - __uint_as_float(r1 & 0xFFFF0000u);
  lpack = (__float_as_uint(l0) >> 16) | (__float_as_uint(l1) & 0xFFFF0000u);
}
__device__ __forceinline__ unsigned pk_h(unsigned a, unsigned b) {
  return (a & 0xFFFFu) | (b << 16);
}
__device__ __forceinline__ unsigned pk_l(unsigned a, unsigned b) {
  return (a >> 16) | (b & 0xFFFF0000u);
}

// ---------------- pad x -> packed xphl[plane][66 rows x stride 68] ---------
__global__ __launch_bounds__(256) void k_pad_x(
    const float* __restrict__ x, unsigned* __restrict__ xphl) {
  const int plane = blockIdx.x;  // 2048
  const float* src = x + (size_t)plane * 4096;
  unsigned* dst = xphl + (size_t)plane * 4488;
  for (int e = threadIdx.x; e < 4356; e += 256) {
    int r = e / 66, cc = e - r * 66;
    float v = 0.f;
    if (r >= 1 && r <= 64 && cc >= 1 && cc <= 64) v = src[(r - 1) * 64 + (cc - 1)];
    dst[r * 68 + cc] = cvtpack(v);
  }
}

// ---------------- weight conversions ---------------------------------------
__global__ __launch_bounds__(256) void k_cvt_wdown(
    const float* __restrict__ w, unsigned short* __restrict__ wh,
    unsigned short* __restrict__ wl) {
  int e = blockIdx.x * 256 + threadIdx.x;  // 1,048,576: [oc][4096]
  cvt1(w[e], wh[e], wl[e]);
}

__global__ __launch_bounds__(256) void k_cvt_wqkv(
    const float* __restrict__ wq, unsigned short* __restrict__ wh,
    unsigned short* __restrict__ wl) {
  int e = blockIdx.x * 256 + threadIdx.x;  // 12288: [col][d]
  int col = e >> 6, d = e & 63;
  float f = wq[d * 192 + col];
  if (col < 64) f *= 0.125f;  // fold attn scale into q (pow2: exact)
  cvt1(f, wh[e], wl[e]);
}

__global__ __launch_bounds__(256) void k_cvt_wup(
    const float* __restrict__ w_up, unsigned short* __restrict__ wth,
    unsigned short* __restrict__ wtl) {
  int e = blockIdx.x * 256 + threadIdx.x;  // 2^20: [class][oc][kp=tap*256+ic]
  int kp = e & 1023, oc = (e >> 10) & 255, c = e >> 18;
  int tap = kp >> 8, ic = kp & 255;
  int tk = tap >> 1, txi = tap & 1;
  int ry = c >> 1, rx = c & 1;
  int ky = (1 - ry) + 2 * tk, kx = (1 - rx) + 2 * txi;
  cvt1(w_up[((size_t)(ic * 256 + oc) * 4 + ky) * 4 + kx], wth[e], wtl[e]);
}

__global__ __launch_bounds__(256) void k_cvt_wpw(
    const float* __restrict__ w, unsigned short* __restrict__ wh,
    unsigned short* __restrict__ wl) {
  int e = blockIdx.x * 256 + threadIdx.x;  // 65536 [oc][ic]
  cvt1(w[e], wh[e], wl[e]);
}

// ====================== MFMA cores =========================================
// 16m x 64n wave tile (attention / qkv path)
__device__ __forceinline__ void mfma_chunk(
    const unsigned short (*Ah)[72], const unsigned short (*Al)[72],
    const unsigned short (*Bh)[72], const unsigned short (*Bl)[72],
    f32x4_t (&acc)[4], int wm, int lane) {
  const int l16 = lane & 15, quad = lane >> 4;
#pragma unroll
  for (int ks = 0; ks < 2; ++ks) {
    int ko = ks * 32 + quad * 8;
    bf16x8_t ah = *(const bf16x8_t*)&Ah[wm + l16][ko];
    bf16x8_t al = *(const bf16x8_t*)&Al[wm + l16][ko];
#pragma unroll
    for (int nt = 0; nt < 4; ++nt) {
      bf16x8_t bh = *(const bf16x8_t*)&Bh[nt * 16 + l16][ko];
      bf16x8_t bl = *(const bf16x8_t*)&Bl[nt * 16 + l16][ko];
      acc[nt] = MFMA16(ah, bh, acc[nt]);
      acc[nt] = MFMA16(ah, bl, acc[nt]);
      acc[nt] = MFMA16(al, bh, acc[nt]);
    }
  }
}

// 32m x 32n wave tile (conv_down: 64x64 block, 2x2 waves)
__device__ __forceinline__ void mfma_tile2x2(
    const unsigned short (*Ah)[72], const unsigned short (*Al)[72],
    const unsigned short (*Bh)[72], const unsigned short (*Bl)[72],
    f32x4_t (&acc)[2][2], int wm, int wn, int lane) {
  const int l16 = lane & 15, quad = lane >> 4;
#pragma unroll
  for (int ks = 0; ks < 2; ++ks) {
    int ko = ks * 32 + quad * 8;
    bf16x8_t ah[2], al[2];
#pragma unroll
    for (int mt = 0; mt < 2; ++mt) {
      ah[mt] = *(const bf16x8_t*)&Ah[wm + mt * 16 + l16][ko];
      al[mt] = *(const bf16x8_t*)&Al[wm + mt * 16 + l16][ko];
    }
#pragma unroll
    for (int nt = 0; nt < 2; ++nt) {
      bf16x8_t bh = *(const bf16x8_t*)&Bh[wn + nt * 16 + l16][ko];
      bf16x8_t bl = *(const bf16x8_t*)&Bl[wn + nt * 16 + l16][ko];
#pragma unroll
      for (int mt = 0; mt < 2; ++mt) {
        acc[mt][nt] = MFMA16(ah[mt], bh, acc[mt][nt]);
        acc[mt][nt] = MFMA16(ah[mt], bl, acc[mt][nt]);
        acc[mt][nt] = MFMA16(al[mt], bh, acc[mt][nt]);
      }
    }
  }
}

// 32m x 64n wave tile (convT/pw: 64x128 block, 2x2 waves)
__device__ __forceinline__ void mfma_tile2x4(
    const unsigned short (*Ah)[72], const unsigned short (*Al)[72],
    const unsigned short (*Bh)[72], const unsigned short (*Bl)[72],
    f32x4_t (&acc)[2][4], int wm, int wn, int lane) {
  const int l16 = lane & 15, quad = lane >> 4;
#pragma unroll
  for (int ks = 0; ks < 2; ++ks) {
    int ko = ks * 32 + quad * 8;
    bf16x8_t ah[2], al[2];
#pragma unroll
    for (int mt = 0; mt < 2; ++mt) {
      ah[mt] = *(const bf16x8_t*)&Ah[wm + mt * 16 + l16][ko];
      al[mt] = *(const bf16x8_t*)&Al[wm + mt * 16 + l16][ko];
    }
#pragma unroll
    for (int nt = 0; nt < 4; ++nt) {
      bf16x8_t bh = *(const bf16x8_t*)&Bh[wn + nt * 16 + l16][ko];
      bf16x8_t bl = *(const bf16x8_t*)&Bl[wn + nt * 16 + l16][ko];
#pragma unroll
      for (int mt = 0; mt < 2; ++mt) {
        acc[mt][nt] = MFMA16(ah[mt], bh, acc[mt][nt]);
        acc[mt][nt] = MFMA16(ah[mt], bl, acc[mt][nt]);
        acc[mt][nt] = MFMA16(al[mt], bh, acc[mt][nt]);
      }
    }
  }
}

// ---------------- conv down k4 s2 p1, 64oc x 64pix, 2x2 waves, K=4096 ------
// Values bit-identical to round 6 (same K chain, bias in epilogue, packed out).
__global__ __launch_bounds__(256) void k_conv_down_mfma(
    const unsigned* __restrict__ xphl, const unsigned short* __restrict__ wdh,
    const unsigned short* __restrict__ wdl, const float* __restrict__ bias,
    unsigned* __restrict__ xdhl) {
  __shared__ unsigned short Ah[64][72], Al[64][72], Bh[64][72], Bl[64][72];
  const int t = threadIdx.x;
  const int pix0 = blockIdx.x * 64, oc0 = blockIdx.y * 64;
  const int bimg = pix0 >> 10, pos = pix0 & 1023;
  const int pl = t & 63, icg = t >> 6;
  const int rem = (pix0 + pl) & 1023;
  const int oy = rem >> 5, ox = rem & 31;
  const unsigned* xb = xphl + ((size_t)bimg * 256 + icg) * 4488 + (oy * 2) * 68 + ox * 2;
  const int wave = t >> 6, lane = t & 63, l16 = lane & 15, quad = lane >> 4;
  const int wm = (wave & 1) * 32, wn = (wave >> 1) * 32;
  const int ar = t >> 2, ac = (t & 3) * 16;
  const unsigned short* wra = wdh + (size_t)(oc0 + ar) * 4096 + ac;
  const unsigned short* wrl = wdl + (size_t)(oc0 + ar) * 4096 + ac;
  f32x4_t acc[2][2] = {};
  for (int kb = 0; kb < 4096; kb += 64) {
    bf16x8_t a0 = *(const bf16x8_t*)(wra + kb);
    bf16x8_t a1 = *(const bf16x8_t*)(wra + kb + 8);
    bf16x8_t a2 = *(const bf16x8_t*)(wrl + kb);
    bf16x8_t a3 = *(const bf16x8_t*)(wrl + kb + 8);
    unsigned u[16];
#pragma unroll
    for (int r = 0; r < 4; ++r) {
      uint2 u01 = *(const uint2*)(xb + r * 68);
      uint2 u23 = *(const uint2*)(xb + r * 68 + 2);
      u[4 * r + 0] = u01.x; u[4 * r + 1] = u01.y;
      u[4 * r + 2] = u23.x; u[4 * r + 3] = u23.y;
    }
    unsigned hp[8], lp[8];
#pragma unroll
    for (int j = 0; j < 8; ++j) {
      hp[j] = pk_h(u[2 * j], u[2 * j + 1]);
      lp[j] = pk_l(u[2 * j], u[2 * j + 1]);
    }
    __syncthreads();
    *(bf16x8_t*)&Ah[ar][ac] = a0;
    *(bf16x8_t*)&Ah[ar][ac + 8] = a1;
    *(bf16x8_t*)&Al[ar][ac] = a2;
    *(bf16x8_t*)&Al[ar][ac + 8] = a3;
    *(uint4*)&Bh[pl][icg * 16] = make_uint4(hp[0], hp[1], hp[2], hp[3]);
    *(uint4*)&Bh[pl][icg * 16 + 8] = make_uint4(hp[4], hp[5], hp[6], hp[7]);
    *(uint4*)&Bl[pl][icg * 16] = make_uint4(lp[0], lp[1], lp[2], lp[3]);
    *(uint4*)&Bl[pl][icg * 16 + 8] = make_uint4(lp[4], lp[5], lp[6], lp[7]);
    __syncthreads();
    mfma_tile2x2(Ah, Al, Bh, Bl, acc, wm, wn, lane);
    xb += 4 * 4488;
  }
#pragma unroll
  for (int mt = 0; mt < 2; ++mt)
#pragma unroll
    for (int r = 0; r < 4; ++r) {
      int oc = oc0 + wm + mt * 16 + quad * 4 + r;
      float bv = bias[oc];
#pragma unroll
      for (int nt = 0; nt < 2; ++nt)
        xdhl[((size_t)(bimg * 256 + oc)) * 1024 + pos + wn + nt * 16 + l16] =
            cvtpack(acc[mt][nt][r] + bv);
    }
}

// ---------------- qkv projection (round 6 version) -------------------------
// MODE0: coarse, reads packed xdhl. MODE1: fine gather from fp32 coarse.
template <int MODE>
__global__ __launch_bounds__(256) void k_qkv_mfma(
    const unsigned* __restrict__ srcp, const float* __restrict__ srcf,
    const unsigned short* __restrict__ wh, const unsigned short* __restrict__ wl,
    const float* __restrict__ bq, const int* __restrict__ topk,
    unsigned short* __restrict__ qh, unsigned short* __restrict__ ql,
    unsigned short* __restrict__ kh, unsigned short* __restrict__ kl,
    unsigned short* __restrict__ vth, unsigned short* __restrict__ vtl) {
  __shared__ unsigned short Ah[64][72], Al[64][72];
  const int t = threadIdx.x;
  const int tok0 = blockIdx.x * 64;
  const int pair = blockIdx.y;
  const int b = pair >> 2, h = pair & 3;
  const int tokl = t & 63, dg = t >> 6;
  unsigned hp[8], lp[8];
  if (MODE == 0) {
    const unsigned* base = srcp + ((size_t)(b * 256 + h * 64 + dg * 16)) * 1024 + tok0 + tokl;
    unsigned u[16];
#pragma unroll
    for (int j = 0; j < 16; ++j) u[j] = base[(size_t)j * 1024];
#pragma unroll
    for (int j = 0; j < 8; ++j) {
      hp[j] = pk_h(u[2 * j], u[2 * j + 1]);
      lp[j] = pk_l(u[2 * j], u[2 * j + 1]);
    }
  } else {
    int tok = tok0 + tokl;
    int pp = topk[pair * 256 + (tok >> 2)];
    int py = (tok >> 1) & 1, px = tok & 1;
    int ry = (pp >> 5) * 2 + py, rx = (pp & 31) * 2 + px;
    const float* base = srcf + ((size_t)(b * 256 + h * 64 + dg * 16)) * 4096 + ry * 64 + rx;
    float fv[16];
#pragma unroll
    for (int j = 0; j < 16; ++j) fv[j] = base[(size_t)j * 4096];
#pragma unroll
    for (int j = 0; j < 8; ++j) cvt2(fv[2 * j], fv[2 * j + 1], hp[j], lp[j]);
  }
  *(uint4*)&Ah[tokl][dg * 16] = make_uint4(hp[0], hp[1], hp[2], hp[3]);
  *(uint4*)&Ah[tokl][dg * 16 + 8] = make_uint4(hp[4], hp[5], hp[6], hp[7]);
  *(uint4*)&Al[tokl][dg * 16] = make_uint4(lp[0], lp[1], lp[2], lp[3]);
  *(uint4*)&Al[tokl][dg * 16 + 8] = make_uint4(lp[4], lp[5], lp[6], lp[7]);
  __syncthreads();
  const int wave = t >> 6, lane = t & 63, l16 = lane & 15, quad = lane >> 4;
  f32x4_t acc[4][3] = {};
#pragma unroll
  for (int ks = 0; ks < 2; ++ks) {
    int ko = ks * 32 + quad * 8;
    bf16x8_t bh0[3], bl0[3];
#pragma unroll
    for (int nt = 0; nt < 3; ++nt) {
      int col = wave * 48 + nt * 16 + l16;
      bh0[nt] = *(const bf16x8_t*)(wh + col * 64 + ko);
      bl0[nt] = *(const bf16x8_t*)(wl + col * 64 + ko);
    }
#pragma unroll
    for (int mt = 0; mt < 4; ++mt) {
      bf16x8_t ah = *(const bf16x8_t*)&Ah[mt * 16 + l16][ko];
      bf16x8_t al = *(const bf16x8_t*)&Al[mt * 16 + l16][ko];
#pragma unroll
      for (int nt = 0; nt < 3; ++nt) {
        acc[mt][nt] = MFMA16(ah, bh0[nt], acc[mt][nt]);
        acc[mt][nt] = MFMA16(ah, bl0[nt], acc[mt][nt]);
        acc[mt][nt] = MFMA16(al, bh0[nt], acc[mt][nt]);
      }
    }
  }
#pragma unroll
  for (int nt = 0; nt < 3; ++nt) {
    int col = wave * 48 + nt * 16 + l16;
    float bqv = bq[col];
    if (col < 64) bqv *= 0.125f;
#pragma unroll
    for (int mt = 0; mt < 4; ++mt) {
#pragma unroll
      for (int r = 0; r < 4; ++r) {
        int tok = tok0 + mt * 16 + quad * 4 + r;
        float val = acc[mt][nt][r] + bqv;
        unsigned short hh, ll;
        cvt1(val, hh, ll);
        if (col < 64) {
          size_t o = ((size_t)pair * 1024 + tok) * 64 + col;
          qh[o] = hh; ql[o] = ll;
        } else if (col < 128) {
          size_t o = ((size_t)pair * 1024 + tok) * 64 + (col - 64);
          kh[o] = hh; kl[o] = ll;
        } else {
          size_t o = ((size_t)pair * 64 + (col - 128)) * 1024 + tok;
          vth[o] = hh; vtl[o] = ll;
        }
      }
    }
  }
}

// ---------------- fused flash attention ------------------------------------
template <int COARSE>
__global__ __launch_bounds__(256) void k_attn(
    const unsigned short* __restrict__ qh, const unsigned short* __restrict__ ql,
    const unsigned short* __restrict__ kh, const unsigned short* __restrict__ kl,
    const unsigned short* __restrict__ vth, const unsigned short* __restrict__ vtl,
    float* __restrict__ score, unsigned* __restrict__ outc,
    float* __restrict__ outf) {
  __shared__ __align__(16) unsigned short Qb[2][64][72];
  __shared__ __align__(16) unsigned short Kb[2][64][72];
  __shared__ __align__(16) unsigned short Pb[2][64][72];
  __shared__ float mlW[4][2][64];
  __shared__ float mC[64], lC[64];
  __shared__ float colsum[1024];
  const int t = threadIdx.x;
  const int q0 = blockIdx.x * 64;
  const int pair = blockIdx.y;
  const int wave = t >> 6, lane = t & 63;
  const int l16 = lane & 15, quad = lane >> 4;
  const int wm = wave * 16;
  const int sr = t >> 3, skc = (t & 7) * 8;

  const size_t qbase = ((size_t)pair * 1024 + q0) * 64;
#pragma unroll
  for (int i = 0; i < 2; ++i) {
    int r = sr + i * 32;
    *(bf16x8_t*)&Qb[0][r][skc] = *(const bf16x8_t*)(qh + qbase + (size_t)r * 64 + skc);
    *(bf16x8_t*)&Qb[1][r][skc] = *(const bf16x8_t*)(ql + qbase + (size_t)r * 64 + skc);
  }
  if (COARSE) {
#pragma unroll
    for (int i = 0; i < 4; ++i) colsum[t + i * 256] = 0.f;
  }

  const size_t kmbase = (size_t)pair * 1024 * 64;
  const size_t vbase = (size_t)pair * 64 * 1024;

  float mrun[4] = {-1e30f, -1e30f, -1e30f, -1e30f};
  float lrun[4] = {0.f, 0.f, 0.f, 0.f};
  for (int kb = 0; kb < 1024; kb += 64) {
    __syncthreads();
#pragma unroll
    for (int i = 0; i < 2; ++i) {
      int r = sr + i * 32;
      *(bf16x8_t*)&Kb[0][r][skc] = *(const bf16x8_t*)(kh + kmbase + (size_t)(kb + r) * 64 + skc);
      *(bf16x8_t*)&Kb[1][r][skc] = *(const bf16x8_t*)(kl + kmbase + (size_t)(kb + r) * 64 + skc);
    }
    __syncthreads();
    f32x4_t acc[4] = {};
    mfma_chunk(Kb[0], Kb[1], Qb[0], Qb[1], acc, wm, lane);
#pragma unroll
    for (int nt = 0; nt < 4; ++nt) {
      float m0 = fmaxf(fmaxf(acc[nt][0], acc[nt][1]), fmaxf(acc[nt][2], acc[nt][3]));
      m0 = fmaxf(m0, __shfl_xor(m0, 16));
      m0 = fmaxf(m0, __shfl_xor(m0, 32));
      float mn = fmaxf(mrun[nt], m0);
      float s0 = __expf(acc[nt][0] - mn) + __expf(acc[nt][1] - mn) +
                 __expf(acc[nt][2] - mn) + __expf(acc[nt][3] - mn);
      s0 += __shfl_xor(s0, 16);
      s0 += __shfl_xor(s0, 32);
      lrun[nt] = lrun[nt] * __expf(mrun[nt] - mn) + s0;
      mrun[nt] = mn;
    }
  }
  __syncthreads();
  if (quad == 0) {
#pragma unroll
    for (int nt = 0; nt < 4; ++nt) {
      mlW[wave][0][nt * 16 + l16] = mrun[nt];
      mlW[wave][1][nt * 16 + l16] = lrun[nt];
    }
  }
  __syncthreads();
  if (t < 64) {
    float m0 = mlW[0][0][t], m1 = mlW[1][0][t], m2 = mlW[2][0][t], m3 = mlW[3][0][t];
    float mm = fmaxf(fmaxf(m0, m1), fmaxf(m2, m3));
    float ll = mlW[0][1][t] * __expf(m0 - mm) + mlW[1][1][t] * __expf(m1 - mm) +
               mlW[2][1][t] * __expf(m2 - mm) + mlW[3][1][t] * __expf(m3 - mm);
    mC[t] = mm;
    lC[t] = 1.0f / ll;
  }
  __syncthreads();
  float mq[4], il[4];
#pragma unroll
  for (int nt = 0; nt < 4; ++nt) {
    mq[nt] = mC[nt * 16 + l16];
    il[nt] = lC[nt * 16 + l16];
  }

  f32x4_t accO[4] = {};
  for (int kb = 0; kb < 1024; kb += 64) {
    __syncthreads();
#pragma unroll
    for (int i = 0; i < 2; ++i) {
      int r = sr + i * 32;
      *(bf16x8_t*)&Kb[0][r][skc] = *(const bf16x8_t*)(kh + kmbase + (size_t)(kb + r) * 64 + skc);
      *(bf16x8_t*)&Kb[1][r][skc] = *(const bf16x8_t*)(kl + kmbase + (size_t)(kb + r) * 64 + skc);
    }
    __syncthreads();
    f32x4_t acc[4] = {};
    mfma_chunk(Kb[0], Kb[1], Qb[0], Qb[1], acc, wm, lane);
    float P[4][4];
#pragma unroll
    for (int nt = 0; nt < 4; ++nt)
#pragma unroll
      for (int r = 0; r < 4; ++r) P[nt][r] = __expf(acc[nt][r] - mq[nt]) * il[nt];
    if (COARSE) {
#pragma unroll
      for (int r = 0; r < 4; ++r) {
        float cs = P[0][r] + P[1][r] + P[2][r] + P[3][r];
        cs += __shfl_xor(cs, 1);
        cs += __shfl_xor(cs, 2);
        cs += __shfl_xor(cs, 4);
        cs += __shfl_xor(cs, 8);
        if (l16 == 0) colsum[kb + wm + quad * 4 + r] += cs;
      }
    }
    __syncthreads();
#pragma unroll
    for (int nt = 0; nt < 4; ++nt) {
      unsigned h01, l01, h23, l23;
      cvt2(P[nt][0], P[nt][1], h01, l01);
      cvt2(P[nt][2], P[nt][3], h23, l23);
      *(uint2*)&Pb[0][nt * 16 + l16][wm + quad * 4] = make_uint2(h01, h23);
      *(uint2*)&Pb[1][nt * 16 + l16][wm + quad * 4] = make_uint2(l01, l23);
    }
#pragma unroll
    for (int i = 0; i < 2; ++i) {
      int r = sr + i * 32;
      *(bf16x8_t*)&Kb[0][r][skc] = *(const bf16x8_t*)(vth + vbase + (size_t)r * 1024 + kb + skc);
      *(bf16x8_t*)&Kb[1][r][skc] = *(const bf16x8_t*)(vtl + vbase + (size_t)r * 1024 + kb + skc);
    }
    __syncthreads();
    mfma_chunk(Pb[0], Pb[1], Kb[0], Kb[1], accO, wm, lane);
  }
  __syncthreads();

  if (COARSE) {
#pragma unroll
    for (int i = 0; i < 4; ++i)
      atomicAdd(&score[pair * 1024 + t + i * 256], colsum[t + i * 256]);
    float (*Tr)[68] = reinterpret_cast<float(*)[68]>(&Pb[0][0][0]);
#pragma unroll
    for (int nt = 0; nt < 4; ++nt)
#pragma unroll
      for (int r = 0; r < 4; ++r)
        Tr[nt * 16 + l16][wm + quad * 4 + r] = accO[nt][r];
    __syncthreads();
    const int b = pair >> 2, h = pair & 3;
#pragma unroll
    for (int i = 0; i < 16; ++i) {
      int e = t + i * 256;
      int d = e >> 6, ql_ = e & 63;
      int pix = q0 + ql_;
      int iy = (pix >> 5) + 1, ix = (pix & 31) + 1;
      outc[((size_t)(b * 256 + h * 64 + d)) * 1156 + iy * 34 + ix] = cvtpack(Tr[d][ql_]);
    }
  } else {
#pragma unroll
    for (int nt = 0; nt < 4; ++nt)
#pragma unroll
      for (int r = 0; r < 4; ++r) {
        int qm = q0 + wm + quad * 4 + r;
        outf[((size_t)pair * 1024 + qm) * 64 + nt * 16 + l16] = accO[nt][r];
      }
  }
}

// ---------------- per-pair top-256 via bitonic sort ------------------------
__global__ __launch_bounds__(256) void k_topk(
    const float* __restrict__ score, int* __restrict__ idx) {
  __shared__ unsigned long long key[1024];
  const int pair = blockIdx.x;
  const int t = threadIdx.x;
#pragma unroll
  for (int j = 0; j < 4; ++j) {
    int i = t + j * 256;
    unsigned u = __float_as_uint(score[pair * 1024 + i]);
    u = u ^ ((u & 0x80000000u) ? 0xFFFFFFFFu : 0x80000000u);
    u = ~u;
    key[i] = ((unsigned long long)u << 32) | (unsigned)i;
  }
  __syncthreads();
  for (int k = 2; k <= 1024; k <<= 1) {
    for (int j = k >> 1; j > 0; j >>= 1) {
      for (int w = 0; w < 4; ++w) {
        int i = t + w * 256;
        int l = i ^ j;
        if (l > i) {
          bool up = ((i & k) == 0);
          unsigned long long a = key[i], b = key[l];
          if ((a > b) == up) { key[i] = b; key[l] = a; }
        }
      }
      __syncthreads();
    }
  }
  idx[pair * 256 + t] = (int)(key[t] & 0xFFFFFFFFu);
}

// ---------------- convT: 64oc x 128pix tile, 4 classes ---------------------
__global__ __launch_bounds__(256) void k_convT_mfma(
    const unsigned* __restrict__ inp, const unsigned short* __restrict__ wth,
    const unsigned short* __restrict__ wtl, const float* __restrict__ bias,
    float* __restrict__ out) {
  __shared__ unsigned short Ah[64][72], Al[64][72];
  __shared__ unsigned short Bh[128][72], Bl[128][72];
  const int t = threadIdx.x;
  const int pix0 = blockIdx.x * 128;
  const int oc0 = blockIdx.y * 64;
  const int cls = blockIdx.z;
  const int ry = cls >> 1, rx = cls & 1;
  const int b = pix0 >> 10;
  const int wave = t >> 6, lane = t & 63;
  const int l16 = lane & 15, quad = lane >> 4;
  const int wm = (wave & 1) * 32, wn = (wave >> 1) * 64;
  const int pl = t & 127, icg = t >> 7;
  const int remg = (pix0 + pl) & 1023;
  const int tyy = remg >> 5, txx = remg & 31;
  const int ar = t >> 2, ac = (t & 3) * 16;
  const size_t wbase = ((size_t)cls * 256 + oc0 + ar) * 1024 + ac;
  f32x4_t acc[2][4] = {};
  for (int kb = 0; kb < 1024; kb += 64) {
    const int tap = kb >> 8, ic0 = kb & 255;
    const int tk = tap >> 1, txi = tap & 1;
    const int iy = tyy + ry + 1 - tk, ix = txx + rx + 1 - txi;
    const unsigned* p = inp + (size_t)(b * 256 + ic0 + icg * 32) * 1156 + iy * 34 + ix;
    unsigned u[32];
#pragma unroll
    for (int j = 0; j < 32; ++j) u[j] = p[(size_t)j * 1156];
    unsigned hp[16], lpk[16];
#pragma unroll
    for (int j = 0; j < 16; ++j) {
      hp[j] = pk_h(u[2 * j], u[2 * j + 1]);
      lpk[j] = pk_l(u[2 * j], u[2 * j + 1]);
    }
    bf16x8_t a0 = *(const bf16x8_t*)(wth + wbase + kb);
    bf16x8_t a1 = *(const bf16x8_t*)(wth + wbase + kb + 8);
    bf16x8_t a2 = *(const bf16x8_t*)(wtl + wbase + kb);
    bf16x8_t a3 = *(const bf16x8_t*)(wtl + wbase + kb + 8);
    __syncthreads();
    *(bf16x8_t*)&Ah[ar][ac] = a0;
    *(bf16x8_t*)&Ah[ar][ac + 8] = a1;
    *(bf16x8_t*)&Al[ar][ac] = a2;
    *(bf16x8_t*)&Al[ar][ac + 8] = a3;
    {
      int kc = icg * 32;
      *(uint4*)&Bh[pl][kc] = make_uint4(hp[0], hp[1], hp[2], hp[3]);
      *(uint4*)&Bh[pl][kc + 8] = make_uint4(hp[4], hp[5], hp[6], hp[7]);
      *(uint4*)&Bh[pl][kc + 16] = make_uint4(hp[8], hp[9], hp[10], hp[11]);
      *(uint4*)&Bh[pl][kc + 24] = make_uint4(hp[12], hp[13], hp[14], hp[15]);
      *(uint4*)&Bl[pl][kc] = make_uint4(lpk[0], lpk[1], lpk[2], lpk[3]);
      *(uint4*)&Bl[pl][kc + 8] = make_uint4(lpk[4], lpk[5], lpk[6], lpk[7]);
      *(uint4*)&Bl[pl][kc + 16] = make_uint4(lpk[8], lpk[9], lpk[10], lpk[11]);
      *(uint4*)&Bl[pl][kc + 24] = make_uint4(lpk[12], lpk[13], lpk[14], lpk[15]);
    }
    __syncthreads();
    mfma_tile2x4(Ah, Al, Bh, Bl, acc, wm, wn, lane);
  }
#pragma unroll
  for (int mt = 0; mt < 2; ++mt)
#pragma unroll
    for (int r = 0; r < 4; ++r) {
      int oc = oc0 + wm + mt * 16 + quad * 4 + r;
      float bvs = bias[oc];
#pragma unroll
      for (int nt = 0; nt < 4; ++nt) {
        int pix = pix0 + wn + nt * 16 + l16;
        int rem2 = pix & 1023;
        int y = (rem2 >> 5) * 2 + ry, xx = (rem2 & 31) * 2 + rx;
        out[((size_t)(b * 256 + oc) * 64 + y) * 64 + xx] = acc[mt][nt][r] + bvs;
      }
    }
}

// ---------------- scatter fine outputs into y ------------------------------
__global__ __launch_bounds__(256) void k_scatter(
    const float* __restrict__ outf, const int* __restrict__ idx,
    float* __restrict__ y) {
  int g = blockIdx.x * 256 + threadIdx.x;
  int pair = g >> 16;
  int rem = g & 65535;
  int tok = rem >> 6, d = rem & 63;
  int b = pair >> 2, h = pair & 3;
  int pp = idx[pair * 256 + (tok >> 2)];
  int py = (tok >> 1) & 1, px = tok & 1;
  int ry = (pp >> 5) * 2 + py, rx = (pp & 31) * 2 + px;
  y[((size_t)(b * 256 + h * 64 + d) * 64 + ry) * 64 + rx] += outf[g];
}

// ---------------- depthwise 3x3 + BN + relu6 -> packed yd ------------------
__global__ __launch_bounds__(256) void k_dwconv(
    const float* __restrict__ y, const float* __restrict__ wdw,
    const float* __restrict__ g, const float* __restrict__ bb,
    const float* __restrict__ m, const float* __restrict__ vv,
    unsigned* __restrict__ ydhl) {
  int gi = blockIdx.x * 256 + threadIdx.x;
  int x = gi & 63, yy = (gi >> 6) & 63, ch = (gi >> 12) & 255, b = gi >> 20;
  const float* plane = y + (size_t)(b * 256 + ch) * 4096;
  const float* wc = wdw + ch * 9;
  float s = 0.f;
#pragma unroll
  for (int ky = 0; ky < 3; ++ky) {
    int iy = yy + ky - 1;
    if (iy < 0 || iy >= 64) continue;
#pragma unroll
    for (int kx = 0; kx < 3; ++kx) {
      int ix = x + kx - 1;
      if (ix < 0 || ix >= 64) continue;
      s = fmaf(plane[iy * 64 + ix], wc[ky * 3 + kx], s);
    }
  }
  float sc = g[ch] * rsqrtf(vv[ch] + EPS_);
  float val = s * sc + (bb[ch] - m[ch] * sc);
  ydhl[gi] = cvtpack(fminf(fmaxf(val, 0.f), 6.f));
}

// ---------------- pointwise 1x1 + BN + relu6, 64oc x 128pix ----------------
__global__ __launch_bounds__(256) void k_pw_mfma(
    const unsigned* __restrict__ ydhl, const unsigned short* __restrict__ wh,
    const unsigned short* __restrict__ wl, const float* __restrict__ g,
    const float* __restrict__ bb, const float* __restrict__ m,
    const float* __restrict__ vv, float* __restrict__ out) {
  __shared__ unsigned short Ah[64][72], Al[64][72];
  __shared__ unsigned short Bh[128][72], Bl[128][72];
  const int t = threadIdx.x;
  const int pix0 = blockIdx.x * 128;
  const int oc0 = blockIdx.y * 64;
  const int b = pix0 >> 12, pos0 = pix0 & 4095;
  const int wave = t >> 6, lane = t & 63;
  const int l16 = lane & 15, quad = lane >> 4;
  const int wm = (wave & 1) * 32, wn = (wave >> 1) * 64;
  const int pl = t & 127, icg = t >> 7;
  const int ar = t >> 2, ac = (t & 3) * 16;
  f32x4_t acc[2][4] = {};
  for (int kb = 0; kb < 256; kb += 64) {
    const unsigned* p = ydhl + (size_t)(b * 256 + kb + icg * 32) * 4096 + pos0 + pl;
    unsigned u[32];
#pragma unroll
    for (int j = 0; j < 32; ++j) u[j] = p[(size_t)j * 4096];
    unsigned hp[16], lpk[16];
#pragma unroll
    for (int j = 0; j < 16; ++j) {
      hp[j] = pk_h(u[2 * j], u[2 * j + 1]);
      lpk[j] = pk_l(u[2 * j], u[2 * j + 1]);
    }
    bf16x8_t a0 = *(const bf16x8_t*)(wh + (size_t)(oc0 + ar) * 256 + kb + ac);
    bf16x8_t a1 = *(const bf16x8_t*)(wh + (size_t)(oc0 + ar) * 256 + kb + ac + 8);
    bf16x8_t a2 = *(const bf16x8_t*)(wl + (size_t)(oc0 + ar) * 256 + kb + ac);
    bf16x8_t a3 = *(const bf16x8_t*)(wl + (size_t)(oc0 + ar) * 256 + kb + ac + 8);
    __syncthreads();
    *(bf16x8_t*)&Ah[ar][ac] = a0;
    *(bf16x8_t*)&Ah[ar][ac + 8] = a1;
    *(bf16x8_t*)&Al[ar][ac] = a2;
    *(bf16x8_t*)&Al[ar][ac + 8] = a3;
    {
      int kc = icg * 32;
      *(uint4*)&Bh[pl][kc] = make_uint4(hp[0], hp[1], hp[2], hp[3]);
      *(uint4*)&Bh[pl][kc + 8] = make_uint4(hp[4], hp[5], hp[6], hp[7]);
      *(uint4*)&Bh[pl][kc + 16] = make_uint4(hp[8], hp[9], hp[10], hp[11]);
      *(uint4*)&Bh[pl][kc + 24] = make_uint4(hp[12], hp[13], hp[14], hp[15]);
      *(uint4*)&Bl[pl][kc] = make_uint4(lpk[0], lpk[1], lpk[2], lpk[3]);
      *(uint4*)&Bl[pl][kc + 8] = make_uint4(lpk[4], lpk[5], lpk[6], lpk[7]);
      *(uint4*)&Bl[pl][kc + 16] = make_uint4(lpk[8], lpk[9], lpk[10], lpk[11]);
      *(uint4*)&Bl[pl][kc + 24] = make_uint4(lpk[12], lpk[13], lpk[14], lpk[15]);
    }
    __syncthreads();
    mfma_tile2x4(Ah, Al, Bh, Bl, acc, wm, wn, lane);
  }
#pragma unroll
  for (int mt = 0; mt < 2; ++mt)
#pragma unroll
    for (int r = 0; r < 4; ++r) {
      int oc = oc0 + wm + mt * 16 + quad * 4 + r;
      float sc = g[oc] * rsqrtf(vv[oc] + EPS_);
      float off = bb[oc] - m[oc] * sc;
#pragma unroll
      for (int nt = 0; nt < 4; ++nt) {
        int pix = pos0 + wn + nt * 16 + l16;
        float val = fminf(fmaxf(acc[mt][nt][r] * sc + off, 0.f), 6.f);
        out[(size_t)(b * 256 + oc) * 4096 + pix] = val;
      }
    }
}

// ---------------------------------------------------------------------------
extern "C" void kernel_launch(void* const* d_in, const int* in_sizes, int n_in,
                              void* d_out, int out_size, void* d_ws, size_t ws_size,
                              hipStream_t stream) {
  (void)in_sizes; (void)n_in; (void)out_size; (void)ws_size;
  const float* x       = (const float*)d_in[0];
  const float* w_down  = (const float*)d_in[1];
  const float* b_down  = (const float*)d_in[2];
  const float* w_qkv_c = (const float*)d_in[3];
  const float* b_qkv_c = (const float*)d_in[4];
  const float* w_up    = (const float*)d_in[5];
  const float* b_up    = (const float*)d_in[6];
  const float* w_qkv_f = (const float*)d_in[7];
  const float* b_qkv_f = (const float*)d_in[8];
  const float* w_dw    = (const float*)d_in[9];
  const float* bn_dw_g = (const float*)d_in[10];
  const float* bn_dw_b = (const float*)d_in[11];
  const float* bn_dw_m = (const float*)d_in[12];
  const float* bn_dw_v = (const float*)d_in[13];
  const float* w_pw    = (const float*)d_in[14];
  const float* bn_pw_g = (const float*)d_in[15];
  const float* bn_pw_b = (const float*)d_in[16];
  const float* bn_pw_m = (const float*)d_in[17];
  const float* bn_pw_v = (const float*)d_in[18];

  float* ws = (float*)d_ws;  // offsets in 4-byte units (round 6 layout)
  unsigned*       xphl   = (unsigned*)ws;                   // 9,191,424 u
  unsigned*       ydhl   = (unsigned*)ws;                   // alias (xphl dead by then)
  unsigned short* qh     = (unsigned short*)(ws + 33554432);
  unsigned short* ql     = (unsigned short*)(ws + 34603008);
  unsigned short* kh     = (unsigned short*)(ws + 35651584);
  unsigned short* kl     = (unsigned short*)(ws + 36700160);
  unsigned short* vth    = (unsigned short*)(ws + 37748736);
  unsigned short* vtl    = (unsigned short*)(ws + 38797312);
  unsigned*       xdhl   = (unsigned*)(ws + 39845888);      // 2,097,152 u
  unsigned*       outcphl= (unsigned*)(ws + 41943040);      // 2,367,488 u
  float*          coarse = ws + 44310528;                   // 8,388,608 f
  float*          outf   = ws + 52699136;                   // 2,097,152 f
  float*          score  = ws + 54796288;                   // 32,768 f
  unsigned short* wdh    = (unsigned short*)(ws + 54829056);
  unsigned short* wdl    = (unsigned short*)(ws + 55353344);
  unsigned short* wt_hi  = (unsigned short*)(ws + 55877632);
  unsigned short* wt_lo  = (unsigned short*)(ws + 56401920);
  unsigned short* wpw_hi = (unsigned short*)(ws + 56926208);
  unsigned short* wpw_lo = (unsigned short*)(ws + 56958976);
  unsigned short* wqh_c  = (unsigned short*)(ws + 56991744);
  unsigned short* wql_c  = (unsigned short*)(ws + 56997888);
  unsigned short* wqh_f  = (unsigned short*)(ws + 57004032);
  unsigned short* wql_f  = (unsigned short*)(ws + 57010176);
  int*            idx    = (int*)(ws + 57016320);           // 8,192 int

  hipMemsetAsync(score, 0, 32768 * sizeof(float), stream);
  hipMemsetAsync(outcphl, 0, (size_t)2367488 * sizeof(unsigned), stream);
  k_pad_x<<<2048, 256, 0, stream>>>(x, xphl);
  k_cvt_wdown<<<4096, 256, 0, stream>>>(w_down, wdh, wdl);
  k_cvt_wqkv<<<48, 256, 0, stream>>>(w_qkv_c, wqh_c, wql_c);
  k_cvt_wqkv<<<48, 256, 0, stream>>>(w_qkv_f, wqh_f, wql_f);
  k_cvt_wup<<<4096, 256, 0, stream>>>(w_up, wt_hi, wt_lo);
  k_cvt_wpw<<<256, 256, 0, stream>>>(w_pw, wpw_hi, wpw_lo);

  k_conv_down_mfma<<<dim3(128, 4), 256, 0, stream>>>(xphl, wdh, wdl, b_down, xdhl);
  k_qkv_mfma<0><<<dim3(16, 32), 256, 0, stream>>>(xdhl, nullptr, wqh_c, wql_c, b_qkv_c,
                                                  nullptr, qh, ql, kh, kl, vth, vtl);
  k_attn<1><<<dim3(16, 32), 256, 0, stream>>>(qh, ql, kh, kl, vth, vtl, score,
                                              outcphl, nullptr);
  k_topk<<<32, 256, 0, stream>>>(score, idx);
  k_convT_mfma<<<dim3(64, 4, 4), 256, 0, stream>>>(outcphl, wt_hi, wt_lo, b_up, coarse);

  k_qkv_mfma<1><<<dim3(16, 32), 256, 0, stream>>>(nullptr, coarse, wqh_f, wql_f, b_qkv_f,
                                                  idx, qh, ql, kh, kl, vth, vtl);
  k_attn<0><<<dim3(16, 32), 256, 0, stream>>>(qh, ql, kh, kl, vth, vtl, nullptr,
                                              nullptr, outf);
  k_scatter<<<8192, 256, 0, stream>>>(outf, idx, coarse);
  k_dwconv<<<32768, 256, 0, stream>>>(coarse, w_dw, bn_dw_g, bn_dw_b, bn_dw_m, bn_dw_v, ydhl);
  k_pw_mfma<<<dim3(256, 4), 256, 0, stream>>>(ydhl, wpw_hi, wpw_lo, bn_pw_g, bn_pw_b,
                                              bn_pw_m, bn_pw_v, (float*)d_out);
}

// Round 9
// 611.670 us; speedup vs baseline: 2.6705x; 1.0086x over previous
//
#include <hip/hip_runtime.h>
#include <cstdint>
#include <cstddef>

// ---------------------------------------------------------------------------
// RegionSelectionAttention. Round 9: coarse attention kept bit-identical
// (score path) but with dedicated V buffer (pass-2 barriers 4->3); fine
// attention rewritten as single-pass online flash (value path only).
// ---------------------------------------------------------------------------

#define EPS_ 1e-5f

typedef short bf16x8_t __attribute__((ext_vector_type(8)));
typedef float f32x4_t __attribute__((ext_vector_type(4)));
#define MFMA16(a, b, c) __builtin_amdgcn_mfma_f32_16x16x32_bf16(a, b, c, 0, 0, 0)

__device__ __forceinline__ void cvt1(float f, unsigned short& h, unsigned short& l) {
  unsigned u = __float_as_uint(f);
  unsigned r = u + 0x7FFFu + ((u >> 16) & 1u);
  h = (unsigned short)(r >> 16);
  float lo = f - __uint_as_float(r & 0xFFFF0000u);
  l = (unsigned short)(__float_as_uint(lo) >> 16);
}
__device__ __forceinline__ unsigned cvtpack(float f) {
  unsigned short h, l;
  cvt1(f, h, l);
  return (unsigned)h | ((unsigned)l << 16);
}
__device__ __forceinline__ void cvt2(float f0, float f1, unsigned& hpack, unsigned& lpack) {
  unsigned u0 = __float_as_uint(f0), u1 = __float_as_uint(f1);
  unsigned r0 = u0 + 0x7FFFu + ((u0 >> 16) & 1u);
  unsigned r1 = u1 + 0x7FFFu + ((u1 >> 16) & 1u);
  hpack = (r0 >> 16) | (r1 & 0xFFFF0000u);
  float l0 = f0 - __uint_as_float(r0 & 0xFFFF0000u);
  float l1 = f1 - __uint_as_float(r1 & 0xFFFF0000u);
  lpack = (__float_as_uint(l0) >> 16) | (__float_as_uint(l1) & 0xFFFF0000u);
}
__device__ __forceinline__ unsigned pk_h(unsigned a, unsigned b) {
  return (a & 0xFFFFu) | (b << 16);
}
__device__ __forceinline__ unsigned pk_l(unsigned a, unsigned b) {
  return (a >> 16) | (b & 0xFFFF0000u);
}

// ---------------- pad x -> packed xphl[plane][66 rows x stride 68] ---------
__global__ __launch_bounds__(256) void k_pad_x(
    const float* __restrict__ x, unsigned* __restrict__ xphl) {
  const int plane = blockIdx.x;  // 2048
  const float* src = x + (size_t)plane * 4096;
  unsigned* dst = xphl + (size_t)plane * 4488;
  for (int e = threadIdx.x; e < 4356; e += 256) {
    int r = e / 66, cc = e - r * 66;
    float v = 0.f;
    if (r >= 1 && r <= 64 && cc >= 1 && cc <= 64) v = src[(r - 1) * 64 + (cc - 1)];
    dst[r * 68 + cc] = cvtpack(v);
  }
}

// ---------------- weight conversions ---------------------------------------
__global__ __launch_bounds__(256) void k_cvt_wdown(
    const float* __restrict__ w, unsigned short* __restrict__ wh,
    unsigned short* __restrict__ wl) {
  int e = blockIdx.x * 256 + threadIdx.x;  // 1,048,576: [oc][4096]
  cvt1(w[e], wh[e], wl[e]);
}

__global__ __launch_bounds__(256) void k_cvt_wqkv(
    const float* __restrict__ wq, unsigned short* __restrict__ wh,
    unsigned short* __restrict__ wl) {
  int e = blockIdx.x * 256 + threadIdx.x;  // 12288: [col][d]
  int col = e >> 6, d = e & 63;
  float f = wq[d * 192 + col];
  if (col < 64) f *= 0.125f;  // fold attn scale into q (pow2: exact)
  cvt1(f, wh[e], wl[e]);
}

__global__ __launch_bounds__(256) void k_cvt_wup(
    const float* __restrict__ w_up, unsigned short* __restrict__ wth,
    unsigned short* __restrict__ wtl) {
  int e = blockIdx.x * 256 + threadIdx.x;  // 2^20: [class][oc][kp=tap*256+ic]
  int kp = e & 1023, oc = (e >> 10) & 255, c = e >> 18;
  int tap = kp >> 8, ic = kp & 255;
  int tk = tap >> 1, txi = tap & 1;
  int ry = c >> 1, rx = c & 1;
  int ky = (1 - ry) + 2 * tk, kx = (1 - rx) + 2 * txi;
  cvt1(w_up[((size_t)(ic * 256 + oc) * 4 + ky) * 4 + kx], wth[e], wtl[e]);
}

__global__ __launch_bounds__(256) void k_cvt_wpw(
    const float* __restrict__ w, unsigned short* __restrict__ wh,
    unsigned short* __restrict__ wl) {
  int e = blockIdx.x * 256 + threadIdx.x;  // 65536 [oc][ic]
  cvt1(w[e], wh[e], wl[e]);
}

// ====================== MFMA cores =========================================
__device__ __forceinline__ void mfma_chunk(
    const unsigned short (*Ah)[72], const unsigned short (*Al)[72],
    const unsigned short (*Bh)[72], const unsigned short (*Bl)[72],
    f32x4_t (&acc)[4], int wm, int lane) {
  const int l16 = lane & 15, quad = lane >> 4;
#pragma unroll
  for (int ks = 0; ks < 2; ++ks) {
    int ko = ks * 32 + quad * 8;
    bf16x8_t ah = *(const bf16x8_t*)&Ah[wm + l16][ko];
    bf16x8_t al = *(const bf16x8_t*)&Al[wm + l16][ko];
#pragma unroll
    for (int nt = 0; nt < 4; ++nt) {
      bf16x8_t bh = *(const bf16x8_t*)&Bh[nt * 16 + l16][ko];
      bf16x8_t bl = *(const bf16x8_t*)&Bl[nt * 16 + l16][ko];
      acc[nt] = MFMA16(ah, bh, acc[nt]);
      acc[nt] = MFMA16(ah, bl, acc[nt]);
      acc[nt] = MFMA16(al, bh, acc[nt]);
    }
  }
}

__device__ __forceinline__ void mfma_tile2x2(
    const unsigned short (*Ah)[72], const unsigned short (*Al)[72],
    const unsigned short (*Bh)[72], const unsigned short (*Bl)[72],
    f32x4_t (&acc)[2][2], int wm, int wn, int lane) {
  const int l16 = lane & 15, quad = lane >> 4;
#pragma unroll
  for (int ks = 0; ks < 2; ++ks) {
    int ko = ks * 32 + quad * 8;
    bf16x8_t ah[2], al[2];
#pragma unroll
    for (int mt = 0; mt < 2; ++mt) {
      ah[mt] = *(const bf16x8_t*)&Ah[wm + mt * 16 + l16][ko];
      al[mt] = *(const bf16x8_t*)&Al[wm + mt * 16 + l16][ko];
    }
#pragma unroll
    for (int nt = 0; nt < 2; ++nt) {
      bf16x8_t bh = *(const bf16x8_t*)&Bh[wn + nt * 16 + l16][ko];
      bf16x8_t bl = *(const bf16x8_t*)&Bl[wn + nt * 16 + l16][ko];
#pragma unroll
      for (int mt = 0; mt < 2; ++mt) {
        acc[mt][nt] = MFMA16(ah[mt], bh, acc[mt][nt]);
        acc[mt][nt] = MFMA16(ah[mt], bl, acc[mt][nt]);
        acc[mt][nt] = MFMA16(al[mt], bh, acc[mt][nt]);
      }
    }
  }
}

__device__ __forceinline__ void mfma_tile2x4(
    const unsigned short (*Ah)[72], const unsigned short (*Al)[72],
    const unsigned short (*Bh)[72], const unsigned short (*Bl)[72],
    f32x4_t (&acc)[2][4], int wm, int wn, int lane) {
  const int l16 = lane & 15, quad = lane >> 4;
#pragma unroll
  for (int ks = 0; ks < 2; ++ks) {
    int ko = ks * 32 + quad * 8;
    bf16x8_t ah[2], al[2];
#pragma unroll
    for (int mt = 0; mt < 2; ++mt) {
      ah[mt] = *(const bf16x8_t*)&Ah[wm + mt * 16 + l16][ko];
      al[mt] = *(const bf16x8_t*)&Al[wm + mt * 16 + l16][ko];
    }
#pragma unroll
    for (int nt = 0; nt < 4; ++nt) {
      bf16x8_t bh = *(const bf16x8_t*)&Bh[wn + nt * 16 + l16][ko];
      bf16x8_t bl = *(const bf16x8_t*)&Bl[wn + nt * 16 + l16][ko];
#pragma unroll
      for (int mt = 0; mt < 2; ++mt) {
        acc[mt][nt] = MFMA16(ah[mt], bh, acc[mt][nt]);
        acc[mt][nt] = MFMA16(ah[mt], bl, acc[mt][nt]);
        acc[mt][nt] = MFMA16(al[mt], bh, acc[mt][nt]);
      }
    }
  }
}

// ---------------- conv down k4 s2 p1, 64oc x 64pix, 2x2 waves, K=4096 ------
__global__ __launch_bounds__(256) void k_conv_down_mfma(
    const unsigned* __restrict__ xphl, const unsigned short* __restrict__ wdh,
    const unsigned short* __restrict__ wdl, const float* __restrict__ bias,
    unsigned* __restrict__ xdhl) {
  __shared__ unsigned short Ah[64][72], Al[64][72], Bh[64][72], Bl[64][72];
  const int t = threadIdx.x;
  const int pix0 = blockIdx.x * 64, oc0 = blockIdx.y * 64;
  const int bimg = pix0 >> 10, pos = pix0 & 1023;
  const int pl = t & 63, icg = t >> 6;
  const int rem = (pix0 + pl) & 1023;
  const int oy = rem >> 5, ox = rem & 31;
  const unsigned* xb = xphl + ((size_t)bimg * 256 + icg) * 4488 + (oy * 2) * 68 + ox * 2;
  const int wave = t >> 6, lane = t & 63, l16 = lane & 15, quad = lane >> 4;
  const int wm = (wave & 1) * 32, wn = (wave >> 1) * 32;
  const int ar = t >> 2, ac = (t & 3) * 16;
  const unsigned short* wra = wdh + (size_t)(oc0 + ar) * 4096 + ac;
  const unsigned short* wrl = wdl + (size_t)(oc0 + ar) * 4096 + ac;
  f32x4_t acc[2][2] = {};
  for (int kb = 0; kb < 4096; kb += 64) {
    bf16x8_t a0 = *(const bf16x8_t*)(wra + kb);
    bf16x8_t a1 = *(const bf16x8_t*)(wra + kb + 8);
    bf16x8_t a2 = *(const bf16x8_t*)(wrl + kb);
    bf16x8_t a3 = *(const bf16x8_t*)(wrl + kb + 8);
    unsigned u[16];
#pragma unroll
    for (int r = 0; r < 4; ++r) {
      uint2 u01 = *(const uint2*)(xb + r * 68);
      uint2 u23 = *(const uint2*)(xb + r * 68 + 2);
      u[4 * r + 0] = u01.x; u[4 * r + 1] = u01.y;
      u[4 * r + 2] = u23.x; u[4 * r + 3] = u23.y;
    }
    unsigned hp[8], lp[8];
#pragma unroll
    for (int j = 0; j < 8; ++j) {
      hp[j] = pk_h(u[2 * j], u[2 * j + 1]);
      lp[j] = pk_l(u[2 * j], u[2 * j + 1]);
    }
    __syncthreads();
    *(bf16x8_t*)&Ah[ar][ac] = a0;
    *(bf16x8_t*)&Ah[ar][ac + 8] = a1;
    *(bf16x8_t*)&Al[ar][ac] = a2;
    *(bf16x8_t*)&Al[ar][ac + 8] = a3;
    *(uint4*)&Bh[pl][icg * 16] = make_uint4(hp[0], hp[1], hp[2], hp[3]);
    *(uint4*)&Bh[pl][icg * 16 + 8] = make_uint4(hp[4], hp[5], hp[6], hp[7]);
    *(uint4*)&Bl[pl][icg * 16] = make_uint4(lp[0], lp[1], lp[2], lp[3]);
    *(uint4*)&Bl[pl][icg * 16 + 8] = make_uint4(lp[4], lp[5], lp[6], lp[7]);
    __syncthreads();
    mfma_tile2x2(Ah, Al, Bh, Bl, acc, wm, wn, lane);
    xb += 4 * 4488;
  }
#pragma unroll
  for (int mt = 0; mt < 2; ++mt)
#pragma unroll
    for (int r = 0; r < 4; ++r) {
      int oc = oc0 + wm + mt * 16 + quad * 4 + r;
      float bv = bias[oc];
#pragma unroll
      for (int nt = 0; nt < 2; ++nt)
        xdhl[((size_t)(bimg * 256 + oc)) * 1024 + pos + wn + nt * 16 + l16] =
            cvtpack(acc[mt][nt][r] + bv);
    }
}

// ---------------- qkv projection -------------------------------------------
template <int MODE>
__global__ __launch_bounds__(256) void k_qkv_mfma(
    const unsigned* __restrict__ srcp, const float* __restrict__ srcf,
    const unsigned short* __restrict__ wh, const unsigned short* __restrict__ wl,
    const float* __restrict__ bq, const int* __restrict__ topk,
    unsigned short* __restrict__ qh, unsigned short* __restrict__ ql,
    unsigned short* __restrict__ kh, unsigned short* __restrict__ kl,
    unsigned short* __restrict__ vth, unsigned short* __restrict__ vtl) {
  __shared__ unsigned short Ah[64][72], Al[64][72];
  const int t = threadIdx.x;
  const int tok0 = blockIdx.x * 64;
  const int pair = blockIdx.y;
  const int b = pair >> 2, h = pair & 3;
  const int tokl = t & 63, dg = t >> 6;
  unsigned hp[8], lp[8];
  if (MODE == 0) {
    const unsigned* base = srcp + ((size_t)(b * 256 + h * 64 + dg * 16)) * 1024 + tok0 + tokl;
    unsigned u[16];
#pragma unroll
    for (int j = 0; j < 16; ++j) u[j] = base[(size_t)j * 1024];
#pragma unroll
    for (int j = 0; j < 8; ++j) {
      hp[j] = pk_h(u[2 * j], u[2 * j + 1]);
      lp[j] = pk_l(u[2 * j], u[2 * j + 1]);
    }
  } else {
    int tok = tok0 + tokl;
    int pp = topk[pair * 256 + (tok >> 2)];
    int py = (tok >> 1) & 1, px = tok & 1;
    int ry = (pp >> 5) * 2 + py, rx = (pp & 31) * 2 + px;
    const float* base = srcf + ((size_t)(b * 256 + h * 64 + dg * 16)) * 4096 + ry * 64 + rx;
    float fv[16];
#pragma unroll
    for (int j = 0; j < 16; ++j) fv[j] = base[(size_t)j * 4096];
#pragma unroll
    for (int j = 0; j < 8; ++j) cvt2(fv[2 * j], fv[2 * j + 1], hp[j], lp[j]);
  }
  *(uint4*)&Ah[tokl][dg * 16] = make_uint4(hp[0], hp[1], hp[2], hp[3]);
  *(uint4*)&Ah[tokl][dg * 16 + 8] = make_uint4(hp[4], hp[5], hp[6], hp[7]);
  *(uint4*)&Al[tokl][dg * 16] = make_uint4(lp[0], lp[1], lp[2], lp[3]);
  *(uint4*)&Al[tokl][dg * 16 + 8] = make_uint4(lp[4], lp[5], lp[6], lp[7]);
  __syncthreads();
  const int wave = t >> 6, lane = t & 63, l16 = lane & 15, quad = lane >> 4;
  f32x4_t acc[4][3] = {};
#pragma unroll
  for (int ks = 0; ks < 2; ++ks) {
    int ko = ks * 32 + quad * 8;
    bf16x8_t bh0[3], bl0[3];
#pragma unroll
    for (int nt = 0; nt < 3; ++nt) {
      int col = wave * 48 + nt * 16 + l16;
      bh0[nt] = *(const bf16x8_t*)(wh + col * 64 + ko);
      bl0[nt] = *(const bf16x8_t*)(wl + col * 64 + ko);
    }
#pragma unroll
    for (int mt = 0; mt < 4; ++mt) {
      bf16x8_t ah = *(const bf16x8_t*)&Ah[mt * 16 + l16][ko];
      bf16x8_t al = *(const bf16x8_t*)&Al[mt * 16 + l16][ko];
#pragma unroll
      for (int nt = 0; nt < 3; ++nt) {
        acc[mt][nt] = MFMA16(ah, bh0[nt], acc[mt][nt]);
        acc[mt][nt] = MFMA16(ah, bl0[nt], acc[mt][nt]);
        acc[mt][nt] = MFMA16(al, bh0[nt], acc[mt][nt]);
      }
    }
  }
#pragma unroll
  for (int nt = 0; nt < 3; ++nt) {
    int col = wave * 48 + nt * 16 + l16;
    float bqv = bq[col];
    if (col < 64) bqv *= 0.125f;
#pragma unroll
    for (int mt = 0; mt < 4; ++mt) {
#pragma unroll
      for (int r = 0; r < 4; ++r) {
        int tok = tok0 + mt * 16 + quad * 4 + r;
        float val = acc[mt][nt][r] + bqv;
        unsigned short hh, ll;
        cvt1(val, hh, ll);
        if (col < 64) {
          size_t o = ((size_t)pair * 1024 + tok) * 64 + col;
          qh[o] = hh; ql[o] = ll;
        } else if (col < 128) {
          size_t o = ((size_t)pair * 1024 + tok) * 64 + (col - 64);
          kh[o] = hh; kl[o] = ll;
        } else {
          size_t o = ((size_t)pair * 64 + (col - 128)) * 1024 + tok;
          vth[o] = hh; vtl[o] = ll;
        }
      }
    }
  }
}

// ---------------- coarse fused attention (score path, bit-identical) -------
__global__ __launch_bounds__(256) void k_attn_coarse(
    const unsigned short* __restrict__ qh, const unsigned short* __restrict__ ql,
    const unsigned short* __restrict__ kh, const unsigned short* __restrict__ kl,
    const unsigned short* __restrict__ vth, const unsigned short* __restrict__ vtl,
    float* __restrict__ score, unsigned* __restrict__ outc) {
  __shared__ __align__(16) unsigned short Qb[2][64][72];
  __shared__ __align__(16) unsigned short Kb[2][64][72];
  __shared__ __align__(16) unsigned short Vb[2][64][72];
  __shared__ __align__(16) unsigned short Pb[2][64][72];
  __shared__ float mlW[4][2][64];
  __shared__ float mC[64], lC[64];
  __shared__ float colsum[1024];
  const int t = threadIdx.x;
  const int q0 = blockIdx.x * 64;
  const int pair = blockIdx.y;
  const int wave = t >> 6, lane = t & 63;
  const int l16 = lane & 15, quad = lane >> 4;
  const int wm = wave * 16;
  const int sr = t >> 3, skc = (t & 7) * 8;

  const size_t qbase = ((size_t)pair * 1024 + q0) * 64;
#pragma unroll
  for (int i = 0; i < 2; ++i) {
    int r = sr + i * 32;
    *(bf16x8_t*)&Qb[0][r][skc] = *(const bf16x8_t*)(qh + qbase + (size_t)r * 64 + skc);
    *(bf16x8_t*)&Qb[1][r][skc] = *(const bf16x8_t*)(ql + qbase + (size_t)r * 64 + skc);
  }
#pragma unroll
  for (int i = 0; i < 4; ++i) colsum[t + i * 256] = 0.f;

  const size_t kmbase = (size_t)pair * 1024 * 64;
  const size_t vbase = (size_t)pair * 64 * 1024;

  // ---- pass 1: online (m,l), numerics identical to round 8 ----
  float mrun[4] = {-1e30f, -1e30f, -1e30f, -1e30f};
  float lrun[4] = {0.f, 0.f, 0.f, 0.f};
  for (int kb = 0; kb < 1024; kb += 64) {
    __syncthreads();
#pragma unroll
    for (int i = 0; i < 2; ++i) {
      int r = sr + i * 32;
      *(bf16x8_t*)&Kb[0][r][skc] = *(const bf16x8_t*)(kh + kmbase + (size_t)(kb + r) * 64 + skc);
      *(bf16x8_t*)&Kb[1][r][skc] = *(const bf16x8_t*)(kl + kmbase + (size_t)(kb + r) * 64 + skc);
    }
    __syncthreads();
    f32x4_t acc[4] = {};
    mfma_chunk(Kb[0], Kb[1], Qb[0], Qb[1], acc, wm, lane);
#pragma unroll
    for (int nt = 0; nt < 4; ++nt) {
      float m0 = fmaxf(fmaxf(acc[nt][0], acc[nt][1]), fmaxf(acc[nt][2], acc[nt][3]));
      m0 = fmaxf(m0, __shfl_xor(m0, 16));
      m0 = fmaxf(m0, __shfl_xor(m0, 32));
      float mn = fmaxf(mrun[nt], m0);
      float s0 = __expf(acc[nt][0] - mn) + __expf(acc[nt][1] - mn) +
                 __expf(acc[nt][2] - mn) + __expf(acc[nt][3] - mn);
      s0 += __shfl_xor(s0, 16);
      s0 += __shfl_xor(s0, 32);
      lrun[nt] = lrun[nt] * __expf(mrun[nt] - mn) + s0;
      mrun[nt] = mn;
    }
  }
  __syncthreads();
  if (quad == 0) {
#pragma unroll
    for (int nt = 0; nt < 4; ++nt) {
      mlW[wave][0][nt * 16 + l16] = mrun[nt];
      mlW[wave][1][nt * 16 + l16] = lrun[nt];
    }
  }
  __syncthreads();
  if (t < 64) {
    float m0 = mlW[0][0][t], m1 = mlW[1][0][t], m2 = mlW[2][0][t], m3 = mlW[3][0][t];
    float mm = fmaxf(fmaxf(m0, m1), fmaxf(m2, m3));
    float ll = mlW[0][1][t] * __expf(m0 - mm) + mlW[1][1][t] * __expf(m1 - mm) +
               mlW[2][1][t] * __expf(m2 - mm) + mlW[3][1][t] * __expf(m3 - mm);
    mC[t] = mm;
    lC[t] = 1.0f / ll;
  }
  __syncthreads();
  float mq[4], il[4];
#pragma unroll
  for (int nt = 0; nt < 4; ++nt) {
    mq[nt] = mC[nt * 16 + l16];
    il[nt] = lC[nt * 16 + l16];
  }

  // ---- pass 2: recompute, final P, colsum, PV. 3 barriers/chunk ----
  f32x4_t accO[4] = {};
  for (int kb = 0; kb < 1024; kb += 64) {
    __syncthreads();  // prev PV done reading Pb/Vb
#pragma unroll
    for (int i = 0; i < 2; ++i) {
      int r = sr + i * 32;
      *(bf16x8_t*)&Kb[0][r][skc] = *(const bf16x8_t*)(kh + kmbase + (size_t)(kb + r) * 64 + skc);
      *(bf16x8_t*)&Kb[1][r][skc] = *(const bf16x8_t*)(kl + kmbase + (size_t)(kb + r) * 64 + skc);
      *(bf16x8_t*)&Vb[0][r][skc] = *(const bf16x8_t*)(vth + vbase + (size_t)r * 1024 + kb + skc);
      *(bf16x8_t*)&Vb[1][r][skc] = *(const bf16x8_t*)(vtl + vbase + (size_t)r * 1024 + kb + skc);
    }
    __syncthreads();
    f32x4_t acc[4] = {};
    mfma_chunk(Kb[0], Kb[1], Qb[0], Qb[1], acc, wm, lane);
    float P[4][4];
#pragma unroll
    for (int nt = 0; nt < 4; ++nt)
#pragma unroll
      for (int r = 0; r < 4; ++r) P[nt][r] = __expf(acc[nt][r] - mq[nt]) * il[nt];
#pragma unroll
    for (int r = 0; r < 4; ++r) {
      float cs = P[0][r] + P[1][r] + P[2][r] + P[3][r];
      cs += __shfl_xor(cs, 1);
      cs += __shfl_xor(cs, 2);
      cs += __shfl_xor(cs, 4);
      cs += __shfl_xor(cs, 8);
      if (l16 == 0) colsum[kb + wm + quad * 4 + r] += cs;
    }
#pragma unroll
    for (int nt = 0; nt < 4; ++nt) {
      unsigned h01, l01, h23, l23;
      cvt2(P[nt][0], P[nt][1], h01, l01);
      cvt2(P[nt][2], P[nt][3], h23, l23);
      *(uint2*)&Pb[0][nt * 16 + l16][wm + quad * 4] = make_uint2(h01, h23);
      *(uint2*)&Pb[1][nt * 16 + l16][wm + quad * 4] = make_uint2(l01, l23);
    }
    __syncthreads();  // Pb visible
    mfma_chunk(Pb[0], Pb[1], Vb[0], Vb[1], accO, wm, lane);
  }
  __syncthreads();

#pragma unroll
  for (int i = 0; i < 4; ++i)
    atomicAdd(&score[pair * 1024 + t + i * 256], colsum[t + i * 256]);
  float (*Tr)[68] = reinterpret_cast<float(*)[68]>(&Pb[0][0][0]);
#pragma unroll
  for (int nt = 0; nt < 4; ++nt)
#pragma unroll
    for (int r = 0; r < 4; ++r)
      Tr[nt * 16 + l16][wm + quad * 4 + r] = accO[nt][r];
  __syncthreads();
  const int b = pair >> 2, h = pair & 3;
#pragma unroll
  for (int i = 0; i < 16; ++i) {
    int e = t + i * 256;
    int d = e >> 6, ql_ = e & 63;
    int pix = q0 + ql_;
    int iy = (pix >> 5) + 1, ix = (pix & 31) + 1;
    outc[((size_t)(b * 256 + h * 64 + d)) * 1156 + iy * 34 + ix] = cvtpack(Tr[d][ql_]);
  }
}

// ---------------- fine fused attention: single-pass online flash -----------
// Value path only (no colsum, no top-k downstream) -> online O rescaling ok.
__global__ __launch_bounds__(256) void k_attn_fine(
    const unsigned short* __restrict__ qh, const unsigned short* __restrict__ ql,
    const unsigned short* __restrict__ kh, const unsigned short* __restrict__ kl,
    const unsigned short* __restrict__ vth, const unsigned short* __restrict__ vtl,
    float* __restrict__ outf) {
  __shared__ __align__(16) unsigned short Qb[2][64][72];
  __shared__ __align__(16) unsigned short Kb[2][64][72];
  __shared__ __align__(16) unsigned short Vb[2][64][72];
  __shared__ __align__(16) unsigned short Pb[2][64][72];
  __shared__ float m_run[64], l_run[64], alphaS[64];
  __shared__ float mWc[4][64], sWc[4][64];
  const int t = threadIdx.x;
  const int q0 = blockIdx.x * 64;
  const int pair = blockIdx.y;
  const int wave = t >> 6, lane = t & 63;
  const int l16 = lane & 15, quad = lane >> 4;
  const int wm = wave * 16;
  const int sr = t >> 3, skc = (t & 7) * 8;

  const size_t qbase = ((size_t)pair * 1024 + q0) * 64;
#pragma unroll
  for (int i = 0; i < 2; ++i) {
    int r = sr + i * 32;
    *(bf16x8_t*)&Qb[0][r][skc] = *(const bf16x8_t*)(qh + qbase + (size_t)r * 64 + skc);
    *(bf16x8_t*)&Qb[1][r][skc] = *(const bf16x8_t*)(ql + qbase + (size_t)r * 64 + skc);
  }
  if (t < 64) { m_run[t] = -1e30f; l_run[t] = 0.f; }

  const size_t kmbase = (size_t)pair * 1024 * 64;
  const size_t vbase = (size_t)pair * 64 * 1024;

  f32x4_t accO[4] = {};
  for (int kb = 0; kb < 1024; kb += 64) {
    __syncthreads();  // prev PV done reading Pb/Vb; m/l arrays consumed
#pragma unroll
    for (int i = 0; i < 2; ++i) {
      int r = sr + i * 32;
      *(bf16x8_t*)&Kb[0][r][skc] = *(const bf16x8_t*)(kh + kmbase + (size_t)(kb + r) * 64 + skc);
      *(bf16x8_t*)&Kb[1][r][skc] = *(const bf16x8_t*)(kl + kmbase + (size_t)(kb + r) * 64 + skc);
      *(bf16x8_t*)&Vb[0][r][skc] = *(const bf16x8_t*)(vth + vbase + (size_t)r * 1024 + kb + skc);
      *(bf16x8_t*)&Vb[1][r][skc] = *(const bf16x8_t*)(vtl + vbase + (size_t)r * 1024 + kb + skc);
    }
    __syncthreads();
    f32x4_t acc[4] = {};
    mfma_chunk(Kb[0], Kb[1], Qb[0], Qb[1], acc, wm, lane);  // S^T tile
    // per-wave k-max per q
#pragma unroll
    for (int nt = 0; nt < 4; ++nt) {
      float m0 = fmaxf(fmaxf(acc[nt][0], acc[nt][1]), fmaxf(acc[nt][2], acc[nt][3]));
      m0 = fmaxf(m0, __shfl_xor(m0, 16));
      m0 = fmaxf(m0, __shfl_xor(m0, 32));
      if (quad == 0) mWc[wave][nt * 16 + l16] = m0;
    }
    __syncthreads();
    if (t < 64) {
      float mn = fmaxf(fmaxf(fmaxf(mWc[0][t], mWc[1][t]), fmaxf(mWc[2][t], mWc[3][t])),
                       m_run[t]);
      alphaS[t] = __expf(m_run[t] - mn);
      m_run[t] = mn;
    }
    __syncthreads();
    // P = exp(s - m_new); write Pb; per-wave partial l sums; rescale accO
    float P[4][4];
#pragma unroll
    for (int nt = 0; nt < 4; ++nt) {
      float mn = m_run[nt * 16 + l16];
#pragma unroll
      for (int r = 0; r < 4; ++r) P[nt][r] = __expf(acc[nt][r] - mn);
      float s0 = P[nt][0] + P[nt][1] + P[nt][2] + P[nt][3];
      s0 += __shfl_xor(s0, 16);
      s0 += __shfl_xor(s0, 32);
      if (quad == 0) sWc[wave][nt * 16 + l16] = s0;
      unsigned h01, l01, h23, l23;
      cvt2(P[nt][0], P[nt][1], h01, l01);
      cvt2(P[nt][2], P[nt][3], h23, l23);
      *(uint2*)&Pb[0][nt * 16 + l16][wm + quad * 4] = make_uint2(h01, h23);
      *(uint2*)&Pb[1][nt * 16 + l16][wm + quad * 4] = make_uint2(l01, l23);
    }
#pragma unroll
    for (int r = 0; r < 4; ++r) {
      float a = alphaS[wm + quad * 4 + r];
#pragma unroll
      for (int nt = 0; nt < 4; ++nt) accO[nt][r] *= a;
    }
    __syncthreads();  // Pb + sWc visible
    if (t < 64)
      l_run[t] = l_run[t] * alphaS[t] + (sWc[0][t] + sWc[1][t] + sWc[2][t] + sWc[3][t]);
    mfma_chunk(Pb[0], Pb[1], Vb[0], Vb[1], accO, wm, lane);  // O += P~ @ V
  }
  __syncthreads();
#pragma unroll
  for (int r = 0; r < 4; ++r) {
    float invl = 1.0f / l_run[wm + quad * 4 + r];
    int qm = q0 + wm + quad * 4 + r;
#pragma unroll
    for (int nt = 0; nt < 4; ++nt)
      outf[((size_t)pair * 1024 + qm) * 64 + nt * 16 + l16] = accO[nt][r] * invl;
  }
}

// ---------------- per-pair top-256 via bitonic sort ------------------------
__global__ __launch_bounds__(256) void k_topk(
    const float* __restrict__ score, int* __restrict__ idx) {
  __shared__ unsigned long long key[1024];
  const int pair = blockIdx.x;
  const int t = threadIdx.x;
#pragma unroll
  for (int j = 0; j < 4; ++j) {
    int i = t + j * 256;
    unsigned u = __float_as_uint(score[pair * 1024 + i]);
    u = u ^ ((u & 0x80000000u) ? 0xFFFFFFFFu : 0x80000000u);
    u = ~u;
    key[i] = ((unsigned long long)u << 32) | (unsigned)i;
  }
  __syncthreads();
  for (int k = 2; k <= 1024; k <<= 1) {
    for (int j = k >> 1; j > 0; j >>= 1) {
      for (int w = 0; w < 4; ++w) {
        int i = t + w * 256;
        int l = i ^ j;
        if (l > i) {
          bool up = ((i & k) == 0);
          unsigned long long a = key[i], b = key[l];
          if ((a > b) == up) { key[i] = b; key[l] = a; }
        }
      }
      __syncthreads();
    }
  }
  idx[pair * 256 + t] = (int)(key[t] & 0xFFFFFFFFu);
}

// ---------------- convT: 64oc x 128pix tile, 4 classes ---------------------
__global__ __launch_bounds__(256) void k_convT_mfma(
    const unsigned* __restrict__ inp, const unsigned short* __restrict__ wth,
    const unsigned short* __restrict__ wtl, const float* __restrict__ bias,
    float* __restrict__ out) {
  __shared__ unsigned short Ah[64][72], Al[64][72];
  __shared__ unsigned short Bh[128][72], Bl[128][72];
  const int t = threadIdx.x;
  const int pix0 = blockIdx.x * 128;
  const int oc0 = blockIdx.y * 64;
  const int cls = blockIdx.z;
  const int ry = cls >> 1, rx = cls & 1;
  const int b = pix0 >> 10;
  const int wave = t >> 6, lane = t & 63;
  const int l16 = lane & 15, quad = lane >> 4;
  const int wm = (wave & 1) * 32, wn = (wave >> 1) * 64;
  const int pl = t & 127, icg = t >> 7;
  const int remg = (pix0 + pl) & 1023;
  const int tyy = remg >> 5, txx = remg & 31;
  const int ar = t >> 2, ac = (t & 3) * 16;
  const size_t wbase = ((size_t)cls * 256 + oc0 + ar) * 1024 + ac;
  f32x4_t acc[2][4] = {};
  for (int kb = 0; kb < 1024; kb += 64) {
    const int tap = kb >> 8, ic0 = kb & 255;
    const int tk = tap >> 1, txi = tap & 1;
    const int iy = tyy + ry + 1 - tk, ix = txx + rx + 1 - txi;
    const unsigned* p = inp + (size_t)(b * 256 + ic0 + icg * 32) * 1156 + iy * 34 + ix;
    unsigned u[32];
#pragma unroll
    for (int j = 0; j < 32; ++j) u[j] = p[(size_t)j * 1156];
    unsigned hp[16], lpk[16];
#pragma unroll
    for (int j = 0; j < 16; ++j) {
      hp[j] = pk_h(u[2 * j], u[2 * j + 1]);
      lpk[j] = pk_l(u[2 * j], u[2 * j + 1]);
    }
    bf16x8_t a0 = *(const bf16x8_t*)(wth + wbase + kb);
    bf16x8_t a1 = *(const bf16x8_t*)(wth + wbase + kb + 8);
    bf16x8_t a2 = *(const bf16x8_t*)(wtl + wbase + kb);
    bf16x8_t a3 = *(const bf16x8_t*)(wtl + wbase + kb + 8);
    __syncthreads();
    *(bf16x8_t*)&Ah[ar][ac] = a0;
    *(bf16x8_t*)&Ah[ar][ac + 8] = a1;
    *(bf16x8_t*)&Al[ar][ac] = a2;
    *(bf16x8_t*)&Al[ar][ac + 8] = a3;
    {
      int kc = icg * 32;
      *(uint4*)&Bh[pl][kc] = make_uint4(hp[0], hp[1], hp[2], hp[3]);
      *(uint4*)&Bh[pl][kc + 8] = make_uint4(hp[4], hp[5], hp[6], hp[7]);
      *(uint4*)&Bh[pl][kc + 16] = make_uint4(hp[8], hp[9], hp[10], hp[11]);
      *(uint4*)&Bh[pl][kc + 24] = make_uint4(hp[12], hp[13], hp[14], hp[15]);
      *(uint4*)&Bl[pl][kc] = make_uint4(lpk[0], lpk[1], lpk[2], lpk[3]);
      *(uint4*)&Bl[pl][kc + 8] = make_uint4(lpk[4], lpk[5], lpk[6], lpk[7]);
      *(uint4*)&Bl[pl][kc + 16] = make_uint4(lpk[8], lpk[9], lpk[10], lpk[11]);
      *(uint4*)&Bl[pl][kc + 24] = make_uint4(lpk[12], lpk[13], lpk[14], lpk[15]);
    }
    __syncthreads();
    mfma_tile2x4(Ah, Al, Bh, Bl, acc, wm, wn, lane);
  }
#pragma unroll
  for (int mt = 0; mt < 2; ++mt)
#pragma unroll
    for (int r = 0; r < 4; ++r) {
      int oc = oc0 + wm + mt * 16 + quad * 4 + r;
      float bvs = bias[oc];
#pragma unroll
      for (int nt = 0; nt < 4; ++nt) {
        int pix = pix0 + wn + nt * 16 + l16;
        int rem2 = pix & 1023;
        int y = (rem2 >> 5) * 2 + ry, xx = (rem2 & 31) * 2 + rx;
        out[((size_t)(b * 256 + oc) * 64 + y) * 64 + xx] = acc[mt][nt][r] + bvs;
      }
    }
}

// ---------------- scatter fine outputs into y ------------------------------
__global__ __launch_bounds__(256) void k_scatter(
    const float* __restrict__ outf, const int* __restrict__ idx,
    float* __restrict__ y) {
  int g = blockIdx.x * 256 + threadIdx.x;
  int pair = g >> 16;
  int rem = g & 65535;
  int tok = rem >> 6, d = rem & 63;
  int b = pair >> 2, h = pair & 3;
  int pp = idx[pair * 256 + (tok >> 2)];
  int py = (tok >> 1) & 1, px = tok & 1;
  int ry = (pp >> 5) * 2 + py, rx = (pp & 31) * 2 + px;
  y[((size_t)(b * 256 + h * 64 + d) * 64 + ry) * 64 + rx] += outf[g];
}

// ---------------- depthwise 3x3 + BN + relu6 -> packed yd ------------------
__global__ __launch_bounds__(256) void k_dwconv(
    const float* __restrict__ y, const float* __restrict__ wdw,
    const float* __restrict__ g, const float* __restrict__ bb,
    const float* __restrict__ m, const float* __restrict__ vv,
    unsigned* __restrict__ ydhl) {
  int gi = blockIdx.x * 256 + threadIdx.x;
  int x = gi & 63, yy = (gi >> 6) & 63, ch = (gi >> 12) & 255, b = gi >> 20;
  const float* plane = y + (size_t)(b * 256 + ch) * 4096;
  const float* wc = wdw + ch * 9;
  float s = 0.f;
#pragma unroll
  for (int ky = 0; ky < 3; ++ky) {
    int iy = yy + ky - 1;
    if (iy < 0 || iy >= 64) continue;
#pragma unroll
    for (int kx = 0; kx < 3; ++kx) {
      int ix = x + kx - 1;
      if (ix < 0 || ix >= 64) continue;
      s = fmaf(plane[iy * 64 + ix], wc[ky * 3 + kx], s);
    }
  }
  float sc = g[ch] * rsqrtf(vv[ch] + EPS_);
  float val = s * sc + (bb[ch] - m[ch] * sc);
  ydhl[gi] = cvtpack(fminf(fmaxf(val, 0.f), 6.f));
}

// ---------------- pointwise 1x1 + BN + relu6, 64oc x 128pix ----------------
__global__ __launch_bounds__(256) void k_pw_mfma(
    const unsigned* __restrict__ ydhl, const unsigned short* __restrict__ wh,
    const unsigned short* __restrict__ wl, const float* __restrict__ g,
    const float* __restrict__ bb, const float* __restrict__ m,
    const float* __restrict__ vv, float* __restrict__ out) {
  __shared__ unsigned short Ah[64][72], Al[64][72];
  __shared__ unsigned short Bh[128][72], Bl[128][72];
  const int t = threadIdx.x;
  const int pix0 = blockIdx.x * 128;
  const int oc0 = blockIdx.y * 64;
  const int b = pix0 >> 12, pos0 = pix0 & 4095;
  const int wave = t >> 6, lane = t & 63;
  const int l16 = lane & 15, quad = lane >> 4;
  const int wm = (wave & 1) * 32, wn = (wave >> 1) * 64;
  const int pl = t & 127, icg = t >> 7;
  const int ar = t >> 2, ac = (t & 3) * 16;
  f32x4_t acc[2][4] = {};
  for (int kb = 0; kb < 256; kb += 64) {
    const unsigned* p = ydhl + (size_t)(b * 256 + kb + icg * 32) * 4096 + pos0 + pl;
    unsigned u[32];
#pragma unroll
    for (int j = 0; j < 32; ++j) u[j] = p[(size_t)j * 4096];
    unsigned hp[16], lpk[16];
#pragma unroll
    for (int j = 0; j < 16; ++j) {
      hp[j] = pk_h(u[2 * j], u[2 * j + 1]);
      lpk[j] = pk_l(u[2 * j], u[2 * j + 1]);
    }
    bf16x8_t a0 = *(const bf16x8_t*)(wh + (size_t)(oc0 + ar) * 256 + kb + ac);
    bf16x8_t a1 = *(const bf16x8_t*)(wh + (size_t)(oc0 + ar) * 256 + kb + ac + 8);
    bf16x8_t a2 = *(const bf16x8_t*)(wl + (size_t)(oc0 + ar) * 256 + kb + ac);
    bf16x8_t a3 = *(const bf16x8_t*)(wl + (size_t)(oc0 + ar) * 256 + kb + ac + 8);
    __syncthreads();
    *(bf16x8_t*)&Ah[ar][ac] = a0;
    *(bf16x8_t*)&Ah[ar][ac + 8] = a1;
    *(bf16x8_t*)&Al[ar][ac] = a2;
    *(bf16x8_t*)&Al[ar][ac + 8] = a3;
    {
      int kc = icg * 32;
      *(uint4*)&Bh[pl][kc] = make_uint4(hp[0], hp[1], hp[2], hp[3]);
      *(uint4*)&Bh[pl][kc + 8] = make_uint4(hp[4], hp[5], hp[6], hp[7]);
      *(uint4*)&Bh[pl][kc + 16] = make_uint4(hp[8], hp[9], hp[10], hp[11]);
      *(uint4*)&Bh[pl][kc + 24] = make_uint4(hp[12], hp[13], hp[14], hp[15]);
      *(uint4*)&Bl[pl][kc] = make_uint4(lpk[0], lpk[1], lpk[2], lpk[3]);
      *(uint4*)&Bl[pl][kc + 8] = make_uint4(lpk[4], lpk[5], lpk[6], lpk[7]);
      *(uint4*)&Bl[pl][kc + 16] = make_uint4(lpk[8], lpk[9], lpk[10], lpk[11]);
      *(uint4*)&Bl[pl][kc + 24] = make_uint4(lpk[12], lpk[13], lpk[14], lpk[15]);
    }
    __syncthreads();
    mfma_tile2x4(Ah, Al, Bh, Bl, acc, wm, wn, lane);
  }
#pragma unroll
  for (int mt = 0; mt < 2; ++mt)
#pragma unroll
    for (int r = 0; r < 4; ++r) {
      int oc = oc0 + wm + mt * 16 + quad * 4 + r;
      float sc = g[oc] * rsqrtf(vv[oc] + EPS_);
      float off = bb[oc] - m[oc] * sc;
#pragma unroll
      for (int nt = 0; nt < 4; ++nt) {
        int pix = pos0 + wn + nt * 16 + l16;
        float val = fminf(fmaxf(acc[mt][nt][r] * sc + off, 0.f), 6.f);
        out[(size_t)(b * 256 + oc) * 4096 + pix] = val;
      }
    }
}

// ---------------------------------------------------------------------------
extern "C" void kernel_launch(void* const* d_in, const int* in_sizes, int n_in,
                              void* d_out, int out_size, void* d_ws, size_t ws_size,
                              hipStream_t stream) {
  (void)in_sizes; (void)n_in; (void)out_size; (void)ws_size;
  const float* x       = (const float*)d_in[0];
  const float* w_down  = (const float*)d_in[1];
  const float* b_down  = (const float*)d_in[2];
  const float* w_qkv_c = (const float*)d_in[3];
  const float* b_qkv_c = (const float*)d_in[4];
  const float* w_up    = (const float*)d_in[5];
  const float* b_up    = (const float*)d_in[6];
  const float* w_qkv_f = (const float*)d_in[7];
  const float* b_qkv_f = (const float*)d_in[8];
  const float* w_dw    = (const float*)d_in[9];
  const float* bn_dw_g = (const float*)d_in[10];
  const float* bn_dw_b = (const float*)d_in[11];
  const float* bn_dw_m = (const float*)d_in[12];
  const float* bn_dw_v = (const float*)d_in[13];
  const float* w_pw    = (const float*)d_in[14];
  const float* bn_pw_g = (const float*)d_in[15];
  const float* bn_pw_b = (const float*)d_in[16];
  const float* bn_pw_m = (const float*)d_in[17];
  const float* bn_pw_v = (const float*)d_in[18];

  float* ws = (float*)d_ws;  // offsets in 4-byte units (round 6/8 layout)
  unsigned*       xphl   = (unsigned*)ws;                   // 9,191,424 u
  unsigned*       ydhl   = (unsigned*)ws;                   // alias (xphl dead by then)
  unsigned short* qh     = (unsigned short*)(ws + 33554432);
  unsigned short* ql     = (unsigned short*)(ws + 34603008);
  unsigned short* kh     = (unsigned short*)(ws + 35651584);
  unsigned short* kl     = (unsigned short*)(ws + 36700160);
  unsigned short* vth    = (unsigned short*)(ws + 37748736);
  unsigned short* vtl    = (unsigned short*)(ws + 38797312);
  unsigned*       xdhl   = (unsigned*)(ws + 39845888);      // 2,097,152 u
  unsigned*       outcphl= (unsigned*)(ws + 41943040);      // 2,367,488 u
  float*          coarse = ws + 44310528;                   // 8,388,608 f
  float*          outf   = ws + 52699136;                   // 2,097,152 f
  float*          score  = ws + 54796288;                   // 32,768 f
  unsigned short* wdh    = (unsigned short*)(ws + 54829056);
  unsigned short* wdl    = (unsigned short*)(ws + 55353344);
  unsigned short* wt_hi  = (unsigned short*)(ws + 55877632);
  unsigned short* wt_lo  = (unsigned short*)(ws + 56401920);
  unsigned short* wpw_hi = (unsigned short*)(ws + 56926208);
  unsigned short* wpw_lo = (unsigned short*)(ws + 56958976);
  unsigned short* wqh_c  = (unsigned short*)(ws + 56991744);
  unsigned short* wql_c  = (unsigned short*)(ws + 56997888);
  unsigned short* wqh_f  = (unsigned short*)(ws + 57004032);
  unsigned short* wql_f  = (unsigned short*)(ws + 57010176);
  int*            idx    = (int*)(ws + 57016320);           // 8,192 int

  hipMemsetAsync(score, 0, 32768 * sizeof(float), stream);
  hipMemsetAsync(outcphl, 0, (size_t)2367488 * sizeof(unsigned), stream);
  k_pad_x<<<2048, 256, 0, stream>>>(x, xphl);
  k_cvt_wdown<<<4096, 256, 0, stream>>>(w_down, wdh, wdl);
  k_cvt_wqkv<<<48, 256, 0, stream>>>(w_qkv_c, wqh_c, wql_c);
  k_cvt_wqkv<<<48, 256, 0, stream>>>(w_qkv_f, wqh_f, wql_f);
  k_cvt_wup<<<4096, 256, 0, stream>>>(w_up, wt_hi, wt_lo);
  k_cvt_wpw<<<256, 256, 0, stream>>>(w_pw, wpw_hi, wpw_lo);

  k_conv_down_mfma<<<dim3(128, 4), 256, 0, stream>>>(xphl, wdh, wdl, b_down, xdhl);
  k_qkv_mfma<0><<<dim3(16, 32), 256, 0, stream>>>(xdhl, nullptr, wqh_c, wql_c, b_qkv_c,
                                                  nullptr, qh, ql, kh, kl, vth, vtl);
  k_attn_coarse<<<dim3(16, 32), 256, 0, stream>>>(qh, ql, kh, kl, vth, vtl, score, outcphl);
  k_topk<<<32, 256, 0, stream>>>(score, idx);
  k_convT_mfma<<<dim3(64, 4, 4), 256, 0, stream>>>(outcphl, wt_hi, wt_lo, b_up, coarse);

  k_qkv_mfma<1><<<dim3(16, 32), 256, 0, stream>>>(nullptr, coarse, wqh_f, wql_f, b_qkv_f,
                                                  idx, qh, ql, kh, kl, vth, vtl);
  k_attn_fine<<<dim3(16, 32), 256, 0, stream>>>(qh, ql, kh, kl, vth, vtl, outf);
  k_scatter<<<8192, 256, 0, stream>>>(outf, idx, coarse);
  k_dwconv<<<32768, 256, 0, stream>>>(coarse, w_dw, bn_dw_g, bn_dw_b, bn_dw_m, bn_dw_v, ydhl);
  k_pw_mfma<<<dim3(256, 4), 256, 0, stream>>>(ydhl, wpw_hi, wpw_lo, bn_pw_g, bn_pw_b,
                                              bn_pw_m, bn_pw_v, (float*)d_out);
}